// Round 10
// baseline (468.251 us; speedup 1.0000x reference)
//
#include <hip/hip_runtime.h>
#include <hip/hip_bf16.h>

#define DI __device__ __forceinline__
using u16 = unsigned short;
using u32 = unsigned int;

typedef short short8 __attribute__((ext_vector_type(8)));   // 8 bf16 (4 VGPRs)
typedef float f32x4 __attribute__((ext_vector_type(4)));

#define F4C(v, i) ((i) == 0 ? (v).x : (i) == 1 ? (v).y : (i) == 2 ? (v).z : (v).w)

DI float bflo(u32 u) { return __uint_as_float(u << 16); }
DI float bfhi(u32 u) { return __uint_as_float(u & 0xffff0000u); }
DI u16 f2bf(float a) {
  u32 xu = __float_as_uint(a);
  return (u16)((xu + 0x7fffu + ((xu >> 16) & 1)) >> 16);
}
DI u32 pack_bf16x2(float a, float b) {
  u32 xu = __float_as_uint(a), yu = __float_as_uint(b);
  xu = (xu + 0x7fffu + ((xu >> 16) & 1)) >> 16;
  yu = (yu + 0x7fffu + ((yu >> 16) & 1)) >> 16;
  return (xu & 0xffffu) | (yu << 16);
}

// ---------------- workspace layout (float units) ----------------
static constexpr size_t OFF_REGB = 0;
static constexpr size_t OFF_REGA = 16777216;
static constexpr size_t OFF_WT0  = 33554432;
static constexpr size_t OFF_WT1  = OFF_WT0 + 1179648;
static constexpr size_t OFF_WT2  = OFF_WT1 + 294912;
static constexpr size_t OFF_WTF  = OFF_WT2 + 73728;
static constexpr size_t OFF_ST   = 35200000;
static constexpr size_t O_PSUM = OFF_ST + 1048576;   // 512*64*2 float2 = 131072 floats

// ---------------- all weight pre-transposes in one launch ----------------
__global__ __launch_bounds__(256)
void wtrans_all(const float* __restrict__ dw0, const float* __restrict__ dw1,
                const float* __restrict__ dw2, const float* __restrict__ fcw,
                u16* __restrict__ wt0, u16* __restrict__ wt1,
                u16* __restrict__ wt2, u16* __restrict__ wtf)
{
  int id = blockIdx.x * 256 + threadIdx.x;
  if (id < 131072) {                       // dw0: CO=256, CI=512
    int m = id >> 9, c = id & 511;
    const float* src = dw0 + ((size_t)m * 512 + c) * 9;
#pragma unroll
    for (int tap = 0; tap < 9; ++tap)
      wt0[((size_t)tap * 256 + m) * 512 + c] = f2bf(src[tap]);
  } else if (id < 163840) {                // dw1: CO=128, CI=256
    int j = id - 131072;
    int m = j >> 8, c = j & 255;
    const float* src = dw1 + ((size_t)m * 256 + c) * 9;
#pragma unroll
    for (int tap = 0; tap < 9; ++tap)
      wt1[((size_t)tap * 128 + m) * 256 + c] = f2bf(src[tap]);
  } else if (id < 172032) {                // dw2: CO=64, CI=128
    int j = id - 163840;
    int m = j >> 7, c = j & 127;
    const float* src = dw2 + ((size_t)m * 128 + c) * 9;
#pragma unroll
    for (int tap = 0; tap < 9; ++tap)
      wt2[((size_t)tap * 64 + m) * 128 + c] = f2bf(src[tap]);
  } else {                                 // fc: wtf[d][c]
    int j = id - 172032;
    int d = j >> 8, c = j & 255;
    wtf[j] = f2bf(fcw[c * 512 + d]);
  }
}

// ---------------- fc1 via MFMA; GN0 applied in epilogue; x0 stored px-major ----------------
DI void fc_stage_A(const float* __restrict__ feat, int b, u16* Ab, int t)
{
#pragma unroll
  for (int it = 0; it < 2; ++it) {
    int idx = t + it * 256;
    int cp = idx >> 2, hw4 = idx & 3;
    int c = cp * 2;
    const float* xp = feat + ((size_t)b * 256 + c) * 16 + hw4 * 4;
    float4 v0 = *(const float4*)xp;
    float4 v1 = *(const float4*)(xp + 16);
    int c64 = c >> 6, jb = (c & 63) >> 3;
#pragma unroll
    for (int j = 0; j < 4; ++j) {
      int hw = hw4 * 4 + j;
      int row = c64 * 16 + hw;
      *(u32*)&Ab[(row << 6) + ((jb ^ (row & 7)) << 3) + (c & 7)] =
          pack_bf16x2(F4C(v0, j), F4C(v1, j));
    }
  }
}

__global__ __launch_bounds__(256, 3)
void fc_mfma(const float* __restrict__ feat, const u16* __restrict__ wtf,
             const float* __restrict__ fb, const float* __restrict__ gw,
             const float* __restrict__ gb, u16* __restrict__ x0)
{
  __shared__ __align__(16) u16 Wl[256 * 64];
  __shared__ __align__(16) u16 Al[2][64 * 64];
  const int t = threadIdx.x;
  const int lane = t & 63, wave = t >> 6;
  const int n15 = lane & 15, kq = lane >> 4;
  // XCD swizzle: XCD k owns b in [64k, 64k+64); 8 d-blocks of same b-group co-located
  const int lin = blockIdx.y * 8 + blockIdx.x;
  const int xk = lin & 7, pos = lin >> 3;          // pos 0..63
  const int d0 = (pos & 7) * 64;
  const int b0 = (xk * 8 + (pos >> 3)) * 8;

#pragma unroll
  for (int it = 0; it < 8; ++it) {
    int idx = t + it * 256;
    int dl = idx >> 5, jb32 = idx & 31;
    int row = (jb32 >> 3) * 64 + dl, jb = jb32 & 7;
    uint4 v = *(const uint4*)(wtf + (size_t)(d0 + dl) * 256 + jb32 * 8);
    *(uint4*)&Wl[(row << 6) + ((jb ^ (row & 7)) << 3)] = v;
  }
  fc_stage_A(feat, b0, Al[0], t);

  const int dg = d0 + wave * 16 + n15;
  const float bvn = fb[dg];
  const float gwv = gw[dg], gbv = gb[dg];

  for (int bi = 0; bi < 8; ++bi) {
    __syncthreads();
    if (bi + 1 < 8) fc_stage_A(feat, b0 + bi + 1, Al[(bi + 1) & 1], t);

    const u16* A = Al[bi & 1];
    f32x4 acc0 = {0.f, 0.f, 0.f, 0.f}, acc1 = {0.f, 0.f, 0.f, 0.f};
#pragma unroll
    for (int ks = 0; ks < 8; ++ks) {
      int js = ks * 4 + kq;
      int ra = (js >> 3) * 16 + n15;
      int rb = (js >> 3) * 64 + wave * 16 + n15;
      short8 av = *(const short8*)&A[(ra << 6) + (((js & 7) ^ (ra & 7)) << 3)];
      short8 bv = *(const short8*)&Wl[(rb << 6) + (((js & 7) ^ (rb & 7)) << 3)];
      if (ks & 1) acc1 = __builtin_amdgcn_mfma_f32_16x16x32_bf16(av, bv, acc1, 0, 0, 0);
      else        acc0 = __builtin_amdgcn_mfma_f32_16x16x32_bf16(av, bv, acc0, 0, 0, 0);
    }

    int b = b0 + bi;
    float v[4], s = 0.f, s2 = 0.f;
#pragma unroll
    for (int r = 0; r < 4; ++r) {
      v[r] = fmaxf(acc0[r] + acc1[r] + bvn, 0.f);
      s += v[r]; s2 += v[r] * v[r];
    }
    s  += __shfl_xor(s, 16, 64);  s  += __shfl_xor(s, 32, 64);
    s2 += __shfl_xor(s2, 16, 64); s2 += __shfl_xor(s2, 32, 64);
    // GN0 applied here: every lane has full 16-px sums after the butterfly.
    float mu = s * (1.f / 16.f);
    float var = fmaxf(s2 * (1.f / 16.f) - mu * mu, 0.f);
    float scale = gwv * rsqrtf(var + 1e-5f);
    float shift = gbv - mu * scale;
    // x0 layout px-major [b][16 px][512 d]; lane's 4 values are px kq*4+r, channel dg
    u16* yp = x0 + ((size_t)b * 16 + kq * 4) * 512 + dg;
#pragma unroll
    for (int r = 0; r < 4; ++r) yp[(size_t)r * 512] = f2bf(v[r] * scale + shift);
  }
}

// ---------------- deconv stages 0/1: T14 async prefetch (issue-early / write-late)
// STAGE 0: reads x0 px-major [b][16px][512c], writes x1 px-major [b][64px][256c].
// STAGE 1: reads x1 px-major, writes x2 px-major [b][256px][128c].
template<int STAGE>
__global__ __launch_bounds__(256, 3)
void deconv_mfma(const u16* __restrict__ x, const u16* __restrict__ wt,
                 const float* __restrict__ bias, u16* __restrict__ y,
                 const float* __restrict__ gwn, const float* __restrict__ gbn)
{
  constexpr int CI  = STAGE == 0 ? 512 : 256;
  constexpr int CO  = CI / 2;
  constexpr int H   = STAGE == 0 ? 4 : 8;
  constexpr int WP  = H + 1;
  constexpr int XROWS = STAGE == 0 ? 100 : 81;
  constexpr int NCH = CI / 64;
  __shared__ __align__(16) u16 Wl[288 * 64];
  __shared__ __align__(16) u16 Xl[XROWS * 64];
  __shared__ float2 sbuf[2][2][16];
  __shared__ float scl[32], shl[32];

  const int t = threadIdx.x;
  const int lane = t & 63, wave = t >> 6;
  const int ms = wave >> 1, ns = wave & 1;
  const int n15 = lane & 15, kq = lane >> 4;

  // XCD swizzle: XCD k owns b in [64k, 64k+64); all m-blocks of a b co-located
  int m0, b0;
  if constexpr (STAGE == 0) {
    int lin = blockIdx.y * 8 + blockIdx.x;       // 1024 blocks
    int xk = lin & 7, pos = lin >> 3;            // pos 0..127
    m0 = (pos & 7) * 32;
    b0 = (xk * 16 + (pos >> 3)) * 4;
  } else {
    int lin = blockIdx.y * 4 + blockIdx.x;       // 2048 blocks
    int xk = lin & 7, pos = lin >> 3;            // pos 0..255
    m0 = (pos & 3) * 32;
    b0 = xk * 64 + (pos >> 2);
  }

  int xrow[2];
#pragma unroll
  for (int ni = 0; ni < 2; ++ni) {
    if constexpr (STAGE == 0) xrow[ni] = (ns * 2 + ni) * 25 + (n15 >> 2) * 5 + (n15 & 3);
    else                      xrow[ni] = (2 * (ns * 2 + ni) + (n15 >> 3)) * 9 + (n15 & 7);
  }
  const int am = ms * 16 + n15;

  for (int i = t; i < XROWS * 32; i += 256) ((u32*)Xl)[i] = 0;

  f32x4 acc[2][4];
#pragma unroll
  for (int ni = 0; ni < 2; ++ni)
#pragma unroll
    for (int c = 0; c < 4; ++c) acc[ni][c] = f32x4{0.f, 0.f, 0.f, 0.f};

  uint4 wreg[9], xreg[2];
  auto loadWX = [&](int c0_) {
#pragma unroll
    for (int it = 0; it < 9; ++it) {
      int idx = t + it * 256;
      int row = idx >> 3, jb = idx & 7;
      int tap = row >> 5, ml = row & 31;
      wreg[it] = *(const uint4*)(wt + ((size_t)(tap * CO + m0 + ml)) * CI + c0_ + jb * 8);
    }
    if constexpr (STAGE == 0) {
#pragma unroll
      for (int it = 0; it < 2; ++it) {
        int idx = t + it * 256;
        int pxl = idx >> 3, jb = idx & 7;
        int img = pxl >> 4, p = pxl & 15;
        xreg[it] = *(const uint4*)(x + ((size_t)(b0 + img) * 16 + p) * 512 + c0_ + jb * 8);
      }
    } else {
#pragma unroll
      for (int it = 0; it < 2; ++it) {
        int idx = t + it * 256;
        int pxl = idx >> 3, jb = idx & 7;
        xreg[it] = *(const uint4*)(x + ((size_t)b0 * 64 + pxl) * 256 + c0_ + jb * 8);
      }
    }
  };

  loadWX(0);
  for (int ch = 0; ch < NCH; ++ch) {
    __syncthreads();
    // commit prefetched staging to LDS
#pragma unroll
    for (int it = 0; it < 9; ++it) {
      int idx = t + it * 256;
      int row = idx >> 3, jb = idx & 7;
      *(uint4*)&Wl[(row << 6) + ((jb ^ (row & 7)) << 3)] = wreg[it];
    }
#pragma unroll
    for (int it = 0; it < 2; ++it) {
      int idx = t + it * 256;
      int pxl = idx >> 3, jb = idx & 7;
      int row;
      if constexpr (STAGE == 0) {
        int img = pxl >> 4, p = pxl & 15;
        row = img * 25 + (p >> 2) * 5 + (p & 3);
      } else {
        row = (pxl >> 3) * 9 + (pxl & 7);
      }
      *(uint4*)&Xl[(row << 6) + ((jb ^ (row & 7)) << 3)] = xreg[it];
    }
    // issue next chunk's loads early: latency hides under MFMA phase below
    if (ch + 1 < NCH) loadWX((ch + 1) * 64);
    __syncthreads();

#pragma unroll
    for (int s = 0; s < 2; ++s) {
      const int js = s * 4 + kq;
      short8 a[9];
#pragma unroll
      for (int tap = 0; tap < 9; ++tap) {
        int row = tap * 32 + am;
        a[tap] = *(const short8*)&Wl[(row << 6) + ((js ^ (row & 7)) << 3)];
      }
#pragma unroll
      for (int ni = 0; ni < 2; ++ni) {
        int r0 = xrow[ni], r1 = r0 + 1, r2 = r0 + WP, r3 = r0 + WP + 1;
        short8 b00 = *(const short8*)&Xl[(r0 << 6) + ((js ^ (r0 & 7)) << 3)];
        short8 b01 = *(const short8*)&Xl[(r1 << 6) + ((js ^ (r1 & 7)) << 3)];
        short8 b10 = *(const short8*)&Xl[(r2 << 6) + ((js ^ (r2 & 7)) << 3)];
        short8 b11 = *(const short8*)&Xl[(r3 << 6) + ((js ^ (r3 & 7)) << 3)];
        acc[ni][0] = __builtin_amdgcn_mfma_f32_16x16x32_bf16(a[4], b00, acc[ni][0], 0, 0, 0);
        acc[ni][1] = __builtin_amdgcn_mfma_f32_16x16x32_bf16(a[3], b00, acc[ni][1], 0, 0, 0);
        acc[ni][1] = __builtin_amdgcn_mfma_f32_16x16x32_bf16(a[5], b01, acc[ni][1], 0, 0, 0);
        acc[ni][2] = __builtin_amdgcn_mfma_f32_16x16x32_bf16(a[1], b00, acc[ni][2], 0, 0, 0);
        acc[ni][2] = __builtin_amdgcn_mfma_f32_16x16x32_bf16(a[7], b10, acc[ni][2], 0, 0, 0);
        acc[ni][3] = __builtin_amdgcn_mfma_f32_16x16x32_bf16(a[0], b00, acc[ni][3], 0, 0, 0);
        acc[ni][3] = __builtin_amdgcn_mfma_f32_16x16x32_bf16(a[2], b01, acc[ni][3], 0, 0, 0);
        acc[ni][3] = __builtin_amdgcn_mfma_f32_16x16x32_bf16(a[6], b10, acc[ni][3], 0, 0, 0);
        acc[ni][3] = __builtin_amdgcn_mfma_f32_16x16x32_bf16(a[8], b11, acc[ni][3], 0, 0, 0);
      }
    }
  }

  // ---- epilogue: bias + relu + next-GN normalize + store ----
  float bv[4];
#pragma unroll
  for (int r = 0; r < 4; ++r) bv[r] = bias[m0 + ms * 16 + kq * 4 + r];

  if constexpr (STAGE == 0) {
    float gw4[4], gb4[4];
#pragma unroll
    for (int r = 0; r < 4; ++r) {
      int m = m0 + ms * 16 + kq * 4 + r;
      gw4[r] = gwn[m]; gb4[r] = gbn[m];
    }
#pragma unroll
    for (int ni = 0; ni < 2; ++ni) {
      int b = b0 + ns * 2 + ni, iy = n15 >> 2, ix = n15 & 3;
      float val[4][4];
      float sr[4] = {0.f, 0.f, 0.f, 0.f}, sr2[4] = {0.f, 0.f, 0.f, 0.f};
#pragma unroll
      for (int cl = 0; cl < 4; ++cl)
#pragma unroll
        for (int r = 0; r < 4; ++r) {
          val[cl][r] = fmaxf(acc[ni][cl][r] + bv[r], 0.f);
          sr[r] += val[cl][r]; sr2[r] += val[cl][r] * val[cl][r];
        }
#pragma unroll
      for (int r = 0; r < 4; ++r) {
#pragma unroll
        for (int off = 1; off <= 8; off <<= 1) {
          sr[r]  += __shfl_xor(sr[r], off, 64);
          sr2[r] += __shfl_xor(sr2[r], off, 64);
        }
      }
      // full 64-px stats now in all lanes -> normalize in-lane, store normalized px-major
      float scv[4], shv[4];
#pragma unroll
      for (int r = 0; r < 4; ++r) {
        float mu = sr[r] * (1.f / 64.f);
        float var = fmaxf(sr2[r] * (1.f / 64.f) - mu * mu, 0.f);
        scv[r] = gw4[r] * rsqrtf(var + 1e-5f);
        shv[r] = gb4[r] - mu * scv[r];
      }
      // x1 layout [b][8x8 px][256 c]
#pragma unroll
      for (int cl = 0; cl < 4; ++cl) {
        int oy = 2 * iy + (cl >> 1), ox = 2 * ix + (cl & 1);
        size_t base = ((size_t)b * 64 + oy * 8 + ox) * 256 + m0 + ms * 16 + kq * 4;
        uint2 pk = {pack_bf16x2(val[cl][0] * scv[0] + shv[0],
                                val[cl][1] * scv[1] + shv[1]),
                    pack_bf16x2(val[cl][2] * scv[2] + shv[2],
                                val[cl][3] * scv[3] + shv[3])};
        *(uint2*)(y + base) = pk;
      }
    }
  } else {
    float sr[4] = {0.f, 0.f, 0.f, 0.f}, sr2[4] = {0.f, 0.f, 0.f, 0.f};
#pragma unroll
    for (int ni = 0; ni < 2; ++ni)
#pragma unroll
      for (int cl = 0; cl < 4; ++cl)
#pragma unroll
        for (int r = 0; r < 4; ++r) {
          float v = fmaxf(acc[ni][cl][r] + bv[r], 0.f);
          sr[r] += v; sr2[r] += v * v;
        }
#pragma unroll
    for (int r = 0; r < 4; ++r) {
#pragma unroll
      for (int off = 1; off <= 8; off <<= 1) {
        sr[r]  += __shfl_xor(sr[r], off, 64);
        sr2[r] += __shfl_xor(sr2[r], off, 64);
      }
    }
    __syncthreads();
    if (n15 == 0) {
#pragma unroll
      for (int r = 0; r < 4; ++r) sbuf[ms][ns][kq * 4 + r] = float2{sr[r], sr2[r]};
    }
    __syncthreads();
    if (t < 32) {
      int msx = t >> 4, i = t & 15;
      float2 p0 = sbuf[msx][0][i], p1 = sbuf[msx][1][i];
      float s = p0.x + p1.x, s2 = p0.y + p1.y;
      float mu = s * (1.f / 256.f);
      float var = fmaxf(s2 * (1.f / 256.f) - mu * mu, 0.f);
      int m = m0 + msx * 16 + i;
      float scale = gwn[m] * rsqrtf(var + 1e-5f);
      scl[t] = scale;
      shl[t] = gbn[m] - mu * scale;
    }
    __syncthreads();
    float scv[4], shv[4];
#pragma unroll
    for (int r = 0; r < 4; ++r) {
      scv[r] = scl[ms * 16 + kq * 4 + r];
      shv[r] = shl[ms * 16 + kq * 4 + r];
    }
    // x2 layout [b][256 px][128 c], stored pre-normalized
#pragma unroll
    for (int ni = 0; ni < 2; ++ni) {
      int iy = 2 * (ns * 2 + ni) + (n15 >> 3), ix = n15 & 7;
#pragma unroll
      for (int cl = 0; cl < 4; ++cl) {
        int opx = (2 * iy + (cl >> 1)) * 16 + 2 * ix + (cl & 1);
        size_t base = ((size_t)b0 * 256 + opx) * 128 + m0 + ms * 16 + kq * 4;
        float v0 = fmaxf(acc[ni][cl][0] + bv[0], 0.f) * scv[0] + shv[0];
        float v1 = fmaxf(acc[ni][cl][1] + bv[1], 0.f) * scv[1] + shv[1];
        float v2 = fmaxf(acc[ni][cl][2] + bv[2], 0.f) * scv[2] + shv[2];
        float v3 = fmaxf(acc[ni][cl][3] + bv[3], 0.f) * scv[3] + shv[3];
        *(u32*)(y + base)     = pack_bf16x2(v0, v1);
        *(u32*)(y + base + 2) = pack_bf16x2(v2, v3);
      }
    }
  }
}

// ---------------- stage-2 deconv: 4 n-tiles/wave, shared B rows; T14 prefetch ----------------
#define XRD(row) (*(const short8*)&Xl[((row) << 6) + (((js ^ ((row) & 7))) << 3)])
__global__ __launch_bounds__(256, 2)
void deconv2_q(const u16* __restrict__ x, const u16* __restrict__ wt,
               const float* __restrict__ bias, u16* __restrict__ y,
               float2* __restrict__ psum)
{
  __shared__ __align__(16) u16 Wl[288 * 64];
  __shared__ __align__(16) u16 Xl[153 * 64];  // row = rl*17 + ix, rl 0..8 (halo stays 0)
  __shared__ float2 sbuf[2][2][16];

  const int t = threadIdx.x;
  const int lane = t & 63, wave = t >> 6;
  const int ms = wave >> 1, ns = wave & 1;
  const int n15 = lane & 15, kq = lane >> 4;
  // XCD swizzle: XCD k owns b in [64k, 64k+64)
  const int lin = blockIdx.y * 4 + blockIdx.x;   // 2048 blocks
  const int xk = lin & 7, pos = lin >> 3;        // pos 0..255
  const int b   = xk * 64 + (pos >> 2);
  const int m0  = (pos & 1) * 32;
  const int qz2 = (pos >> 1) & 1;                // 0..1 (16 output rows each)

  for (int i = t; i < 153 * 32; i += 256) ((u32*)Xl)[i] = 0;

  const int am = ms * 16 + n15;
  const int xr0 = (ns * 4) * 17 + n15;

  f32x4 acc[4][4];
#pragma unroll
  for (int ni = 0; ni < 4; ++ni)
#pragma unroll
    for (int c = 0; c < 4; ++c) acc[ni][c] = f32x4{0.f, 0.f, 0.f, 0.f};

  const int NPX = (qz2 == 0) ? 144 : 128;     // input rows 0..8 / 8..15 (+zero halo)

  uint4 wreg[9], xreg[5];
  auto loadWX = [&](int c0_) {
#pragma unroll
    for (int it = 0; it < 9; ++it) {
      int idx = t + it * 256;
      int row = idx >> 3, jb = idx & 7;
      int tap = row >> 5, ml = row & 31;
      wreg[it] = *(const uint4*)(wt + ((size_t)(tap * 64 + m0 + ml)) * 128 + c0_ + jb * 8);
    }
#pragma unroll
    for (int it = 0; it < 5; ++it) {
      int idx = t + it * 256;
      if (idx < NPX * 8) {
        int pxl = idx >> 3, jb = idx & 7;
        int rl = pxl >> 4, ix = pxl & 15;
        int gpx = (8 * qz2 + rl) * 16 + ix;
        xreg[it] = *(const uint4*)(x + ((size_t)b * 256 + gpx) * 128 + c0_ + jb * 8);
      }
    }
  };

  loadWX(0);
  for (int ch = 0; ch < 2; ++ch) {
    __syncthreads();
    // commit prefetched staging to LDS
#pragma unroll
    for (int it = 0; it < 9; ++it) {
      int idx = t + it * 256;
      int row = idx >> 3, jb = idx & 7;
      *(uint4*)&Wl[(row << 6) + ((jb ^ (row & 7)) << 3)] = wreg[it];
    }
#pragma unroll
    for (int it = 0; it < 5; ++it) {
      int idx = t + it * 256;
      if (idx < NPX * 8) {
        int pxl = idx >> 3, jb = idx & 7;
        int rl = pxl >> 4, ix = pxl & 15;
        int row = rl * 17 + ix;
        *(uint4*)&Xl[(row << 6) + ((jb ^ (row & 7)) << 3)] = xreg[it];
      }
    }
    if (ch == 0) loadWX(64);      // issue-early: hides under MFMA below
    __syncthreads();

#pragma unroll
    for (int s = 0; s < 2; ++s) {
      const int js = s * 4 + kq;
      short8 a[9];
#pragma unroll
      for (int tap = 0; tap < 9; ++tap) {
        int row = tap * 32 + am;
        a[tap] = *(const short8*)&Wl[(row << 6) + ((js ^ (row & 7)) << 3)];
      }
      // 10 B rows shared across the wave's 4 adjacent n-tiles
      short8 Brow[10];
#pragma unroll
      for (int k = 0; k < 5; ++k) {
        Brow[2 * k]     = XRD(xr0 + 17 * k);
        Brow[2 * k + 1] = XRD(xr0 + 17 * k + 1);
      }
      __builtin_amdgcn_s_setprio(1);
#pragma unroll
      for (int ni = 0; ni < 4; ++ni) {
        short8 b00 = Brow[2 * ni],     b01 = Brow[2 * ni + 1];
        short8 b10 = Brow[2 * ni + 2], b11 = Brow[2 * ni + 3];
        acc[ni][0] = __builtin_amdgcn_mfma_f32_16x16x32_bf16(a[4], b00, acc[ni][0], 0, 0, 0);
        acc[ni][1] = __builtin_amdgcn_mfma_f32_16x16x32_bf16(a[3], b00, acc[ni][1], 0, 0, 0);
        acc[ni][1] = __builtin_amdgcn_mfma_f32_16x16x32_bf16(a[5], b01, acc[ni][1], 0, 0, 0);
        acc[ni][2] = __builtin_amdgcn_mfma_f32_16x16x32_bf16(a[1], b00, acc[ni][2], 0, 0, 0);
        acc[ni][2] = __builtin_amdgcn_mfma_f32_16x16x32_bf16(a[7], b10, acc[ni][2], 0, 0, 0);
        acc[ni][3] = __builtin_amdgcn_mfma_f32_16x16x32_bf16(a[0], b00, acc[ni][3], 0, 0, 0);
        acc[ni][3] = __builtin_amdgcn_mfma_f32_16x16x32_bf16(a[2], b01, acc[ni][3], 0, 0, 0);
        acc[ni][3] = __builtin_amdgcn_mfma_f32_16x16x32_bf16(a[6], b10, acc[ni][3], 0, 0, 0);
        acc[ni][3] = __builtin_amdgcn_mfma_f32_16x16x32_bf16(a[8], b11, acc[ni][3], 0, 0, 0);
      }
      __builtin_amdgcn_s_setprio(0);
    }
  }

  // ---- epilogue: bias + relu + store + stat partials ----
  float bv[4];
#pragma unroll
  for (int r = 0; r < 4; ++r) bv[r] = bias[m0 + ms * 16 + kq * 4 + r];
  float sr[4] = {0.f, 0.f, 0.f, 0.f}, sr2[4] = {0.f, 0.f, 0.f, 0.f};
#pragma unroll
  for (int ni = 0; ni < 4; ++ni) {
    int iy = 8 * qz2 + ns * 4 + ni, ix = n15;
#pragma unroll
    for (int r = 0; r < 4; ++r) {
      int m = m0 + ms * 16 + kq * 4 + r;
      float v00 = fmaxf(acc[ni][0][r] + bv[r], 0.f);
      float v01 = fmaxf(acc[ni][1][r] + bv[r], 0.f);
      float v10 = fmaxf(acc[ni][2][r] + bv[r], 0.f);
      float v11 = fmaxf(acc[ni][3][r] + bv[r], 0.f);
      size_t base = ((size_t)b * 64 + m) * 1024 + (size_t)(2 * iy) * 32 + 2 * ix;
      *(u32*)(y + base)      = pack_bf16x2(v00, v01);
      *(u32*)(y + base + 32) = pack_bf16x2(v10, v11);
      sr[r]  += v00 + v01 + v10 + v11;
      sr2[r] += v00 * v00 + v01 * v01 + v10 * v10 + v11 * v11;
    }
  }
#pragma unroll
  for (int r = 0; r < 4; ++r) {
#pragma unroll
    for (int off = 1; off <= 8; off <<= 1) {
      sr[r]  += __shfl_xor(sr[r], off, 64);
      sr2[r] += __shfl_xor(sr2[r], off, 64);
    }
  }
  __syncthreads();
  if (n15 == 0) {
#pragma unroll
    for (int r = 0; r < 4; ++r) sbuf[ms][ns][kq * 4 + r] = float2{sr[r], sr2[r]};
  }
  __syncthreads();
  if (t < 32) {
    int msx = t >> 4, i = t & 15;
    float2 p0 = sbuf[msx][0][i], p1 = sbuf[msx][1][i];
    int m = m0 + msx * 16 + i;
    psum[((size_t)b * 64 + m) * 2 + qz2] = float2{p0.x + p1.x, p0.y + p1.y};
  }
}

// ---------------- block reductions ----------------
DI float breduce_sum(float v, float* buf) {
#pragma unroll
  for (int off = 32; off; off >>= 1) v += __shfl_xor(v, off, 64);
  if ((threadIdx.x & 63) == 0) buf[threadIdx.x >> 6] = v;
  __syncthreads();
  float r = (buf[0] + buf[1]) + (buf[2] + buf[3]);
  __syncthreads();
  return r;
}
DI float breduce_max(float v, float* buf) {
#pragma unroll
  for (int off = 32; off; off >>= 1) v = fmaxf(v, __shfl_xor(v, off, 64));
  if ((threadIdx.x & 63) == 0) buf[threadIdx.x >> 6] = v;
  __syncthreads();
  float r = fmaxf(fmaxf(buf[0], buf[1]), fmaxf(buf[2], buf[3]));
  __syncthreads();
  return r;
}

// ---------------- head: fold stat partials -> norm -> 1x1 conv -> spatial softmax ----------------
__global__ __launch_bounds__(256)
void head_kernel(const u16* __restrict__ x3, const float2* __restrict__ psum,
                 const int* __restrict__ action, const float* __restrict__ hgw,
                 const float* __restrict__ hcw, float* __restrict__ out)
{
  constexpr int C = 64, S = 5, P = 1024;
  const int t = threadIdx.x;
  const int b = (blockIdx.x & 7) * 64 + (blockIdx.x >> 3);   // XCD-consistent b mapping
  const int a = action[b];
  __shared__ float weff[S * C];
  __shared__ float sc_l[C], sh_l[C];
  __shared__ float rbuf[4];
  if (t < C) {
    float2 p0 = psum[((size_t)b * C + t) * 2 + 0];
    float2 p1 = psum[((size_t)b * C + t) * 2 + 1];
    float s = p0.x + p1.x, s2 = p0.y + p1.y;
    float mu = s * (1.f / 1024.f);
    float var = fmaxf(s2 * (1.f / 1024.f) - mu * mu, 0.f);
    float rstd = rsqrtf(var + 1e-5f);
    sc_l[t] = rstd; sh_l[t] = -mu * rstd;
  }
  for (int j = t; j < S * C; j += 256) {
    int s = j >> 6, c = j & 63;
    weff[j] = hcw[(a * S + s) * C + c] * hgw[a * C + c];
  }
  __syncthreads();

  float L[S][4];
#pragma unroll
  for (int s = 0; s < S; ++s)
#pragma unroll
    for (int k = 0; k < 4; ++k) L[s][k] = 0.f;

  const u32* xb = (const u32*)(x3 + (size_t)b * C * P);
  for (int c = 0; c < C; ++c) {
    float scv = sc_l[c], shv = sh_l[c];
    u32 u0 = xb[c * 512 + t];
    u32 u1 = xb[c * 512 + t + 256];
    float xv[4] = {bflo(u0) * scv + shv, bfhi(u0) * scv + shv,
                   bflo(u1) * scv + shv, bfhi(u1) * scv + shv};
#pragma unroll
    for (int s = 0; s < S; ++s) {
      float wv = weff[s * C + c];
#pragma unroll
      for (int k = 0; k < 4; ++k) L[s][k] += xv[k] * wv;
    }
  }

#pragma unroll
  for (int s = 0; s < S; ++s) {
    float m = fmaxf(fmaxf(L[s][0], L[s][1]), fmaxf(L[s][2], L[s][3]));
    m = breduce_max(m, rbuf);
    float se = 0.f, sx = 0.f, sy = 0.f;
    const int pix[4] = {2 * t, 2 * t + 1, 512 + 2 * t, 512 + 2 * t + 1};
#pragma unroll
    for (int k = 0; k < 4; ++k) {
      int p = pix[k];
      float e = __expf(L[s][k] - m);
      se += e;
      sx += e * ((float)(p & 31) * (2.f / 31.f) - 1.f);
      sy += e * ((float)(p >> 5) * (2.f / 31.f) - 1.f);
    }
    se = breduce_sum(se, rbuf);
    sx = breduce_sum(sx, rbuf);
    sy = breduce_sum(sy, rbuf);
    if (t == 0) {
      out[(b * S + s) * 2 + 0] = sx / se;
      out[(b * S + s) * 2 + 1] = sy / se;
    }
  }
}

// ---------------- launcher ----------------
extern "C" void kernel_launch(void* const* d_in, const int* in_sizes, int n_in,
                              void* d_out, int out_size, void* d_ws, size_t ws_size,
                              hipStream_t stream)
{
  (void)in_sizes; (void)n_in; (void)out_size; (void)ws_size;
  const float* feat   = (const float*)d_in[0];
  const int*   action = (const int*)d_in[1];
  const float* fc_w = (const float*)d_in[3];
  const float* fc_b = (const float*)d_in[4];
  const float* gw0  = (const float*)d_in[5];
  const float* gb0  = (const float*)d_in[6];
  const float* dw0  = (const float*)d_in[7];
  const float* db0  = (const float*)d_in[8];
  const float* gw1  = (const float*)d_in[9];
  const float* gb1  = (const float*)d_in[10];
  const float* dw1  = (const float*)d_in[11];
  const float* db1  = (const float*)d_in[12];
  const float* gw2  = (const float*)d_in[13];
  const float* gb2  = (const float*)d_in[14];
  const float* dw2  = (const float*)d_in[15];
  const float* db2  = (const float*)d_in[16];
  const float* hgw  = (const float*)d_in[17];
  const float* hcw  = (const float*)d_in[19];

  float* ws = (float*)d_ws;
  u16* x0 = (u16*)(ws + OFF_REGB);
  u16* x2 = (u16*)(ws + OFF_REGB);
  u16* x1 = (u16*)(ws + OFF_REGA);
  u16* x3 = (u16*)(ws + OFF_REGA);
  u16* wt0 = (u16*)(ws + OFF_WT0);
  u16* wt1 = (u16*)(ws + OFF_WT1);
  u16* wt2 = (u16*)(ws + OFF_WT2);
  u16* wtf = (u16*)(ws + OFF_WTF);
  float2* psum = (float2*)(ws + O_PSUM);

  wtrans_all<<<1184, 256, 0, stream>>>(dw0, dw1, dw2, fc_w, wt0, wt1, wt2, wtf);
  fc_mfma<<<dim3(8, 64), 256, 0, stream>>>(feat, wtf, fc_b, gw0, gb0, x0);
  deconv_mfma<0><<<dim3(8, 128), 256, 0, stream>>>(x0, wt0, db0, x1, gw1, gb1);
  deconv_mfma<1><<<dim3(4, 512), 256, 0, stream>>>(x1, wt1, db1, x2, gw2, gb2);
  deconv2_q<<<dim3(4, 512), 256, 0, stream>>>(x2, wt2, db2, x3, psum);
  head_kernel<<<512, 256, 0, stream>>>(x3, psum, action, hgw, hcw, (float*)d_out);
}

// Round 11
// 249.244 us; speedup vs baseline: 1.8787x; 1.8787x over previous
//
#include <hip/hip_runtime.h>
#include <hip/hip_bf16.h>

#define DI __device__ __forceinline__
using u16 = unsigned short;
using u32 = unsigned int;

typedef short short8 __attribute__((ext_vector_type(8)));   // 8 bf16 (4 VGPRs)
typedef float f32x4 __attribute__((ext_vector_type(4)));

#define F4C(v, i) ((i) == 0 ? (v).x : (i) == 1 ? (v).y : (i) == 2 ? (v).z : (v).w)

DI float bflo(u32 u) { return __uint_as_float(u << 16); }
DI float bfhi(u32 u) { return __uint_as_float(u & 0xffff0000u); }
DI u16 f2bf(float a) {
  u32 xu = __float_as_uint(a);
  return (u16)((xu + 0x7fffu + ((xu >> 16) & 1)) >> 16);
}
DI u32 pack_bf16x2(float a, float b) {
  u32 xu = __float_as_uint(a), yu = __float_as_uint(b);
  xu = (xu + 0x7fffu + ((xu >> 16) & 1)) >> 16;
  yu = (yu + 0x7fffu + ((yu >> 16) & 1)) >> 16;
  return (xu & 0xffffu) | (yu << 16);
}

// ---------------- workspace layout (float units) ----------------
static constexpr size_t OFF_REGB = 0;
static constexpr size_t OFF_REGA = 16777216;
static constexpr size_t OFF_WT0  = 33554432;
static constexpr size_t OFF_WT1  = OFF_WT0 + 1179648;
static constexpr size_t OFF_WT2  = OFF_WT1 + 294912;
static constexpr size_t OFF_WTF  = OFF_WT2 + 73728;
static constexpr size_t OFF_ST   = 35200000;
static constexpr size_t O_PSUM = OFF_ST + 1048576;   // 512*64*2 float2 = 131072 floats

// ---------------- all weight pre-transposes in one launch ----------------
__global__ __launch_bounds__(256)
void wtrans_all(const float* __restrict__ dw0, const float* __restrict__ dw1,
                const float* __restrict__ dw2, const float* __restrict__ fcw,
                u16* __restrict__ wt0, u16* __restrict__ wt1,
                u16* __restrict__ wt2, u16* __restrict__ wtf)
{
  int id = blockIdx.x * 256 + threadIdx.x;
  if (id < 131072) {                       // dw0: CO=256, CI=512
    int m = id >> 9, c = id & 511;
    const float* src = dw0 + ((size_t)m * 512 + c) * 9;
#pragma unroll
    for (int tap = 0; tap < 9; ++tap)
      wt0[((size_t)tap * 256 + m) * 512 + c] = f2bf(src[tap]);
  } else if (id < 163840) {                // dw1: CO=128, CI=256
    int j = id - 131072;
    int m = j >> 8, c = j & 255;
    const float* src = dw1 + ((size_t)m * 256 + c) * 9;
#pragma unroll
    for (int tap = 0; tap < 9; ++tap)
      wt1[((size_t)tap * 128 + m) * 256 + c] = f2bf(src[tap]);
  } else if (id < 172032) {                // dw2: CO=64, CI=128
    int j = id - 163840;
    int m = j >> 7, c = j & 127;
    const float* src = dw2 + ((size_t)m * 128 + c) * 9;
#pragma unroll
    for (int tap = 0; tap < 9; ++tap)
      wt2[((size_t)tap * 64 + m) * 128 + c] = f2bf(src[tap]);
  } else {                                 // fc: wtf[d][c]
    int j = id - 172032;
    int d = j >> 8, c = j & 255;
    wtf[j] = f2bf(fcw[c * 512 + d]);
  }
}

// ---------------- fc1 via MFMA; GN0 applied in epilogue; x0 stored px-major ----------------
DI void fc_stage_A(const float* __restrict__ feat, int b, u16* Ab, int t)
{
#pragma unroll
  for (int it = 0; it < 2; ++it) {
    int idx = t + it * 256;
    int cp = idx >> 2, hw4 = idx & 3;
    int c = cp * 2;
    const float* xp = feat + ((size_t)b * 256 + c) * 16 + hw4 * 4;
    float4 v0 = *(const float4*)xp;
    float4 v1 = *(const float4*)(xp + 16);
    int c64 = c >> 6, jb = (c & 63) >> 3;
#pragma unroll
    for (int j = 0; j < 4; ++j) {
      int hw = hw4 * 4 + j;
      int row = c64 * 16 + hw;
      *(u32*)&Ab[(row << 6) + ((jb ^ (row & 7)) << 3) + (c & 7)] =
          pack_bf16x2(F4C(v0, j), F4C(v1, j));
    }
  }
}

__global__ __launch_bounds__(256, 3)
void fc_mfma(const float* __restrict__ feat, const u16* __restrict__ wtf,
             const float* __restrict__ fb, const float* __restrict__ gw,
             const float* __restrict__ gb, u16* __restrict__ x0)
{
  __shared__ __align__(16) u16 Wl[256 * 64];
  __shared__ __align__(16) u16 Al[2][64 * 64];
  const int t = threadIdx.x;
  const int lane = t & 63, wave = t >> 6;
  const int n15 = lane & 15, kq = lane >> 4;
  // XCD swizzle: XCD k owns b in [64k, 64k+64); 8 d-blocks of same b-group co-located
  const int lin = blockIdx.y * 8 + blockIdx.x;
  const int xk = lin & 7, pos = lin >> 3;          // pos 0..63
  const int d0 = (pos & 7) * 64;
  const int b0 = (xk * 8 + (pos >> 3)) * 8;

#pragma unroll
  for (int it = 0; it < 8; ++it) {
    int idx = t + it * 256;
    int dl = idx >> 5, jb32 = idx & 31;
    int row = (jb32 >> 3) * 64 + dl, jb = jb32 & 7;
    uint4 v = *(const uint4*)(wtf + (size_t)(d0 + dl) * 256 + jb32 * 8);
    *(uint4*)&Wl[(row << 6) + ((jb ^ (row & 7)) << 3)] = v;
  }
  fc_stage_A(feat, b0, Al[0], t);

  const int dg = d0 + wave * 16 + n15;
  const float bvn = fb[dg];
  const float gwv = gw[dg], gbv = gb[dg];

  for (int bi = 0; bi < 8; ++bi) {
    __syncthreads();
    if (bi + 1 < 8) fc_stage_A(feat, b0 + bi + 1, Al[(bi + 1) & 1], t);

    const u16* A = Al[bi & 1];
    f32x4 acc0 = {0.f, 0.f, 0.f, 0.f}, acc1 = {0.f, 0.f, 0.f, 0.f};
#pragma unroll
    for (int ks = 0; ks < 8; ++ks) {
      int js = ks * 4 + kq;
      int ra = (js >> 3) * 16 + n15;
      int rb = (js >> 3) * 64 + wave * 16 + n15;
      short8 av = *(const short8*)&A[(ra << 6) + (((js & 7) ^ (ra & 7)) << 3)];
      short8 bv = *(const short8*)&Wl[(rb << 6) + (((js & 7) ^ (rb & 7)) << 3)];
      if (ks & 1) acc1 = __builtin_amdgcn_mfma_f32_16x16x32_bf16(av, bv, acc1, 0, 0, 0);
      else        acc0 = __builtin_amdgcn_mfma_f32_16x16x32_bf16(av, bv, acc0, 0, 0, 0);
    }

    int b = b0 + bi;
    float v[4], s = 0.f, s2 = 0.f;
#pragma unroll
    for (int r = 0; r < 4; ++r) {
      v[r] = fmaxf(acc0[r] + acc1[r] + bvn, 0.f);
      s += v[r]; s2 += v[r] * v[r];
    }
    s  += __shfl_xor(s, 16, 64);  s  += __shfl_xor(s, 32, 64);
    s2 += __shfl_xor(s2, 16, 64); s2 += __shfl_xor(s2, 32, 64);
    // GN0 applied here: every lane has full 16-px sums after the butterfly.
    float mu = s * (1.f / 16.f);
    float var = fmaxf(s2 * (1.f / 16.f) - mu * mu, 0.f);
    float scale = gwv * rsqrtf(var + 1e-5f);
    float shift = gbv - mu * scale;
    // x0 layout px-major [b][16 px][512 d]; lane's 4 values are px kq*4+r, channel dg
    u16* yp = x0 + ((size_t)b * 16 + kq * 4) * 512 + dg;
#pragma unroll
    for (int r = 0; r < 4; ++r) yp[(size_t)r * 512] = f2bf(v[r] * scale + shift);
  }
}

// ---------------- deconv stages 0/1: inputs pre-normalized px-major; pure-copy stage-X
// STAGE 0: reads x0 px-major [b][16px][512c], writes x1 px-major [b][64px][256c].
// STAGE 1: reads x1 px-major, writes x2 px-major [b][256px][128c].
template<int STAGE>
__global__ __launch_bounds__(256, 3)
void deconv_mfma(const u16* __restrict__ x, const u16* __restrict__ wt,
                 const float* __restrict__ bias, u16* __restrict__ y,
                 const float* __restrict__ gwn, const float* __restrict__ gbn)
{
  constexpr int CI  = STAGE == 0 ? 512 : 256;
  constexpr int CO  = CI / 2;
  constexpr int H   = STAGE == 0 ? 4 : 8;
  constexpr int WP  = H + 1;
  constexpr int XROWS = STAGE == 0 ? 100 : 81;
  constexpr int NCH = CI / 64;
  __shared__ __align__(16) u16 Wl[288 * 64];
  __shared__ __align__(16) u16 Xl[XROWS * 64];
  __shared__ float2 sbuf[2][2][16];
  __shared__ float scl[32], shl[32];

  const int t = threadIdx.x;
  const int lane = t & 63, wave = t >> 6;
  const int ms = wave >> 1, ns = wave & 1;
  const int n15 = lane & 15, kq = lane >> 4;

  // XCD swizzle: XCD k owns b in [64k, 64k+64); all m-blocks of a b co-located
  int m0, b0;
  if constexpr (STAGE == 0) {
    int lin = blockIdx.y * 8 + blockIdx.x;       // 1024 blocks
    int xk = lin & 7, pos = lin >> 3;            // pos 0..127
    m0 = (pos & 7) * 32;
    b0 = (xk * 16 + (pos >> 3)) * 4;
  } else {
    int lin = blockIdx.y * 4 + blockIdx.x;       // 2048 blocks
    int xk = lin & 7, pos = lin >> 3;            // pos 0..255
    m0 = (pos & 3) * 32;
    b0 = xk * 64 + (pos >> 2);
  }

  int xrow[2];
#pragma unroll
  for (int ni = 0; ni < 2; ++ni) {
    if constexpr (STAGE == 0) xrow[ni] = (ns * 2 + ni) * 25 + (n15 >> 2) * 5 + (n15 & 3);
    else                      xrow[ni] = (2 * (ns * 2 + ni) + (n15 >> 3)) * 9 + (n15 & 7);
  }
  const int am = ms * 16 + n15;

  for (int i = t; i < XROWS * 32; i += 256) ((u32*)Xl)[i] = 0;

  f32x4 acc[2][4];
#pragma unroll
  for (int ni = 0; ni < 2; ++ni)
#pragma unroll
    for (int c = 0; c < 4; ++c) acc[ni][c] = f32x4{0.f, 0.f, 0.f, 0.f};

  for (int ch = 0; ch < NCH; ++ch) {
    const int c0 = ch * 64;
    __syncthreads();

#pragma unroll
    for (int it = 0; it < 9; ++it) {
      int idx = t + it * 256;
      int row = idx >> 3, jb = idx & 7;
      int tap = row >> 5, ml = row & 31;
      uint4 v = *(const uint4*)(wt + ((size_t)(tap * CO + m0 + ml)) * CI + c0 + jb * 8);
      *(uint4*)&Wl[(row << 6) + ((jb ^ (row & 7)) << 3)] = v;
    }

    if constexpr (STAGE == 0) {
      // stage X: px-major x0 -> pure coalesced uint4 copy into swizzled LDS
      for (int idx = t; idx < 64 * 8; idx += 256) {
        int pxl = idx >> 3, jb = idx & 7;
        int img = pxl >> 4, p = pxl & 15;
        int iy = p >> 2, ix = p & 3;
        uint4 q = *(const uint4*)(x + ((size_t)(b0 + img) * 16 + p) * 512 + c0 + jb * 8);
        int row = img * 25 + iy * 5 + ix;
        *(uint4*)&Xl[(row << 6) + ((jb ^ (row & 7)) << 3)] = q;
      }
    } else {
      // stage X: px-major x1 -> pure coalesced uint4 copy into swizzled LDS
      for (int idx = t; idx < 64 * 8; idx += 256) {
        int pxl = idx >> 3, jb = idx & 7;
        int py = pxl >> 3, px_ = pxl & 7;
        uint4 q = *(const uint4*)(x + ((size_t)b0 * 64 + pxl) * 256 + c0 + jb * 8);
        int row = py * 9 + px_;
        *(uint4*)&Xl[(row << 6) + ((jb ^ (row & 7)) << 3)] = q;
      }
    }
    __syncthreads();

#pragma unroll
    for (int s = 0; s < 2; ++s) {
      const int js = s * 4 + kq;
      short8 a[9];
#pragma unroll
      for (int tap = 0; tap < 9; ++tap) {
        int row = tap * 32 + am;
        a[tap] = *(const short8*)&Wl[(row << 6) + ((js ^ (row & 7)) << 3)];
      }
#pragma unroll
      for (int ni = 0; ni < 2; ++ni) {
        int r0 = xrow[ni], r1 = r0 + 1, r2 = r0 + WP, r3 = r0 + WP + 1;
        short8 b00 = *(const short8*)&Xl[(r0 << 6) + ((js ^ (r0 & 7)) << 3)];
        short8 b01 = *(const short8*)&Xl[(r1 << 6) + ((js ^ (r1 & 7)) << 3)];
        short8 b10 = *(const short8*)&Xl[(r2 << 6) + ((js ^ (r2 & 7)) << 3)];
        short8 b11 = *(const short8*)&Xl[(r3 << 6) + ((js ^ (r3 & 7)) << 3)];
        acc[ni][0] = __builtin_amdgcn_mfma_f32_16x16x32_bf16(a[4], b00, acc[ni][0], 0, 0, 0);
        acc[ni][1] = __builtin_amdgcn_mfma_f32_16x16x32_bf16(a[3], b00, acc[ni][1], 0, 0, 0);
        acc[ni][1] = __builtin_amdgcn_mfma_f32_16x16x32_bf16(a[5], b01, acc[ni][1], 0, 0, 0);
        acc[ni][2] = __builtin_amdgcn_mfma_f32_16x16x32_bf16(a[1], b00, acc[ni][2], 0, 0, 0);
        acc[ni][2] = __builtin_amdgcn_mfma_f32_16x16x32_bf16(a[7], b10, acc[ni][2], 0, 0, 0);
        acc[ni][3] = __builtin_amdgcn_mfma_f32_16x16x32_bf16(a[0], b00, acc[ni][3], 0, 0, 0);
        acc[ni][3] = __builtin_amdgcn_mfma_f32_16x16x32_bf16(a[2], b01, acc[ni][3], 0, 0, 0);
        acc[ni][3] = __builtin_amdgcn_mfma_f32_16x16x32_bf16(a[6], b10, acc[ni][3], 0, 0, 0);
        acc[ni][3] = __builtin_amdgcn_mfma_f32_16x16x32_bf16(a[8], b11, acc[ni][3], 0, 0, 0);
      }
    }
  }

  // ---- epilogue: bias + relu + next-GN normalize + store ----
  float bv[4];
#pragma unroll
  for (int r = 0; r < 4; ++r) bv[r] = bias[m0 + ms * 16 + kq * 4 + r];

  if constexpr (STAGE == 0) {
    float gw4[4], gb4[4];
#pragma unroll
    for (int r = 0; r < 4; ++r) {
      int m = m0 + ms * 16 + kq * 4 + r;
      gw4[r] = gwn[m]; gb4[r] = gbn[m];
    }
#pragma unroll
    for (int ni = 0; ni < 2; ++ni) {
      int b = b0 + ns * 2 + ni, iy = n15 >> 2, ix = n15 & 3;
      float val[4][4];
      float sr[4] = {0.f, 0.f, 0.f, 0.f}, sr2[4] = {0.f, 0.f, 0.f, 0.f};
#pragma unroll
      for (int cl = 0; cl < 4; ++cl)
#pragma unroll
        for (int r = 0; r < 4; ++r) {
          val[cl][r] = fmaxf(acc[ni][cl][r] + bv[r], 0.f);
          sr[r] += val[cl][r]; sr2[r] += val[cl][r] * val[cl][r];
        }
#pragma unroll
      for (int r = 0; r < 4; ++r) {
#pragma unroll
        for (int off = 1; off <= 8; off <<= 1) {
          sr[r]  += __shfl_xor(sr[r], off, 64);
          sr2[r] += __shfl_xor(sr2[r], off, 64);
        }
      }
      // full 64-px stats now in all lanes -> normalize in-lane, store normalized px-major
      float scv[4], shv[4];
#pragma unroll
      for (int r = 0; r < 4; ++r) {
        float mu = sr[r] * (1.f / 64.f);
        float var = fmaxf(sr2[r] * (1.f / 64.f) - mu * mu, 0.f);
        scv[r] = gw4[r] * rsqrtf(var + 1e-5f);
        shv[r] = gb4[r] - mu * scv[r];
      }
      // x1 layout [b][8x8 px][256 c]
#pragma unroll
      for (int cl = 0; cl < 4; ++cl) {
        int oy = 2 * iy + (cl >> 1), ox = 2 * ix + (cl & 1);
        size_t base = ((size_t)b * 64 + oy * 8 + ox) * 256 + m0 + ms * 16 + kq * 4;
        uint2 pk = {pack_bf16x2(val[cl][0] * scv[0] + shv[0],
                                val[cl][1] * scv[1] + shv[1]),
                    pack_bf16x2(val[cl][2] * scv[2] + shv[2],
                                val[cl][3] * scv[3] + shv[3])};
        *(uint2*)(y + base) = pk;
      }
    }
  } else {
    float sr[4] = {0.f, 0.f, 0.f, 0.f}, sr2[4] = {0.f, 0.f, 0.f, 0.f};
#pragma unroll
    for (int ni = 0; ni < 2; ++ni)
#pragma unroll
      for (int cl = 0; cl < 4; ++cl)
#pragma unroll
        for (int r = 0; r < 4; ++r) {
          float v = fmaxf(acc[ni][cl][r] + bv[r], 0.f);
          sr[r] += v; sr2[r] += v * v;
        }
#pragma unroll
    for (int r = 0; r < 4; ++r) {
#pragma unroll
      for (int off = 1; off <= 8; off <<= 1) {
        sr[r]  += __shfl_xor(sr[r], off, 64);
        sr2[r] += __shfl_xor(sr2[r], off, 64);
      }
    }
    __syncthreads();
    if (n15 == 0) {
#pragma unroll
      for (int r = 0; r < 4; ++r) sbuf[ms][ns][kq * 4 + r] = float2{sr[r], sr2[r]};
    }
    __syncthreads();
    if (t < 32) {
      int msx = t >> 4, i = t & 15;
      float2 p0 = sbuf[msx][0][i], p1 = sbuf[msx][1][i];
      float s = p0.x + p1.x, s2 = p0.y + p1.y;
      float mu = s * (1.f / 256.f);
      float var = fmaxf(s2 * (1.f / 256.f) - mu * mu, 0.f);
      int m = m0 + msx * 16 + i;
      float scale = gwn[m] * rsqrtf(var + 1e-5f);
      scl[t] = scale;
      shl[t] = gbn[m] - mu * scale;
    }
    __syncthreads();
    float scv[4], shv[4];
#pragma unroll
    for (int r = 0; r < 4; ++r) {
      scv[r] = scl[ms * 16 + kq * 4 + r];
      shv[r] = shl[ms * 16 + kq * 4 + r];
    }
    // x2 layout [b][256 px][128 c], stored pre-normalized
#pragma unroll
    for (int ni = 0; ni < 2; ++ni) {
      int iy = 2 * (ns * 2 + ni) + (n15 >> 3), ix = n15 & 7;
#pragma unroll
      for (int cl = 0; cl < 4; ++cl) {
        int opx = (2 * iy + (cl >> 1)) * 16 + 2 * ix + (cl & 1);
        size_t base = ((size_t)b0 * 256 + opx) * 128 + m0 + ms * 16 + kq * 4;
        float v0 = fmaxf(acc[ni][cl][0] + bv[0], 0.f) * scv[0] + shv[0];
        float v1 = fmaxf(acc[ni][cl][1] + bv[1], 0.f) * scv[1] + shv[1];
        float v2 = fmaxf(acc[ni][cl][2] + bv[2], 0.f) * scv[2] + shv[2];
        float v3 = fmaxf(acc[ni][cl][3] + bv[3], 0.f) * scv[3] + shv[3];
        *(u32*)(y + base)     = pack_bf16x2(v0, v1);
        *(u32*)(y + base + 2) = pack_bf16x2(v2, v3);
      }
    }
  }
}

// ---------------- stage-2 deconv: 4 n-tiles/wave, shared B rows; input pre-normalized ----------------
#define XRD(row) (*(const short8*)&Xl[((row) << 6) + (((js ^ ((row) & 7))) << 3)])
__global__ __launch_bounds__(256, 2)
void deconv2_q(const u16* __restrict__ x, const u16* __restrict__ wt,
               const float* __restrict__ bias, u16* __restrict__ y,
               float2* __restrict__ psum)
{
  __shared__ __align__(16) u16 Wl[288 * 64];
  __shared__ __align__(16) u16 Xl[153 * 64];  // row = rl*17 + ix, rl 0..8 (halo stays 0)
  __shared__ float2 sbuf[2][2][16];

  const int t = threadIdx.x;
  const int lane = t & 63, wave = t >> 6;
  const int ms = wave >> 1, ns = wave & 1;
  const int n15 = lane & 15, kq = lane >> 4;
  // XCD swizzle: XCD k owns b in [64k, 64k+64)
  const int lin = blockIdx.y * 4 + blockIdx.x;   // 2048 blocks
  const int xk = lin & 7, pos = lin >> 3;        // pos 0..255
  const int b   = xk * 64 + (pos >> 2);
  const int m0  = (pos & 1) * 32;
  const int qz2 = (pos >> 1) & 1;                // 0..1 (16 output rows each)

  for (int i = t; i < 153 * 32; i += 256) ((u32*)Xl)[i] = 0;

  const int am = ms * 16 + n15;
  const int xr0 = (ns * 4) * 17 + n15;

  f32x4 acc[4][4];
#pragma unroll
  for (int ni = 0; ni < 4; ++ni)
#pragma unroll
    for (int c = 0; c < 4; ++c) acc[ni][c] = f32x4{0.f, 0.f, 0.f, 0.f};

  const int NPX = (qz2 == 0) ? 144 : 128;     // input rows 0..8 / 8..15 (+zero halo)
  for (int ch = 0; ch < 2; ++ch) {
    const int c0 = ch * 64;
    __syncthreads();

    // ---- stage W: 288 rows (tap*32+ml) x 8 blocks ----
#pragma unroll
    for (int it = 0; it < 9; ++it) {
      int idx = t + it * 256;
      int row = idx >> 3, jb = idx & 7;
      int tap = row >> 5, ml = row & 31;
      uint4 v = *(const uint4*)(wt + ((size_t)(tap * 64 + m0 + ml)) * 128 + c0 + jb * 8);
      *(uint4*)&Wl[(row << 6) + ((jb ^ (row & 7)) << 3)] = v;
    }

    // ---- stage X: pure uint4 copy, coalesced -> swizzled b128 (input pre-normalized) ----
    for (int idx = t; idx < NPX * 8; idx += 256) {
      int pxl = idx >> 3, jb = idx & 7;
      int rl = pxl >> 4, ix = pxl & 15;
      int gpx = (8 * qz2 + rl) * 16 + ix;
      uint4 q = *(const uint4*)(x + ((size_t)b * 256 + gpx) * 128 + c0 + jb * 8);
      int row = rl * 17 + ix;
      *(uint4*)&Xl[(row << 6) + ((jb ^ (row & 7)) << 3)] = q;
    }
    __syncthreads();

#pragma unroll
    for (int s = 0; s < 2; ++s) {
      const int js = s * 4 + kq;
      short8 a[9];
#pragma unroll
      for (int tap = 0; tap < 9; ++tap) {
        int row = tap * 32 + am;
        a[tap] = *(const short8*)&Wl[(row << 6) + ((js ^ (row & 7)) << 3)];
      }
      // 10 B rows shared across the wave's 4 adjacent n-tiles
      short8 Brow[10];
#pragma unroll
      for (int k = 0; k < 5; ++k) {
        Brow[2 * k]     = XRD(xr0 + 17 * k);
        Brow[2 * k + 1] = XRD(xr0 + 17 * k + 1);
      }
      __builtin_amdgcn_s_setprio(1);
#pragma unroll
      for (int ni = 0; ni < 4; ++ni) {
        short8 b00 = Brow[2 * ni],     b01 = Brow[2 * ni + 1];
        short8 b10 = Brow[2 * ni + 2], b11 = Brow[2 * ni + 3];
        acc[ni][0] = __builtin_amdgcn_mfma_f32_16x16x32_bf16(a[4], b00, acc[ni][0], 0, 0, 0);
        acc[ni][1] = __builtin_amdgcn_mfma_f32_16x16x32_bf16(a[3], b00, acc[ni][1], 0, 0, 0);
        acc[ni][1] = __builtin_amdgcn_mfma_f32_16x16x32_bf16(a[5], b01, acc[ni][1], 0, 0, 0);
        acc[ni][2] = __builtin_amdgcn_mfma_f32_16x16x32_bf16(a[1], b00, acc[ni][2], 0, 0, 0);
        acc[ni][2] = __builtin_amdgcn_mfma_f32_16x16x32_bf16(a[7], b10, acc[ni][2], 0, 0, 0);
        acc[ni][3] = __builtin_amdgcn_mfma_f32_16x16x32_bf16(a[0], b00, acc[ni][3], 0, 0, 0);
        acc[ni][3] = __builtin_amdgcn_mfma_f32_16x16x32_bf16(a[2], b01, acc[ni][3], 0, 0, 0);
        acc[ni][3] = __builtin_amdgcn_mfma_f32_16x16x32_bf16(a[6], b10, acc[ni][3], 0, 0, 0);
        acc[ni][3] = __builtin_amdgcn_mfma_f32_16x16x32_bf16(a[8], b11, acc[ni][3], 0, 0, 0);
      }
      __builtin_amdgcn_s_setprio(0);
    }
  }

  // ---- epilogue: bias + relu + store + stat partials ----
  float bv[4];
#pragma unroll
  for (int r = 0; r < 4; ++r) bv[r] = bias[m0 + ms * 16 + kq * 4 + r];
  float sr[4] = {0.f, 0.f, 0.f, 0.f}, sr2[4] = {0.f, 0.f, 0.f, 0.f};
#pragma unroll
  for (int ni = 0; ni < 4; ++ni) {
    int iy = 8 * qz2 + ns * 4 + ni, ix = n15;
#pragma unroll
    for (int r = 0; r < 4; ++r) {
      int m = m0 + ms * 16 + kq * 4 + r;
      float v00 = fmaxf(acc[ni][0][r] + bv[r], 0.f);
      float v01 = fmaxf(acc[ni][1][r] + bv[r], 0.f);
      float v10 = fmaxf(acc[ni][2][r] + bv[r], 0.f);
      float v11 = fmaxf(acc[ni][3][r] + bv[r], 0.f);
      size_t base = ((size_t)b * 64 + m) * 1024 + (size_t)(2 * iy) * 32 + 2 * ix;
      *(u32*)(y + base)      = pack_bf16x2(v00, v01);
      *(u32*)(y + base + 32) = pack_bf16x2(v10, v11);
      sr[r]  += v00 + v01 + v10 + v11;
      sr2[r] += v00 * v00 + v01 * v01 + v10 * v10 + v11 * v11;
    }
  }
#pragma unroll
  for (int r = 0; r < 4; ++r) {
#pragma unroll
    for (int off = 1; off <= 8; off <<= 1) {
      sr[r]  += __shfl_xor(sr[r], off, 64);
      sr2[r] += __shfl_xor(sr2[r], off, 64);
    }
  }
  __syncthreads();
  if (n15 == 0) {
#pragma unroll
    for (int r = 0; r < 4; ++r) sbuf[ms][ns][kq * 4 + r] = float2{sr[r], sr2[r]};
  }
  __syncthreads();
  if (t < 32) {
    int msx = t >> 4, i = t & 15;
    float2 p0 = sbuf[msx][0][i], p1 = sbuf[msx][1][i];
    int m = m0 + msx * 16 + i;
    psum[((size_t)b * 64 + m) * 2 + qz2] = float2{p0.x + p1.x, p0.y + p1.y};
  }
}

// ---------------- block reductions ----------------
DI float breduce_sum(float v, float* buf) {
#pragma unroll
  for (int off = 32; off; off >>= 1) v += __shfl_xor(v, off, 64);
  if ((threadIdx.x & 63) == 0) buf[threadIdx.x >> 6] = v;
  __syncthreads();
  float r = (buf[0] + buf[1]) + (buf[2] + buf[3]);
  __syncthreads();
  return r;
}
DI float breduce_max(float v, float* buf) {
#pragma unroll
  for (int off = 32; off; off >>= 1) v = fmaxf(v, __shfl_xor(v, off, 64));
  if ((threadIdx.x & 63) == 0) buf[threadIdx.x >> 6] = v;
  __syncthreads();
  float r = fmaxf(fmaxf(buf[0], buf[1]), fmaxf(buf[2], buf[3]));
  __syncthreads();
  return r;
}

// ---------------- head: fold stat partials -> norm -> 1x1 conv -> spatial softmax ----------------
__global__ __launch_bounds__(256)
void head_kernel(const u16* __restrict__ x3, const float2* __restrict__ psum,
                 const int* __restrict__ action, const float* __restrict__ hgw,
                 const float* __restrict__ hcw, float* __restrict__ out)
{
  constexpr int C = 64, S = 5, P = 1024;
  const int t = threadIdx.x;
  const int b = (blockIdx.x & 7) * 64 + (blockIdx.x >> 3);   // XCD-consistent b mapping
  const int a = action[b];
  __shared__ float weff[S * C];
  __shared__ float sc_l[C], sh_l[C];
  __shared__ float rbuf[4];
  if (t < C) {
    float2 p0 = psum[((size_t)b * C + t) * 2 + 0];
    float2 p1 = psum[((size_t)b * C + t) * 2 + 1];
    float s = p0.x + p1.x, s2 = p0.y + p1.y;
    float mu = s * (1.f / 1024.f);
    float var = fmaxf(s2 * (1.f / 1024.f) - mu * mu, 0.f);
    float rstd = rsqrtf(var + 1e-5f);
    sc_l[t] = rstd; sh_l[t] = -mu * rstd;
  }
  for (int j = t; j < S * C; j += 256) {
    int s = j >> 6, c = j & 63;
    weff[j] = hcw[(a * S + s) * C + c] * hgw[a * C + c];
  }
  __syncthreads();

  float L[S][4];
#pragma unroll
  for (int s = 0; s < S; ++s)
#pragma unroll
    for (int k = 0; k < 4; ++k) L[s][k] = 0.f;

  const u32* xb = (const u32*)(x3 + (size_t)b * C * P);
  for (int c = 0; c < C; ++c) {
    float scv = sc_l[c], shv = sh_l[c];
    u32 u0 = xb[c * 512 + t];
    u32 u1 = xb[c * 512 + t + 256];
    float xv[4] = {bflo(u0) * scv + shv, bfhi(u0) * scv + shv,
                   bflo(u1) * scv + shv, bfhi(u1) * scv + shv};
#pragma unroll
    for (int s = 0; s < S; ++s) {
      float wv = weff[s * C + c];
#pragma unroll
      for (int k = 0; k < 4; ++k) L[s][k] += xv[k] * wv;
    }
  }

#pragma unroll
  for (int s = 0; s < S; ++s) {
    float m = fmaxf(fmaxf(L[s][0], L[s][1]), fmaxf(L[s][2], L[s][3]));
    m = breduce_max(m, rbuf);
    float se = 0.f, sx = 0.f, sy = 0.f;
    const int pix[4] = {2 * t, 2 * t + 1, 512 + 2 * t, 512 + 2 * t + 1};
#pragma unroll
    for (int k = 0; k < 4; ++k) {
      int p = pix[k];
      float e = __expf(L[s][k] - m);
      se += e;
      sx += e * ((float)(p & 31) * (2.f / 31.f) - 1.f);
      sy += e * ((float)(p >> 5) * (2.f / 31.f) - 1.f);
    }
    se = breduce_sum(se, rbuf);
    sx = breduce_sum(sx, rbuf);
    sy = breduce_sum(sy, rbuf);
    if (t == 0) {
      out[(b * S + s) * 2 + 0] = sx / se;
      out[(b * S + s) * 2 + 1] = sy / se;
    }
  }
}

// ---------------- launcher ----------------
extern "C" void kernel_launch(void* const* d_in, const int* in_sizes, int n_in,
                              void* d_out, int out_size, void* d_ws, size_t ws_size,
                              hipStream_t stream)
{
  (void)in_sizes; (void)n_in; (void)out_size; (void)ws_size;
  const float* feat   = (const float*)d_in[0];
  const int*   action = (const int*)d_in[1];
  const float* fc_w = (const float*)d_in[3];
  const float* fc_b = (const float*)d_in[4];
  const float* gw0  = (const float*)d_in[5];
  const float* gb0  = (const float*)d_in[6];
  const float* dw0  = (const float*)d_in[7];
  const float* db0  = (const float*)d_in[8];
  const float* gw1  = (const float*)d_in[9];
  const float* gb1  = (const float*)d_in[10];
  const float* dw1  = (const float*)d_in[11];
  const float* db1  = (const float*)d_in[12];
  const float* gw2  = (const float*)d_in[13];
  const float* gb2  = (const float*)d_in[14];
  const float* dw2  = (const float*)d_in[15];
  const float* db2  = (const float*)d_in[16];
  const float* hgw  = (const float*)d_in[17];
  const float* hcw  = (const float*)d_in[19];

  float* ws = (float*)d_ws;
  u16* x0 = (u16*)(ws + OFF_REGB);
  u16* x2 = (u16*)(ws + OFF_REGB);
  u16* x1 = (u16*)(ws + OFF_REGA);
  u16* x3 = (u16*)(ws + OFF_REGA);
  u16* wt0 = (u16*)(ws + OFF_WT0);
  u16* wt1 = (u16*)(ws + OFF_WT1);
  u16* wt2 = (u16*)(ws + OFF_WT2);
  u16* wtf = (u16*)(ws + OFF_WTF);
  float2* psum = (float2*)(ws + O_PSUM);

  wtrans_all<<<1184, 256, 0, stream>>>(dw0, dw1, dw2, fc_w, wt0, wt1, wt2, wtf);
  fc_mfma<<<dim3(8, 64), 256, 0, stream>>>(feat, wtf, fc_b, gw0, gb0, x0);
  deconv_mfma<0><<<dim3(8, 128), 256, 0, stream>>>(x0, wt0, db0, x1, gw1, gb1);
  deconv_mfma<1><<<dim3(4, 512), 256, 0, stream>>>(x1, wt1, db1, x2, gw2, gb2);
  deconv2_q<<<dim3(4, 512), 256, 0, stream>>>(x2, wt2, db2, x3, psum);
  head_kernel<<<512, 256, 0, stream>>>(x3, psum, action, hgw, hcw, (float*)d_out);
}

// Round 13
// 240.926 us; speedup vs baseline: 1.9435x; 1.0345x over previous
//
#include <hip/hip_runtime.h>
#include <hip/hip_bf16.h>

#define DI __device__ __forceinline__
using u16 = unsigned short;
using u32 = unsigned int;

typedef short short8 __attribute__((ext_vector_type(8)));   // 8 bf16 (4 VGPRs)
typedef float f32x4 __attribute__((ext_vector_type(4)));

#define F4C(v, i) ((i) == 0 ? (v).x : (i) == 1 ? (v).y : (i) == 2 ? (v).z : (v).w)

DI float bflo(u32 u) { return __uint_as_float(u << 16); }
DI float bfhi(u32 u) { return __uint_as_float(u & 0xffff0000u); }
DI u16 f2bf(float a) {
  u32 xu = __float_as_uint(a);
  return (u16)((xu + 0x7fffu + ((xu >> 16) & 1)) >> 16);
}
DI u32 pack_bf16x2(float a, float b) {
  u32 xu = __float_as_uint(a), yu = __float_as_uint(b);
  xu = (xu + 0x7fffu + ((xu >> 16) & 1)) >> 16;
  yu = (yu + 0x7fffu + ((yu >> 16) & 1)) >> 16;
  return (xu & 0xffffu) | (yu << 16);
}

// ---------------- workspace layout (float units) ----------------
static constexpr size_t OFF_REGB = 0;
static constexpr size_t OFF_REGA = 16777216;
static constexpr size_t OFF_WT0  = 33554432;
static constexpr size_t OFF_WT1  = OFF_WT0 + 1179648;
static constexpr size_t OFF_WT2  = OFF_WT1 + 294912;
static constexpr size_t OFF_WTF  = OFF_WT2 + 73728;
static constexpr size_t OFF_ST   = 35200000;
static constexpr size_t O_PSUM = OFF_ST + 1048576;   // 512*64*2 float2 = 131072 floats

// ---------------- all weight pre-transposes in one launch ----------------
__global__ __launch_bounds__(256)
void wtrans_all(const float* __restrict__ dw0, const float* __restrict__ dw1,
                const float* __restrict__ dw2, const float* __restrict__ fcw,
                u16* __restrict__ wt0, u16* __restrict__ wt1,
                u16* __restrict__ wt2, u16* __restrict__ wtf)
{
  int id = blockIdx.x * 256 + threadIdx.x;
  if (id < 131072) {                       // dw0: CO=256, CI=512
    int m = id >> 9, c = id & 511;
    const float* src = dw0 + ((size_t)m * 512 + c) * 9;
#pragma unroll
    for (int tap = 0; tap < 9; ++tap)
      wt0[((size_t)tap * 256 + m) * 512 + c] = f2bf(src[tap]);
  } else if (id < 163840) {                // dw1: CO=128, CI=256
    int j = id - 131072;
    int m = j >> 8, c = j & 255;
    const float* src = dw1 + ((size_t)m * 256 + c) * 9;
#pragma unroll
    for (int tap = 0; tap < 9; ++tap)
      wt1[((size_t)tap * 128 + m) * 256 + c] = f2bf(src[tap]);
  } else if (id < 172032) {                // dw2: CO=64, CI=128
    int j = id - 163840;
    int m = j >> 7, c = j & 127;
    const float* src = dw2 + ((size_t)m * 128 + c) * 9;
#pragma unroll
    for (int tap = 0; tap < 9; ++tap)
      wt2[((size_t)tap * 64 + m) * 128 + c] = f2bf(src[tap]);
  } else {                                 // fc: wtf[d][c]
    int j = id - 172032;
    int d = j >> 8, c = j & 255;
    wtf[j] = f2bf(fcw[c * 512 + d]);
  }
}

// ---------------- fc1 via MFMA; GN0 applied in epilogue; x0 stored px-major ----------------
DI void fc_stage_A(const float* __restrict__ feat, int b, u16* Ab, int t)
{
#pragma unroll
  for (int it = 0; it < 2; ++it) {
    int idx = t + it * 256;
    int cp = idx >> 2, hw4 = idx & 3;
    int c = cp * 2;
    const float* xp = feat + ((size_t)b * 256 + c) * 16 + hw4 * 4;
    float4 v0 = *(const float4*)xp;
    float4 v1 = *(const float4*)(xp + 16);
    int c64 = c >> 6, jb = (c & 63) >> 3;
#pragma unroll
    for (int j = 0; j < 4; ++j) {
      int hw = hw4 * 4 + j;
      int row = c64 * 16 + hw;
      *(u32*)&Ab[(row << 6) + ((jb ^ (row & 7)) << 3) + (c & 7)] =
          pack_bf16x2(F4C(v0, j), F4C(v1, j));
    }
  }
}

__global__ __launch_bounds__(256, 3)
void fc_mfma(const float* __restrict__ feat, const u16* __restrict__ wtf,
             const float* __restrict__ fb, const float* __restrict__ gw,
             const float* __restrict__ gb, u16* __restrict__ x0)
{
  __shared__ __align__(16) u16 Wl[256 * 64];
  __shared__ __align__(16) u16 Al[2][64 * 64];
  const int t = threadIdx.x;
  const int lane = t & 63, wave = t >> 6;
  const int n15 = lane & 15, kq = lane >> 4;
  // XCD swizzle: XCD k owns b in [64k, 64k+64); 8 d-blocks of same b-group co-located
  const int lin = blockIdx.y * 8 + blockIdx.x;
  const int xk = lin & 7, pos = lin >> 3;          // pos 0..63
  const int d0 = (pos & 7) * 64;
  const int b0 = (xk * 8 + (pos >> 3)) * 8;

#pragma unroll
  for (int it = 0; it < 8; ++it) {
    int idx = t + it * 256;
    int dl = idx >> 5, jb32 = idx & 31;
    int row = (jb32 >> 3) * 64 + dl, jb = jb32 & 7;
    uint4 v = *(const uint4*)(wtf + (size_t)(d0 + dl) * 256 + jb32 * 8);
    *(uint4*)&Wl[(row << 6) + ((jb ^ (row & 7)) << 3)] = v;
  }
  fc_stage_A(feat, b0, Al[0], t);

  const int dg = d0 + wave * 16 + n15;
  const float bvn = fb[dg];
  const float gwv = gw[dg], gbv = gb[dg];

  for (int bi = 0; bi < 8; ++bi) {
    __syncthreads();
    if (bi + 1 < 8) fc_stage_A(feat, b0 + bi + 1, Al[(bi + 1) & 1], t);

    const u16* A = Al[bi & 1];
    f32x4 acc0 = {0.f, 0.f, 0.f, 0.f}, acc1 = {0.f, 0.f, 0.f, 0.f};
#pragma unroll
    for (int ks = 0; ks < 8; ++ks) {
      int js = ks * 4 + kq;
      int ra = (js >> 3) * 16 + n15;
      int rb = (js >> 3) * 64 + wave * 16 + n15;
      short8 av = *(const short8*)&A[(ra << 6) + (((js & 7) ^ (ra & 7)) << 3)];
      short8 bv = *(const short8*)&Wl[(rb << 6) + (((js & 7) ^ (rb & 7)) << 3)];
      if (ks & 1) acc1 = __builtin_amdgcn_mfma_f32_16x16x32_bf16(av, bv, acc1, 0, 0, 0);
      else        acc0 = __builtin_amdgcn_mfma_f32_16x16x32_bf16(av, bv, acc0, 0, 0, 0);
    }

    int b = b0 + bi;
    float v[4], s = 0.f, s2 = 0.f;
#pragma unroll
    for (int r = 0; r < 4; ++r) {
      v[r] = fmaxf(acc0[r] + acc1[r] + bvn, 0.f);
      s += v[r]; s2 += v[r] * v[r];
    }
    s  += __shfl_xor(s, 16, 64);  s  += __shfl_xor(s, 32, 64);
    s2 += __shfl_xor(s2, 16, 64); s2 += __shfl_xor(s2, 32, 64);
    // GN0 applied here: every lane has full 16-px sums after the butterfly.
    float mu = s * (1.f / 16.f);
    float var = fmaxf(s2 * (1.f / 16.f) - mu * mu, 0.f);
    float scale = gwv * rsqrtf(var + 1e-5f);
    float shift = gbv - mu * scale;
    // x0 layout px-major [b][16 px][512 d]; lane's 4 values are px kq*4+r, channel dg
    u16* yp = x0 + ((size_t)b * 16 + kq * 4) * 512 + dg;
#pragma unroll
    for (int r = 0; r < 4; ++r) yp[(size_t)r * 512] = f2bf(v[r] * scale + shift);
  }
}

// ---------------- deconv stages 0/1: inputs pre-normalized px-major; pure-copy stage-X
// STAGE 0: reads x0 px-major [b][16px][512c], writes x1 px-major [b][64px][256c].
// STAGE 1: reads x1 px-major, writes x2 px-major [b][256px][128c].
template<int STAGE>
__global__ __launch_bounds__(256, 3)
void deconv_mfma(const u16* __restrict__ x, const u16* __restrict__ wt,
                 const float* __restrict__ bias, u16* __restrict__ y,
                 const float* __restrict__ gwn, const float* __restrict__ gbn)
{
  constexpr int CI  = STAGE == 0 ? 512 : 256;
  constexpr int CO  = CI / 2;
  constexpr int H   = STAGE == 0 ? 4 : 8;
  constexpr int WP  = H + 1;
  constexpr int XROWS = STAGE == 0 ? 100 : 81;
  constexpr int NCH = CI / 64;
  __shared__ __align__(16) u16 Wl[288 * 64];
  __shared__ __align__(16) u16 Xl[XROWS * 64];
  __shared__ float2 sbuf[2][2][16];
  __shared__ float scl[32], shl[32];

  const int t = threadIdx.x;
  const int lane = t & 63, wave = t >> 6;
  const int ms = wave >> 1, ns = wave & 1;
  const int n15 = lane & 15, kq = lane >> 4;

  // XCD swizzle: XCD k owns b in [64k, 64k+64); all m-blocks of a b co-located
  int m0, b0;
  if constexpr (STAGE == 0) {
    int lin = blockIdx.y * 8 + blockIdx.x;       // 1024 blocks
    int xk = lin & 7, pos = lin >> 3;            // pos 0..127
    m0 = (pos & 7) * 32;
    b0 = (xk * 16 + (pos >> 3)) * 4;
  } else {
    int lin = blockIdx.y * 4 + blockIdx.x;       // 2048 blocks
    int xk = lin & 7, pos = lin >> 3;            // pos 0..255
    m0 = (pos & 3) * 32;
    b0 = xk * 64 + (pos >> 2);
  }

  int xrow[2];
#pragma unroll
  for (int ni = 0; ni < 2; ++ni) {
    if constexpr (STAGE == 0) xrow[ni] = (ns * 2 + ni) * 25 + (n15 >> 2) * 5 + (n15 & 3);
    else                      xrow[ni] = (2 * (ns * 2 + ni) + (n15 >> 3)) * 9 + (n15 & 7);
  }
  const int am = ms * 16 + n15;

  for (int i = t; i < XROWS * 32; i += 256) ((u32*)Xl)[i] = 0;

  f32x4 acc[2][4];
#pragma unroll
  for (int ni = 0; ni < 2; ++ni)
#pragma unroll
    for (int c = 0; c < 4; ++c) acc[ni][c] = f32x4{0.f, 0.f, 0.f, 0.f};

  for (int ch = 0; ch < NCH; ++ch) {
    const int c0 = ch * 64;
    __syncthreads();

#pragma unroll
    for (int it = 0; it < 9; ++it) {
      int idx = t + it * 256;
      int row = idx >> 3, jb = idx & 7;
      int tap = row >> 5, ml = row & 31;
      uint4 v = *(const uint4*)(wt + ((size_t)(tap * CO + m0 + ml)) * CI + c0 + jb * 8);
      *(uint4*)&Wl[(row << 6) + ((jb ^ (row & 7)) << 3)] = v;
    }

    if constexpr (STAGE == 0) {
      // stage X: px-major x0 -> pure coalesced uint4 copy into swizzled LDS
      for (int idx = t; idx < 64 * 8; idx += 256) {
        int pxl = idx >> 3, jb = idx & 7;
        int img = pxl >> 4, p = pxl & 15;
        int iy = p >> 2, ix = p & 3;
        uint4 q = *(const uint4*)(x + ((size_t)(b0 + img) * 16 + p) * 512 + c0 + jb * 8);
        int row = img * 25 + iy * 5 + ix;
        *(uint4*)&Xl[(row << 6) + ((jb ^ (row & 7)) << 3)] = q;
      }
    } else {
      // stage X: px-major x1 -> pure coalesced uint4 copy into swizzled LDS
      for (int idx = t; idx < 64 * 8; idx += 256) {
        int pxl = idx >> 3, jb = idx & 7;
        int py = pxl >> 3, px_ = pxl & 7;
        uint4 q = *(const uint4*)(x + ((size_t)b0 * 64 + pxl) * 256 + c0 + jb * 8);
        int row = py * 9 + px_;
        *(uint4*)&Xl[(row << 6) + ((jb ^ (row & 7)) << 3)] = q;
      }
    }
    __syncthreads();

#pragma unroll
    for (int s = 0; s < 2; ++s) {
      const int js = s * 4 + kq;
      short8 a[9];
#pragma unroll
      for (int tap = 0; tap < 9; ++tap) {
        int row = tap * 32 + am;
        a[tap] = *(const short8*)&Wl[(row << 6) + ((js ^ (row & 7)) << 3)];
      }
#pragma unroll
      for (int ni = 0; ni < 2; ++ni) {
        int r0 = xrow[ni], r1 = r0 + 1, r2 = r0 + WP, r3 = r0 + WP + 1;
        short8 b00 = *(const short8*)&Xl[(r0 << 6) + ((js ^ (r0 & 7)) << 3)];
        short8 b01 = *(const short8*)&Xl[(r1 << 6) + ((js ^ (r1 & 7)) << 3)];
        short8 b10 = *(const short8*)&Xl[(r2 << 6) + ((js ^ (r2 & 7)) << 3)];
        short8 b11 = *(const short8*)&Xl[(r3 << 6) + ((js ^ (r3 & 7)) << 3)];
        acc[ni][0] = __builtin_amdgcn_mfma_f32_16x16x32_bf16(a[4], b00, acc[ni][0], 0, 0, 0);
        acc[ni][1] = __builtin_amdgcn_mfma_f32_16x16x32_bf16(a[3], b00, acc[ni][1], 0, 0, 0);
        acc[ni][1] = __builtin_amdgcn_mfma_f32_16x16x32_bf16(a[5], b01, acc[ni][1], 0, 0, 0);
        acc[ni][2] = __builtin_amdgcn_mfma_f32_16x16x32_bf16(a[1], b00, acc[ni][2], 0, 0, 0);
        acc[ni][2] = __builtin_amdgcn_mfma_f32_16x16x32_bf16(a[7], b10, acc[ni][2], 0, 0, 0);
        acc[ni][3] = __builtin_amdgcn_mfma_f32_16x16x32_bf16(a[0], b00, acc[ni][3], 0, 0, 0);
        acc[ni][3] = __builtin_amdgcn_mfma_f32_16x16x32_bf16(a[2], b01, acc[ni][3], 0, 0, 0);
        acc[ni][3] = __builtin_amdgcn_mfma_f32_16x16x32_bf16(a[6], b10, acc[ni][3], 0, 0, 0);
        acc[ni][3] = __builtin_amdgcn_mfma_f32_16x16x32_bf16(a[8], b11, acc[ni][3], 0, 0, 0);
      }
    }
  }

  // ---- epilogue: bias + relu + next-GN normalize + store ----
  float bv[4];
#pragma unroll
  for (int r = 0; r < 4; ++r) bv[r] = bias[m0 + ms * 16 + kq * 4 + r];

  if constexpr (STAGE == 0) {
    float gw4[4], gb4[4];
#pragma unroll
    for (int r = 0; r < 4; ++r) {
      int m = m0 + ms * 16 + kq * 4 + r;
      gw4[r] = gwn[m]; gb4[r] = gbn[m];
    }
#pragma unroll
    for (int ni = 0; ni < 2; ++ni) {
      int b = b0 + ns * 2 + ni, iy = n15 >> 2, ix = n15 & 3;
      float val[4][4];
      float sr[4] = {0.f, 0.f, 0.f, 0.f}, sr2[4] = {0.f, 0.f, 0.f, 0.f};
#pragma unroll
      for (int cl = 0; cl < 4; ++cl)
#pragma unroll
        for (int r = 0; r < 4; ++r) {
          val[cl][r] = fmaxf(acc[ni][cl][r] + bv[r], 0.f);
          sr[r] += val[cl][r]; sr2[r] += val[cl][r] * val[cl][r];
        }
#pragma unroll
      for (int r = 0; r < 4; ++r) {
#pragma unroll
        for (int off = 1; off <= 8; off <<= 1) {
          sr[r]  += __shfl_xor(sr[r], off, 64);
          sr2[r] += __shfl_xor(sr2[r], off, 64);
        }
      }
      // full 64-px stats now in all lanes -> normalize in-lane, store normalized px-major
      float scv[4], shv[4];
#pragma unroll
      for (int r = 0; r < 4; ++r) {
        float mu = sr[r] * (1.f / 64.f);
        float var = fmaxf(sr2[r] * (1.f / 64.f) - mu * mu, 0.f);
        scv[r] = gw4[r] * rsqrtf(var + 1e-5f);
        shv[r] = gb4[r] - mu * scv[r];
      }
      // x1 layout [b][8x8 px][256 c]
#pragma unroll
      for (int cl = 0; cl < 4; ++cl) {
        int oy = 2 * iy + (cl >> 1), ox = 2 * ix + (cl & 1);
        size_t base = ((size_t)b * 64 + oy * 8 + ox) * 256 + m0 + ms * 16 + kq * 4;
        uint2 pk = {pack_bf16x2(val[cl][0] * scv[0] + shv[0],
                                val[cl][1] * scv[1] + shv[1]),
                    pack_bf16x2(val[cl][2] * scv[2] + shv[2],
                                val[cl][3] * scv[3] + shv[3])};
        *(uint2*)(y + base) = pk;
      }
    }
  } else {
    float sr[4] = {0.f, 0.f, 0.f, 0.f}, sr2[4] = {0.f, 0.f, 0.f, 0.f};
#pragma unroll
    for (int ni = 0; ni < 2; ++ni)
#pragma unroll
      for (int cl = 0; cl < 4; ++cl)
#pragma unroll
        for (int r = 0; r < 4; ++r) {
          float v = fmaxf(acc[ni][cl][r] + bv[r], 0.f);
          sr[r] += v; sr2[r] += v * v;
        }
#pragma unroll
    for (int r = 0; r < 4; ++r) {
#pragma unroll
      for (int off = 1; off <= 8; off <<= 1) {
        sr[r]  += __shfl_xor(sr[r], off, 64);
        sr2[r] += __shfl_xor(sr2[r], off, 64);
      }
    }
    __syncthreads();
    if (n15 == 0) {
#pragma unroll
      for (int r = 0; r < 4; ++r) sbuf[ms][ns][kq * 4 + r] = float2{sr[r], sr2[r]};
    }
    __syncthreads();
    if (t < 32) {
      int msx = t >> 4, i = t & 15;
      float2 p0 = sbuf[msx][0][i], p1 = sbuf[msx][1][i];
      float s = p0.x + p1.x, s2 = p0.y + p1.y;
      float mu = s * (1.f / 256.f);
      float var = fmaxf(s2 * (1.f / 256.f) - mu * mu, 0.f);
      int m = m0 + msx * 16 + i;
      float scale = gwn[m] * rsqrtf(var + 1e-5f);
      scl[t] = scale;
      shl[t] = gbn[m] - mu * scale;
    }
    __syncthreads();
    float scv[4], shv[4];
#pragma unroll
    for (int r = 0; r < 4; ++r) {
      scv[r] = scl[ms * 16 + kq * 4 + r];
      shv[r] = shl[ms * 16 + kq * 4 + r];
    }
    // x2 layout [b][256 px][128 c], stored pre-normalized
#pragma unroll
    for (int ni = 0; ni < 2; ++ni) {
      int iy = 2 * (ns * 2 + ni) + (n15 >> 3), ix = n15 & 7;
#pragma unroll
      for (int cl = 0; cl < 4; ++cl) {
        int opx = (2 * iy + (cl >> 1)) * 16 + 2 * ix + (cl & 1);
        size_t base = ((size_t)b0 * 256 + opx) * 128 + m0 + ms * 16 + kq * 4;
        float v0 = fmaxf(acc[ni][cl][0] + bv[0], 0.f) * scv[0] + shv[0];
        float v1 = fmaxf(acc[ni][cl][1] + bv[1], 0.f) * scv[1] + shv[1];
        float v2 = fmaxf(acc[ni][cl][2] + bv[2], 0.f) * scv[2] + shv[2];
        float v3 = fmaxf(acc[ni][cl][3] + bv[3], 0.f) * scv[3] + shv[3];
        *(u32*)(y + base)     = pack_bf16x2(v0, v1);
        *(u32*)(y + base + 2) = pack_bf16x2(v2, v3);
      }
    }
  }
}

// ---------------- stage-2 deconv: 4 n-tiles/wave, shared B rows; input pre-normalized ----------------
#define XRD(row) (*(const short8*)&Xl[((row) << 6) + (((js ^ ((row) & 7))) << 3)])
__global__ __launch_bounds__(256, 2)
void deconv2_q(const u16* __restrict__ x, const u16* __restrict__ wt,
               const float* __restrict__ bias, u16* __restrict__ y,
               float2* __restrict__ psum)
{
  __shared__ __align__(16) u16 Wl[288 * 64];
  __shared__ __align__(16) u16 Xl[153 * 64];  // row = rl*17 + ix, rl 0..8 (halo stays 0)
  __shared__ float2 sbuf[2][2][16];

  const int t = threadIdx.x;
  const int lane = t & 63, wave = t >> 6;
  const int ms = wave >> 1, ns = wave & 1;
  const int n15 = lane & 15, kq = lane >> 4;
  // XCD swizzle: XCD k owns b in [64k, 64k+64)
  const int lin = blockIdx.y * 4 + blockIdx.x;   // 2048 blocks
  const int xk = lin & 7, pos = lin >> 3;        // pos 0..255
  const int b   = xk * 64 + (pos >> 2);
  const int m0  = (pos & 1) * 32;
  const int qz2 = (pos >> 1) & 1;                // 0..1 (16 output rows each)

  for (int i = t; i < 153 * 32; i += 256) ((u32*)Xl)[i] = 0;

  const int am = ms * 16 + n15;
  const int xr0 = (ns * 4) * 17 + n15;

  f32x4 acc[4][4];
#pragma unroll
  for (int ni = 0; ni < 4; ++ni)
#pragma unroll
    for (int c = 0; c < 4; ++c) acc[ni][c] = f32x4{0.f, 0.f, 0.f, 0.f};

  const int NPX = (qz2 == 0) ? 144 : 128;     // input rows 0..8 / 8..15 (+zero halo)
  for (int ch = 0; ch < 2; ++ch) {
    const int c0 = ch * 64;
    __syncthreads();

    // ---- stage W: 288 rows (tap*32+ml) x 8 blocks ----
#pragma unroll
    for (int it = 0; it < 9; ++it) {
      int idx = t + it * 256;
      int row = idx >> 3, jb = idx & 7;
      int tap = row >> 5, ml = row & 31;
      uint4 v = *(const uint4*)(wt + ((size_t)(tap * 64 + m0 + ml)) * 128 + c0 + jb * 8);
      *(uint4*)&Wl[(row << 6) + ((jb ^ (row & 7)) << 3)] = v;
    }

    // ---- stage X: pure uint4 copy, coalesced -> swizzled b128 (input pre-normalized) ----
    for (int idx = t; idx < NPX * 8; idx += 256) {
      int pxl = idx >> 3, jb = idx & 7;
      int rl = pxl >> 4, ix = pxl & 15;
      int gpx = (8 * qz2 + rl) * 16 + ix;
      uint4 q = *(const uint4*)(x + ((size_t)b * 256 + gpx) * 128 + c0 + jb * 8);
      int row = rl * 17 + ix;
      *(uint4*)&Xl[(row << 6) + ((jb ^ (row & 7)) << 3)] = q;
    }
    __syncthreads();

#pragma unroll
    for (int s = 0; s < 2; ++s) {
      const int js = s * 4 + kq;
      short8 a[9];
#pragma unroll
      for (int tap = 0; tap < 9; ++tap) {
        int row = tap * 32 + am;
        a[tap] = *(const short8*)&Wl[(row << 6) + ((js ^ (row & 7)) << 3)];
      }
      // 10 B rows shared across the wave's 4 adjacent n-tiles
      short8 Brow[10];
#pragma unroll
      for (int k = 0; k < 5; ++k) {
        Brow[2 * k]     = XRD(xr0 + 17 * k);
        Brow[2 * k + 1] = XRD(xr0 + 17 * k + 1);
      }
      __builtin_amdgcn_s_setprio(1);
#pragma unroll
      for (int ni = 0; ni < 4; ++ni) {
        short8 b00 = Brow[2 * ni],     b01 = Brow[2 * ni + 1];
        short8 b10 = Brow[2 * ni + 2], b11 = Brow[2 * ni + 3];
        acc[ni][0] = __builtin_amdgcn_mfma_f32_16x16x32_bf16(a[4], b00, acc[ni][0], 0, 0, 0);
        acc[ni][1] = __builtin_amdgcn_mfma_f32_16x16x32_bf16(a[3], b00, acc[ni][1], 0, 0, 0);
        acc[ni][1] = __builtin_amdgcn_mfma_f32_16x16x32_bf16(a[5], b01, acc[ni][1], 0, 0, 0);
        acc[ni][2] = __builtin_amdgcn_mfma_f32_16x16x32_bf16(a[1], b00, acc[ni][2], 0, 0, 0);
        acc[ni][2] = __builtin_amdgcn_mfma_f32_16x16x32_bf16(a[7], b10, acc[ni][2], 0, 0, 0);
        acc[ni][3] = __builtin_amdgcn_mfma_f32_16x16x32_bf16(a[0], b00, acc[ni][3], 0, 0, 0);
        acc[ni][3] = __builtin_amdgcn_mfma_f32_16x16x32_bf16(a[2], b01, acc[ni][3], 0, 0, 0);
        acc[ni][3] = __builtin_amdgcn_mfma_f32_16x16x32_bf16(a[6], b10, acc[ni][3], 0, 0, 0);
        acc[ni][3] = __builtin_amdgcn_mfma_f32_16x16x32_bf16(a[8], b11, acc[ni][3], 0, 0, 0);
      }
      __builtin_amdgcn_s_setprio(0);
    }
  }

  // ---- epilogue: bias + relu + store + stat partials ----
  float bv[4];
#pragma unroll
  for (int r = 0; r < 4; ++r) bv[r] = bias[m0 + ms * 16 + kq * 4 + r];
  float sr[4] = {0.f, 0.f, 0.f, 0.f}, sr2[4] = {0.f, 0.f, 0.f, 0.f};
#pragma unroll
  for (int ni = 0; ni < 4; ++ni) {
    int iy = 8 * qz2 + ns * 4 + ni, ix = n15;
#pragma unroll
    for (int r = 0; r < 4; ++r) {
      int m = m0 + ms * 16 + kq * 4 + r;
      float v00 = fmaxf(acc[ni][0][r] + bv[r], 0.f);
      float v01 = fmaxf(acc[ni][1][r] + bv[r], 0.f);
      float v10 = fmaxf(acc[ni][2][r] + bv[r], 0.f);
      float v11 = fmaxf(acc[ni][3][r] + bv[r], 0.f);
      size_t base = ((size_t)b * 64 + m) * 1024 + (size_t)(2 * iy) * 32 + 2 * ix;
      *(u32*)(y + base)      = pack_bf16x2(v00, v01);
      *(u32*)(y + base + 32) = pack_bf16x2(v10, v11);
      sr[r]  += v00 + v01 + v10 + v11;
      sr2[r] += v00 * v00 + v01 * v01 + v10 * v10 + v11 * v11;
    }
  }
#pragma unroll
  for (int r = 0; r < 4; ++r) {
#pragma unroll
    for (int off = 1; off <= 8; off <<= 1) {
      sr[r]  += __shfl_xor(sr[r], off, 64);
      sr2[r] += __shfl_xor(sr2[r], off, 64);
    }
  }
  __syncthreads();
  if (n15 == 0) {
#pragma unroll
    for (int r = 0; r < 4; ++r) sbuf[ms][ns][kq * 4 + r] = float2{sr[r], sr2[r]};
  }
  __syncthreads();
  if (t < 32) {
    int msx = t >> 4, i = t & 15;
    float2 p0 = sbuf[msx][0][i], p1 = sbuf[msx][1][i];
    int m = m0 + msx * 16 + i;
    psum[((size_t)b * 64 + m) * 2 + qz2] = float2{p0.x + p1.x, p0.y + p1.y};
  }
}

// ---------------- head: fold stat partials -> norm -> 1x1 conv -> spatial softmax ----------------
// Batched reductions: 3 barriers total (was ~40).
__global__ __launch_bounds__(256)
void head_kernel(const u16* __restrict__ x3, const float2* __restrict__ psum,
                 const int* __restrict__ action, const float* __restrict__ hgw,
                 const float* __restrict__ hcw, float* __restrict__ out)
{
  constexpr int C = 64, S = 5, P = 1024;
  const int t = threadIdx.x;
  const int lane = t & 63, wv = t >> 6;
  const int b = (blockIdx.x & 7) * 64 + (blockIdx.x >> 3);   // XCD-consistent b mapping
  const int a = action[b];
  __shared__ float weff[S * C];
  __shared__ float sc_l[C], sh_l[C];
  __shared__ float redm[4][8];    // per-wave maxima (5 used)
  __shared__ float redp[4][16];   // per-wave partial sums (15 used)
  if (t < C) {
    float2 p0 = psum[((size_t)b * C + t) * 2 + 0];
    float2 p1 = psum[((size_t)b * C + t) * 2 + 1];
    float s = p0.x + p1.x, s2 = p0.y + p1.y;
    float mu = s * (1.f / 1024.f);
    float var = fmaxf(s2 * (1.f / 1024.f) - mu * mu, 0.f);
    float rstd = rsqrtf(var + 1e-5f);
    sc_l[t] = rstd; sh_l[t] = -mu * rstd;
  }
  for (int j = t; j < S * C; j += 256) {
    int s = j >> 6, c = j & 63;
    weff[j] = hcw[(a * S + s) * C + c] * hgw[a * C + c];
  }
  __syncthreads();

  float L[S][4];
#pragma unroll
  for (int s = 0; s < S; ++s)
#pragma unroll
    for (int k = 0; k < 4; ++k) L[s][k] = 0.f;

  const u32* xb = (const u32*)(x3 + (size_t)b * C * P);
  for (int c = 0; c < C; ++c) {
    float scv = sc_l[c], shv = sh_l[c];
    u32 u0 = xb[c * 512 + t];
    u32 u1 = xb[c * 512 + t + 256];
    float xv[4] = {bflo(u0) * scv + shv, bfhi(u0) * scv + shv,
                   bflo(u1) * scv + shv, bfhi(u1) * scv + shv};
#pragma unroll
    for (int s = 0; s < S; ++s) {
      float wv_ = weff[s * C + c];
#pragma unroll
      for (int k = 0; k < 4; ++k) L[s][k] += xv[k] * wv_;
    }
  }

  // ---- phase A: all 5 maxima in one interleaved reduce ----
  float m5[S];
#pragma unroll
  for (int s = 0; s < S; ++s)
    m5[s] = fmaxf(fmaxf(L[s][0], L[s][1]), fmaxf(L[s][2], L[s][3]));
#pragma unroll
  for (int off = 32; off; off >>= 1)
#pragma unroll
    for (int s = 0; s < S; ++s) m5[s] = fmaxf(m5[s], __shfl_xor(m5[s], off, 64));
  if (lane == 0) {
#pragma unroll
    for (int s = 0; s < S; ++s) redm[wv][s] = m5[s];
  }
  __syncthreads();
#pragma unroll
  for (int s = 0; s < S; ++s)
    m5[s] = fmaxf(fmaxf(redm[0][s], redm[1][s]), fmaxf(redm[2][s], redm[3][s]));

  // ---- phase B: all 15 sums (se,sx,sy per s) in one interleaved reduce ----
  float p15[15];
  const int pix[4] = {2 * t, 2 * t + 1, 512 + 2 * t, 512 + 2 * t + 1};
#pragma unroll
  for (int s = 0; s < S; ++s) {
    float se = 0.f, sx = 0.f, sy = 0.f;
#pragma unroll
    for (int k = 0; k < 4; ++k) {
      int p = pix[k];
      float e = __expf(L[s][k] - m5[s]);
      se += e;
      sx += e * ((float)(p & 31) * (2.f / 31.f) - 1.f);
      sy += e * ((float)(p >> 5) * (2.f / 31.f) - 1.f);
    }
    p15[s * 3 + 0] = se; p15[s * 3 + 1] = sx; p15[s * 3 + 2] = sy;
  }
#pragma unroll
  for (int off = 32; off; off >>= 1)
#pragma unroll
    for (int j = 0; j < 15; ++j) p15[j] += __shfl_xor(p15[j], off, 64);
  if (lane == 0) {
#pragma unroll
    for (int j = 0; j < 15; ++j) redp[wv][j] = p15[j];
  }
  __syncthreads();
  if (t < S) {
    int s = t;
    float se = redp[0][s * 3] + redp[1][s * 3] + redp[2][s * 3] + redp[3][s * 3];
    float sx = redp[0][s * 3 + 1] + redp[1][s * 3 + 1] + redp[2][s * 3 + 1] + redp[3][s * 3 + 1];
    float sy = redp[0][s * 3 + 2] + redp[1][s * 3 + 2] + redp[2][s * 3 + 2] + redp[3][s * 3 + 2];
    out[(b * S + s) * 2 + 0] = sx / se;
    out[(b * S + s) * 2 + 1] = sy / se;
  }
}

// ---------------- launcher ----------------
extern "C" void kernel_launch(void* const* d_in, const int* in_sizes, int n_in,
                              void* d_out, int out_size, void* d_ws, size_t ws_size,
                              hipStream_t stream)
{
  (void)in_sizes; (void)n_in; (void)out_size; (void)ws_size;
  const float* feat   = (const float*)d_in[0];
  const int*   action = (const int*)d_in[1];
  const float* fc_w = (const float*)d_in[3];
  const float* fc_b = (const float*)d_in[4];
  const float* gw0  = (const float*)d_in[5];
  const float* gb0  = (const float*)d_in[6];
  const float* dw0  = (const float*)d_in[7];
  const float* db0  = (const float*)d_in[8];
  const float* gw1  = (const float*)d_in[9];
  const float* gb1  = (const float*)d_in[10];
  const float* dw1  = (const float*)d_in[11];
  const float* db1  = (const float*)d_in[12];
  const float* gw2  = (const float*)d_in[13];
  const float* gb2  = (const float*)d_in[14];
  const float* dw2  = (const float*)d_in[15];
  const float* db2  = (const float*)d_in[16];
  const float* hgw  = (const float*)d_in[17];
  const float* hcw  = (const float*)d_in[19];

  float* ws = (float*)d_ws;
  u16* x0 = (u16*)(ws + OFF_REGB);
  u16* x2 = (u16*)(ws + OFF_REGB);
  u16* x1 = (u16*)(ws + OFF_REGA);
  u16* x3 = (u16*)(ws + OFF_REGA);
  u16* wt0 = (u16*)(ws + OFF_WT0);
  u16* wt1 = (u16*)(ws + OFF_WT1);
  u16* wt2 = (u16*)(ws + OFF_WT2);
  u16* wtf = (u16*)(ws + OFF_WTF);
  float2* psum = (float2*)(ws + O_PSUM);

  wtrans_all<<<1184, 256, 0, stream>>>(dw0, dw1, dw2, fc_w, wt0, wt1, wt2, wtf);
  fc_mfma<<<dim3(8, 64), 256, 0, stream>>>(feat, wtf, fc_b, gw0, gb0, x0);
  deconv_mfma<0><<<dim3(8, 128), 256, 0, stream>>>(x0, wt0, db0, x1, gw1, gb1);
  deconv_mfma<1><<<dim3(4, 512), 256, 0, stream>>>(x1, wt1, db1, x2, gw2, gb2);
  deconv2_q<<<dim3(4, 512), 256, 0, stream>>>(x2, wt2, db2, x3, psum);
  head_kernel<<<512, 256, 0, stream>>>(x3, psum, action, hgw, hcw, (float*)d_out);
}

// Round 14
// 240.462 us; speedup vs baseline: 1.9473x; 1.0019x over previous
//
#include <hip/hip_runtime.h>
#include <hip/hip_bf16.h>

#define DI __device__ __forceinline__
using u16 = unsigned short;
using u32 = unsigned int;

typedef short short8 __attribute__((ext_vector_type(8)));   // 8 bf16 (4 VGPRs)
typedef float f32x4 __attribute__((ext_vector_type(4)));

#define F4C(v, i) ((i) == 0 ? (v).x : (i) == 1 ? (v).y : (i) == 2 ? (v).z : (v).w)

DI float bflo(u32 u) { return __uint_as_float(u << 16); }
DI float bfhi(u32 u) { return __uint_as_float(u & 0xffff0000u); }
DI u16 f2bf(float a) {
  u32 xu = __float_as_uint(a);
  return (u16)((xu + 0x7fffu + ((xu >> 16) & 1)) >> 16);
}
DI u32 pack_bf16x2(float a, float b) {
  u32 xu = __float_as_uint(a), yu = __float_as_uint(b);
  xu = (xu + 0x7fffu + ((xu >> 16) & 1)) >> 16;
  yu = (yu + 0x7fffu + ((yu >> 16) & 1)) >> 16;
  return (xu & 0xffffu) | (yu << 16);
}

// ---------------- workspace layout (float units) ----------------
static constexpr size_t OFF_REGB = 0;
static constexpr size_t OFF_REGA = 16777216;
static constexpr size_t OFF_WT0  = 33554432;
static constexpr size_t OFF_WT1  = OFF_WT0 + 1179648;
static constexpr size_t OFF_WT2  = OFF_WT1 + 294912;
static constexpr size_t OFF_WTF  = OFF_WT2 + 73728;
static constexpr size_t OFF_ST   = 35200000;
static constexpr size_t O_PSUM = OFF_ST + 1048576;   // 512*64*2 float2 = 131072 floats

// ---------------- all weight pre-transposes in one launch ----------------
__global__ __launch_bounds__(256)
void wtrans_all(const float* __restrict__ dw0, const float* __restrict__ dw1,
                const float* __restrict__ dw2, const float* __restrict__ fcw,
                u16* __restrict__ wt0, u16* __restrict__ wt1,
                u16* __restrict__ wt2, u16* __restrict__ wtf)
{
  int id = blockIdx.x * 256 + threadIdx.x;
  if (id < 131072) {                       // dw0: CO=256, CI=512
    int m = id >> 9, c = id & 511;
    const float* src = dw0 + ((size_t)m * 512 + c) * 9;
#pragma unroll
    for (int tap = 0; tap < 9; ++tap)
      wt0[((size_t)tap * 256 + m) * 512 + c] = f2bf(src[tap]);
  } else if (id < 163840) {                // dw1: CO=128, CI=256
    int j = id - 131072;
    int m = j >> 8, c = j & 255;
    const float* src = dw1 + ((size_t)m * 256 + c) * 9;
#pragma unroll
    for (int tap = 0; tap < 9; ++tap)
      wt1[((size_t)tap * 128 + m) * 256 + c] = f2bf(src[tap]);
  } else if (id < 172032) {                // dw2: CO=64, CI=128
    int j = id - 163840;
    int m = j >> 7, c = j & 127;
    const float* src = dw2 + ((size_t)m * 128 + c) * 9;
#pragma unroll
    for (int tap = 0; tap < 9; ++tap)
      wt2[((size_t)tap * 64 + m) * 128 + c] = f2bf(src[tap]);
  } else {                                 // fc: wtf[d][c]
    int j = id - 172032;
    int d = j >> 8, c = j & 255;
    wtf[j] = f2bf(fcw[c * 512 + d]);
  }
}

// ---------------- fc1 via MFMA; GN0 applied in epilogue; x0 stored px-major ----------------
DI void fc_stage_A(const float* __restrict__ feat, int b, u16* Ab, int t)
{
#pragma unroll
  for (int it = 0; it < 2; ++it) {
    int idx = t + it * 256;
    int cp = idx >> 2, hw4 = idx & 3;
    int c = cp * 2;
    const float* xp = feat + ((size_t)b * 256 + c) * 16 + hw4 * 4;
    float4 v0 = *(const float4*)xp;
    float4 v1 = *(const float4*)(xp + 16);
    int c64 = c >> 6, jb = (c & 63) >> 3;
#pragma unroll
    for (int j = 0; j < 4; ++j) {
      int hw = hw4 * 4 + j;
      int row = c64 * 16 + hw;
      *(u32*)&Ab[(row << 6) + ((jb ^ (row & 7)) << 3) + (c & 7)] =
          pack_bf16x2(F4C(v0, j), F4C(v1, j));
    }
  }
}

__global__ __launch_bounds__(256, 3)
void fc_mfma(const float* __restrict__ feat, const u16* __restrict__ wtf,
             const float* __restrict__ fb, const float* __restrict__ gw,
             const float* __restrict__ gb, u16* __restrict__ x0)
{
  __shared__ __align__(16) u16 Wl[256 * 64];
  __shared__ __align__(16) u16 Al[2][64 * 64];
  const int t = threadIdx.x;
  const int lane = t & 63, wave = t >> 6;
  const int n15 = lane & 15, kq = lane >> 4;
  // XCD swizzle: XCD k owns b in [64k, 64k+64); 8 d-blocks of same b-group co-located
  const int lin = blockIdx.y * 8 + blockIdx.x;
  const int xk = lin & 7, pos = lin >> 3;          // pos 0..63
  const int d0 = (pos & 7) * 64;
  const int b0 = (xk * 8 + (pos >> 3)) * 8;

#pragma unroll
  for (int it = 0; it < 8; ++it) {
    int idx = t + it * 256;
    int dl = idx >> 5, jb32 = idx & 31;
    int row = (jb32 >> 3) * 64 + dl, jb = jb32 & 7;
    uint4 v = *(const uint4*)(wtf + (size_t)(d0 + dl) * 256 + jb32 * 8);
    *(uint4*)&Wl[(row << 6) + ((jb ^ (row & 7)) << 3)] = v;
  }
  fc_stage_A(feat, b0, Al[0], t);

  const int dg = d0 + wave * 16 + n15;
  const float bvn = fb[dg];
  const float gwv = gw[dg], gbv = gb[dg];

  for (int bi = 0; bi < 8; ++bi) {
    __syncthreads();
    if (bi + 1 < 8) fc_stage_A(feat, b0 + bi + 1, Al[(bi + 1) & 1], t);

    const u16* A = Al[bi & 1];
    f32x4 acc0 = {0.f, 0.f, 0.f, 0.f}, acc1 = {0.f, 0.f, 0.f, 0.f};
#pragma unroll
    for (int ks = 0; ks < 8; ++ks) {
      int js = ks * 4 + kq;
      int ra = (js >> 3) * 16 + n15;
      int rb = (js >> 3) * 64 + wave * 16 + n15;
      short8 av = *(const short8*)&A[(ra << 6) + (((js & 7) ^ (ra & 7)) << 3)];
      short8 bv = *(const short8*)&Wl[(rb << 6) + (((js & 7) ^ (rb & 7)) << 3)];
      if (ks & 1) acc1 = __builtin_amdgcn_mfma_f32_16x16x32_bf16(av, bv, acc1, 0, 0, 0);
      else        acc0 = __builtin_amdgcn_mfma_f32_16x16x32_bf16(av, bv, acc0, 0, 0, 0);
    }

    int b = b0 + bi;
    float v[4], s = 0.f, s2 = 0.f;
#pragma unroll
    for (int r = 0; r < 4; ++r) {
      v[r] = fmaxf(acc0[r] + acc1[r] + bvn, 0.f);
      s += v[r]; s2 += v[r] * v[r];
    }
    s  += __shfl_xor(s, 16, 64);  s  += __shfl_xor(s, 32, 64);
    s2 += __shfl_xor(s2, 16, 64); s2 += __shfl_xor(s2, 32, 64);
    // GN0 applied here: every lane has full 16-px sums after the butterfly.
    float mu = s * (1.f / 16.f);
    float var = fmaxf(s2 * (1.f / 16.f) - mu * mu, 0.f);
    float scale = gwv * rsqrtf(var + 1e-5f);
    float shift = gbv - mu * scale;
    // x0 layout px-major [b][16 px][512 d]; lane's 4 values are px kq*4+r, channel dg
    u16* yp = x0 + ((size_t)b * 16 + kq * 4) * 512 + dg;
#pragma unroll
    for (int r = 0; r < 4; ++r) yp[(size_t)r * 512] = f2bf(v[r] * scale + shift);
  }
}

// ---------------- deconv stages 0/1: inputs pre-normalized px-major; pure-copy stage-X
// STAGE 0: reads x0 px-major [b][16px][512c], writes x1 px-major [b][64px][256c].
// STAGE 1: reads x1 px-major, writes x2 px-major [b][256px][128c].
template<int STAGE>
__global__ __launch_bounds__(256, 3)
void deconv_mfma(const u16* __restrict__ x, const u16* __restrict__ wt,
                 const float* __restrict__ bias, u16* __restrict__ y,
                 const float* __restrict__ gwn, const float* __restrict__ gbn)
{
  constexpr int CI  = STAGE == 0 ? 512 : 256;
  constexpr int CO  = CI / 2;
  constexpr int H   = STAGE == 0 ? 4 : 8;
  constexpr int WP  = H + 1;
  constexpr int XROWS = STAGE == 0 ? 100 : 81;
  constexpr int NCH = CI / 64;
  __shared__ __align__(16) u16 Wl[288 * 64];
  __shared__ __align__(16) u16 Xl[XROWS * 64];
  __shared__ float2 sbuf[2][2][16];
  __shared__ float scl[32], shl[32];

  const int t = threadIdx.x;
  const int lane = t & 63, wave = t >> 6;
  const int ms = wave >> 1, ns = wave & 1;
  const int n15 = lane & 15, kq = lane >> 4;

  // XCD swizzle: XCD k owns b in [64k, 64k+64); all m-blocks of a b co-located
  int m0, b0;
  if constexpr (STAGE == 0) {
    int lin = blockIdx.y * 8 + blockIdx.x;       // 1024 blocks
    int xk = lin & 7, pos = lin >> 3;            // pos 0..127
    m0 = (pos & 7) * 32;
    b0 = (xk * 16 + (pos >> 3)) * 4;
  } else {
    int lin = blockIdx.y * 4 + blockIdx.x;       // 2048 blocks
    int xk = lin & 7, pos = lin >> 3;            // pos 0..255
    m0 = (pos & 3) * 32;
    b0 = xk * 64 + (pos >> 2);
  }

  int xrow[2];
#pragma unroll
  for (int ni = 0; ni < 2; ++ni) {
    if constexpr (STAGE == 0) xrow[ni] = (ns * 2 + ni) * 25 + (n15 >> 2) * 5 + (n15 & 3);
    else                      xrow[ni] = (2 * (ns * 2 + ni) + (n15 >> 3)) * 9 + (n15 & 7);
  }
  const int am = ms * 16 + n15;

  for (int i = t; i < XROWS * 32; i += 256) ((u32*)Xl)[i] = 0;

  f32x4 acc[2][4];
#pragma unroll
  for (int ni = 0; ni < 2; ++ni)
#pragma unroll
    for (int c = 0; c < 4; ++c) acc[ni][c] = f32x4{0.f, 0.f, 0.f, 0.f};

  for (int ch = 0; ch < NCH; ++ch) {
    const int c0 = ch * 64;
    __syncthreads();

#pragma unroll
    for (int it = 0; it < 9; ++it) {
      int idx = t + it * 256;
      int row = idx >> 3, jb = idx & 7;
      int tap = row >> 5, ml = row & 31;
      uint4 v = *(const uint4*)(wt + ((size_t)(tap * CO + m0 + ml)) * CI + c0 + jb * 8);
      *(uint4*)&Wl[(row << 6) + ((jb ^ (row & 7)) << 3)] = v;
    }

    if constexpr (STAGE == 0) {
      // stage X: px-major x0 -> pure coalesced uint4 copy into swizzled LDS
      for (int idx = t; idx < 64 * 8; idx += 256) {
        int pxl = idx >> 3, jb = idx & 7;
        int img = pxl >> 4, p = pxl & 15;
        int iy = p >> 2, ix = p & 3;
        uint4 q = *(const uint4*)(x + ((size_t)(b0 + img) * 16 + p) * 512 + c0 + jb * 8);
        int row = img * 25 + iy * 5 + ix;
        *(uint4*)&Xl[(row << 6) + ((jb ^ (row & 7)) << 3)] = q;
      }
    } else {
      // stage X: px-major x1 -> pure coalesced uint4 copy into swizzled LDS
      for (int idx = t; idx < 64 * 8; idx += 256) {
        int pxl = idx >> 3, jb = idx & 7;
        int py = pxl >> 3, px_ = pxl & 7;
        uint4 q = *(const uint4*)(x + ((size_t)b0 * 64 + pxl) * 256 + c0 + jb * 8);
        int row = py * 9 + px_;
        *(uint4*)&Xl[(row << 6) + ((jb ^ (row & 7)) << 3)] = q;
      }
    }
    __syncthreads();

#pragma unroll
    for (int s = 0; s < 2; ++s) {
      const int js = s * 4 + kq;
      short8 a[9];
#pragma unroll
      for (int tap = 0; tap < 9; ++tap) {
        int row = tap * 32 + am;
        a[tap] = *(const short8*)&Wl[(row << 6) + ((js ^ (row & 7)) << 3)];
      }
#pragma unroll
      for (int ni = 0; ni < 2; ++ni) {
        int r0 = xrow[ni], r1 = r0 + 1, r2 = r0 + WP, r3 = r0 + WP + 1;
        short8 b00 = *(const short8*)&Xl[(r0 << 6) + ((js ^ (r0 & 7)) << 3)];
        short8 b01 = *(const short8*)&Xl[(r1 << 6) + ((js ^ (r1 & 7)) << 3)];
        short8 b10 = *(const short8*)&Xl[(r2 << 6) + ((js ^ (r2 & 7)) << 3)];
        short8 b11 = *(const short8*)&Xl[(r3 << 6) + ((js ^ (r3 & 7)) << 3)];
        acc[ni][0] = __builtin_amdgcn_mfma_f32_16x16x32_bf16(a[4], b00, acc[ni][0], 0, 0, 0);
        acc[ni][1] = __builtin_amdgcn_mfma_f32_16x16x32_bf16(a[3], b00, acc[ni][1], 0, 0, 0);
        acc[ni][1] = __builtin_amdgcn_mfma_f32_16x16x32_bf16(a[5], b01, acc[ni][1], 0, 0, 0);
        acc[ni][2] = __builtin_amdgcn_mfma_f32_16x16x32_bf16(a[1], b00, acc[ni][2], 0, 0, 0);
        acc[ni][2] = __builtin_amdgcn_mfma_f32_16x16x32_bf16(a[7], b10, acc[ni][2], 0, 0, 0);
        acc[ni][3] = __builtin_amdgcn_mfma_f32_16x16x32_bf16(a[0], b00, acc[ni][3], 0, 0, 0);
        acc[ni][3] = __builtin_amdgcn_mfma_f32_16x16x32_bf16(a[2], b01, acc[ni][3], 0, 0, 0);
        acc[ni][3] = __builtin_amdgcn_mfma_f32_16x16x32_bf16(a[6], b10, acc[ni][3], 0, 0, 0);
        acc[ni][3] = __builtin_amdgcn_mfma_f32_16x16x32_bf16(a[8], b11, acc[ni][3], 0, 0, 0);
      }
    }
  }

  // ---- epilogue: bias + relu + next-GN normalize + store ----
  float bv[4];
#pragma unroll
  for (int r = 0; r < 4; ++r) bv[r] = bias[m0 + ms * 16 + kq * 4 + r];

  if constexpr (STAGE == 0) {
    float gw4[4], gb4[4];
#pragma unroll
    for (int r = 0; r < 4; ++r) {
      int m = m0 + ms * 16 + kq * 4 + r;
      gw4[r] = gwn[m]; gb4[r] = gbn[m];
    }
#pragma unroll
    for (int ni = 0; ni < 2; ++ni) {
      int b = b0 + ns * 2 + ni, iy = n15 >> 2, ix = n15 & 3;
      float val[4][4];
      float sr[4] = {0.f, 0.f, 0.f, 0.f}, sr2[4] = {0.f, 0.f, 0.f, 0.f};
#pragma unroll
      for (int cl = 0; cl < 4; ++cl)
#pragma unroll
        for (int r = 0; r < 4; ++r) {
          val[cl][r] = fmaxf(acc[ni][cl][r] + bv[r], 0.f);
          sr[r] += val[cl][r]; sr2[r] += val[cl][r] * val[cl][r];
        }
#pragma unroll
      for (int r = 0; r < 4; ++r) {
#pragma unroll
        for (int off = 1; off <= 8; off <<= 1) {
          sr[r]  += __shfl_xor(sr[r], off, 64);
          sr2[r] += __shfl_xor(sr2[r], off, 64);
        }
      }
      // full 64-px stats now in all lanes -> normalize in-lane, store normalized px-major
      float scv[4], shv[4];
#pragma unroll
      for (int r = 0; r < 4; ++r) {
        float mu = sr[r] * (1.f / 64.f);
        float var = fmaxf(sr2[r] * (1.f / 64.f) - mu * mu, 0.f);
        scv[r] = gw4[r] * rsqrtf(var + 1e-5f);
        shv[r] = gb4[r] - mu * scv[r];
      }
      // x1 layout [b][8x8 px][256 c]
#pragma unroll
      for (int cl = 0; cl < 4; ++cl) {
        int oy = 2 * iy + (cl >> 1), ox = 2 * ix + (cl & 1);
        size_t base = ((size_t)b * 64 + oy * 8 + ox) * 256 + m0 + ms * 16 + kq * 4;
        uint2 pk = {pack_bf16x2(val[cl][0] * scv[0] + shv[0],
                                val[cl][1] * scv[1] + shv[1]),
                    pack_bf16x2(val[cl][2] * scv[2] + shv[2],
                                val[cl][3] * scv[3] + shv[3])};
        *(uint2*)(y + base) = pk;
      }
    }
  } else {
    float sr[4] = {0.f, 0.f, 0.f, 0.f}, sr2[4] = {0.f, 0.f, 0.f, 0.f};
#pragma unroll
    for (int ni = 0; ni < 2; ++ni)
#pragma unroll
      for (int cl = 0; cl < 4; ++cl)
#pragma unroll
        for (int r = 0; r < 4; ++r) {
          float v = fmaxf(acc[ni][cl][r] + bv[r], 0.f);
          sr[r] += v; sr2[r] += v * v;
        }
#pragma unroll
    for (int r = 0; r < 4; ++r) {
#pragma unroll
      for (int off = 1; off <= 8; off <<= 1) {
        sr[r]  += __shfl_xor(sr[r], off, 64);
        sr2[r] += __shfl_xor(sr2[r], off, 64);
      }
    }
    __syncthreads();
    if (n15 == 0) {
#pragma unroll
      for (int r = 0; r < 4; ++r) sbuf[ms][ns][kq * 4 + r] = float2{sr[r], sr2[r]};
    }
    __syncthreads();
    if (t < 32) {
      int msx = t >> 4, i = t & 15;
      float2 p0 = sbuf[msx][0][i], p1 = sbuf[msx][1][i];
      float s = p0.x + p1.x, s2 = p0.y + p1.y;
      float mu = s * (1.f / 256.f);
      float var = fmaxf(s2 * (1.f / 256.f) - mu * mu, 0.f);
      int m = m0 + msx * 16 + i;
      float scale = gwn[m] * rsqrtf(var + 1e-5f);
      scl[t] = scale;
      shl[t] = gbn[m] - mu * scale;
    }
    __syncthreads();
    float scv[4], shv[4];
#pragma unroll
    for (int r = 0; r < 4; ++r) {
      scv[r] = scl[ms * 16 + kq * 4 + r];
      shv[r] = shl[ms * 16 + kq * 4 + r];
    }
    // x2 layout [b][256 px][128 c], stored pre-normalized
#pragma unroll
    for (int ni = 0; ni < 2; ++ni) {
      int iy = 2 * (ns * 2 + ni) + (n15 >> 3), ix = n15 & 7;
#pragma unroll
      for (int cl = 0; cl < 4; ++cl) {
        int opx = (2 * iy + (cl >> 1)) * 16 + 2 * ix + (cl & 1);
        size_t base = ((size_t)b0 * 256 + opx) * 128 + m0 + ms * 16 + kq * 4;
        float v0 = fmaxf(acc[ni][cl][0] + bv[0], 0.f) * scv[0] + shv[0];
        float v1 = fmaxf(acc[ni][cl][1] + bv[1], 0.f) * scv[1] + shv[1];
        float v2 = fmaxf(acc[ni][cl][2] + bv[2], 0.f) * scv[2] + shv[2];
        float v3 = fmaxf(acc[ni][cl][3] + bv[3], 0.f) * scv[3] + shv[3];
        *(u32*)(y + base)     = pack_bf16x2(v0, v1);
        *(u32*)(y + base + 2) = pack_bf16x2(v2, v3);
      }
    }
  }
}

// ---------------- stage-2 deconv: merged m-halves; X staged once, reused by both m ----------------
#define XRD(ch, row) (*(const short8*)&Xl[ch][((row) << 6) + (((js ^ ((row) & 7))) << 3)])
__global__ __launch_bounds__(256, 2)
void deconv2_q(const u16* __restrict__ x, const u16* __restrict__ wt,
               const float* __restrict__ bias, u16* __restrict__ y,
               float2* __restrict__ psum)
{
  __shared__ __align__(16) u16 Wl[288 * 64];
  __shared__ __align__(16) u16 Xl[2][153 * 64]; // both ch chunks resident; halo stays 0
  __shared__ float2 sbuf[2][2][16];

  const int t = threadIdx.x;
  const int lane = t & 63, wave = t >> 6;
  const int ms = wave >> 1, ns = wave & 1;
  const int n15 = lane & 15, kq = lane >> 4;
  // XCD swizzle: XCD k owns b in [64k, 64k+64)
  const int lin = blockIdx.y * 2 + blockIdx.x;   // 1024 blocks
  const int xk = lin & 7, pos = lin >> 3;        // pos 0..127
  const int b   = xk * 64 + (pos >> 1);
  const int qz2 = pos & 1;                       // 0..1 (16 output rows each)

  for (int i = t; i < 2 * 153 * 32; i += 256) ((u32*)Xl)[i] = 0;

  const int am = ms * 16 + n15;
  const int xr0 = (ns * 4) * 17 + n15;

  const int NPX = (qz2 == 0) ? 144 : 128;     // input rows 0..8 / 8..15 (+zero halo)

  for (int mh = 0; mh < 2; ++mh) {
    const int m0 = mh * 32;

    f32x4 acc[4][4];
#pragma unroll
    for (int ni = 0; ni < 4; ++ni)
#pragma unroll
      for (int c = 0; c < 4; ++c) acc[ni][c] = f32x4{0.f, 0.f, 0.f, 0.f};

    for (int ch = 0; ch < 2; ++ch) {
      const int c0 = ch * 64;
      __syncthreads();

      // ---- stage W: 288 rows (tap*32+ml) x 8 blocks ----
#pragma unroll
      for (int it = 0; it < 9; ++it) {
        int idx = t + it * 256;
        int row = idx >> 3, jb = idx & 7;
        int tap = row >> 5, ml = row & 31;
        uint4 v = *(const uint4*)(wt + ((size_t)(tap * 64 + m0 + ml)) * 128 + c0 + jb * 8);
        *(uint4*)&Wl[(row << 6) + ((jb ^ (row & 7)) << 3)] = v;
      }

      // ---- stage X only in first m-pass: both m-halves reuse it ----
      if (mh == 0) {
        for (int idx = t; idx < NPX * 8; idx += 256) {
          int pxl = idx >> 3, jb = idx & 7;
          int rl = pxl >> 4, ix = pxl & 15;
          int gpx = (8 * qz2 + rl) * 16 + ix;
          uint4 q = *(const uint4*)(x + ((size_t)b * 256 + gpx) * 128 + c0 + jb * 8);
          int row = rl * 17 + ix;
          *(uint4*)&Xl[ch][(row << 6) + ((jb ^ (row & 7)) << 3)] = q;
        }
      }
      __syncthreads();

#pragma unroll
      for (int s = 0; s < 2; ++s) {
        const int js = s * 4 + kq;
        short8 a[9];
#pragma unroll
        for (int tap = 0; tap < 9; ++tap) {
          int row = tap * 32 + am;
          a[tap] = *(const short8*)&Wl[(row << 6) + ((js ^ (row & 7)) << 3)];
        }
        // 10 B rows shared across the wave's 4 adjacent n-tiles
        short8 Brow[10];
#pragma unroll
        for (int k = 0; k < 5; ++k) {
          Brow[2 * k]     = XRD(ch, xr0 + 17 * k);
          Brow[2 * k + 1] = XRD(ch, xr0 + 17 * k + 1);
        }
        __builtin_amdgcn_s_setprio(1);
#pragma unroll
        for (int ni = 0; ni < 4; ++ni) {
          short8 b00 = Brow[2 * ni],     b01 = Brow[2 * ni + 1];
          short8 b10 = Brow[2 * ni + 2], b11 = Brow[2 * ni + 3];
          acc[ni][0] = __builtin_amdgcn_mfma_f32_16x16x32_bf16(a[4], b00, acc[ni][0], 0, 0, 0);
          acc[ni][1] = __builtin_amdgcn_mfma_f32_16x16x32_bf16(a[3], b00, acc[ni][1], 0, 0, 0);
          acc[ni][1] = __builtin_amdgcn_mfma_f32_16x16x32_bf16(a[5], b01, acc[ni][1], 0, 0, 0);
          acc[ni][2] = __builtin_amdgcn_mfma_f32_16x16x32_bf16(a[1], b00, acc[ni][2], 0, 0, 0);
          acc[ni][2] = __builtin_amdgcn_mfma_f32_16x16x32_bf16(a[7], b10, acc[ni][2], 0, 0, 0);
          acc[ni][3] = __builtin_amdgcn_mfma_f32_16x16x32_bf16(a[0], b00, acc[ni][3], 0, 0, 0);
          acc[ni][3] = __builtin_amdgcn_mfma_f32_16x16x32_bf16(a[2], b01, acc[ni][3], 0, 0, 0);
          acc[ni][3] = __builtin_amdgcn_mfma_f32_16x16x32_bf16(a[6], b10, acc[ni][3], 0, 0, 0);
          acc[ni][3] = __builtin_amdgcn_mfma_f32_16x16x32_bf16(a[8], b11, acc[ni][3], 0, 0, 0);
        }
        __builtin_amdgcn_s_setprio(0);
      }
    }

    // ---- epilogue for this m-half: bias + relu + store + stat partials ----
    float bv[4];
#pragma unroll
    for (int r = 0; r < 4; ++r) bv[r] = bias[m0 + ms * 16 + kq * 4 + r];
    float sr[4] = {0.f, 0.f, 0.f, 0.f}, sr2[4] = {0.f, 0.f, 0.f, 0.f};
#pragma unroll
    for (int ni = 0; ni < 4; ++ni) {
      int iy = 8 * qz2 + ns * 4 + ni, ix = n15;
#pragma unroll
      for (int r = 0; r < 4; ++r) {
        int m = m0 + ms * 16 + kq * 4 + r;
        float v00 = fmaxf(acc[ni][0][r] + bv[r], 0.f);
        float v01 = fmaxf(acc[ni][1][r] + bv[r], 0.f);
        float v10 = fmaxf(acc[ni][2][r] + bv[r], 0.f);
        float v11 = fmaxf(acc[ni][3][r] + bv[r], 0.f);
        size_t base = ((size_t)b * 64 + m) * 1024 + (size_t)(2 * iy) * 32 + 2 * ix;
        *(u32*)(y + base)      = pack_bf16x2(v00, v01);
        *(u32*)(y + base + 32) = pack_bf16x2(v10, v11);
        sr[r]  += v00 + v01 + v10 + v11;
        sr2[r] += v00 * v00 + v01 * v01 + v10 * v10 + v11 * v11;
      }
    }
#pragma unroll
    for (int r = 0; r < 4; ++r) {
#pragma unroll
      for (int off = 1; off <= 8; off <<= 1) {
        sr[r]  += __shfl_xor(sr[r], off, 64);
        sr2[r] += __shfl_xor(sr2[r], off, 64);
      }
    }
    __syncthreads();
    if (n15 == 0) {
#pragma unroll
      for (int r = 0; r < 4; ++r) sbuf[ms][ns][kq * 4 + r] = float2{sr[r], sr2[r]};
    }
    __syncthreads();
    if (t < 32) {
      int msx = t >> 4, i = t & 15;
      float2 p0 = sbuf[msx][0][i], p1 = sbuf[msx][1][i];
      int m = m0 + msx * 16 + i;
      psum[((size_t)b * 64 + m) * 2 + qz2] = float2{p0.x + p1.x, p0.y + p1.y};
    }
  }
}

// ---------------- head: fold stat partials -> norm -> 1x1 conv -> spatial softmax ----------------
// Batched reductions: 3 barriers total.
__global__ __launch_bounds__(256)
void head_kernel(const u16* __restrict__ x3, const float2* __restrict__ psum,
                 const int* __restrict__ action, const float* __restrict__ hgw,
                 const float* __restrict__ hcw, float* __restrict__ out)
{
  constexpr int C = 64, S = 5, P = 1024;
  const int t = threadIdx.x;
  const int lane = t & 63, wv = t >> 6;
  const int b = (blockIdx.x & 7) * 64 + (blockIdx.x >> 3);   // XCD-consistent b mapping
  const int a = action[b];
  __shared__ float weff[S * C];
  __shared__ float sc_l[C], sh_l[C];
  __shared__ float redm[4][8];    // per-wave maxima (5 used)
  __shared__ float redp[4][16];   // per-wave partial sums (15 used)
  if (t < C) {
    float2 p0 = psum[((size_t)b * C + t) * 2 + 0];
    float2 p1 = psum[((size_t)b * C + t) * 2 + 1];
    float s = p0.x + p1.x, s2 = p0.y + p1.y;
    float mu = s * (1.f / 1024.f);
    float var = fmaxf(s2 * (1.f / 1024.f) - mu * mu, 0.f);
    float rstd = rsqrtf(var + 1e-5f);
    sc_l[t] = rstd; sh_l[t] = -mu * rstd;
  }
  for (int j = t; j < S * C; j += 256) {
    int s = j >> 6, c = j & 63;
    weff[j] = hcw[(a * S + s) * C + c] * hgw[a * C + c];
  }
  __syncthreads();

  float L[S][4];
#pragma unroll
  for (int s = 0; s < S; ++s)
#pragma unroll
    for (int k = 0; k < 4; ++k) L[s][k] = 0.f;

  const u32* xb = (const u32*)(x3 + (size_t)b * C * P);
  for (int c = 0; c < C; ++c) {
    float scv = sc_l[c], shv = sh_l[c];
    u32 u0 = xb[c * 512 + t];
    u32 u1 = xb[c * 512 + t + 256];
    float xv[4] = {bflo(u0) * scv + shv, bfhi(u0) * scv + shv,
                   bflo(u1) * scv + shv, bfhi(u1) * scv + shv};
#pragma unroll
    for (int s = 0; s < S; ++s) {
      float wv_ = weff[s * C + c];
#pragma unroll
      for (int k = 0; k < 4; ++k) L[s][k] += xv[k] * wv_;
    }
  }

  // ---- phase A: all 5 maxima in one interleaved reduce ----
  float m5[S];
#pragma unroll
  for (int s = 0; s < S; ++s)
    m5[s] = fmaxf(fmaxf(L[s][0], L[s][1]), fmaxf(L[s][2], L[s][3]));
#pragma unroll
  for (int off = 32; off; off >>= 1)
#pragma unroll
    for (int s = 0; s < S; ++s) m5[s] = fmaxf(m5[s], __shfl_xor(m5[s], off, 64));
  if (lane == 0) {
#pragma unroll
    for (int s = 0; s < S; ++s) redm[wv][s] = m5[s];
  }
  __syncthreads();
#pragma unroll
  for (int s = 0; s < S; ++s)
    m5[s] = fmaxf(fmaxf(redm[0][s], redm[1][s]), fmaxf(redm[2][s], redm[3][s]));

  // ---- phase B: all 15 sums (se,sx,sy per s) in one interleaved reduce ----
  float p15[15];
  const int pix[4] = {2 * t, 2 * t + 1, 512 + 2 * t, 512 + 2 * t + 1};
#pragma unroll
  for (int s = 0; s < S; ++s) {
    float se = 0.f, sx = 0.f, sy = 0.f;
#pragma unroll
    for (int k = 0; k < 4; ++k) {
      int p = pix[k];
      float e = __expf(L[s][k] - m5[s]);
      se += e;
      sx += e * ((float)(p & 31) * (2.f / 31.f) - 1.f);
      sy += e * ((float)(p >> 5) * (2.f / 31.f) - 1.f);
    }
    p15[s * 3 + 0] = se; p15[s * 3 + 1] = sx; p15[s * 3 + 2] = sy;
  }
#pragma unroll
  for (int off = 32; off; off >>= 1)
#pragma unroll
    for (int j = 0; j < 15; ++j) p15[j] += __shfl_xor(p15[j], off, 64);
  if (lane == 0) {
#pragma unroll
    for (int j = 0; j < 15; ++j) redp[wv][j] = p15[j];
  }
  __syncthreads();
  if (t < S) {
    int s = t;
    float se = redp[0][s * 3] + redp[1][s * 3] + redp[2][s * 3] + redp[3][s * 3];
    float sx = redp[0][s * 3 + 1] + redp[1][s * 3 + 1] + redp[2][s * 3 + 1] + redp[3][s * 3 + 1];
    float sy = redp[0][s * 3 + 2] + redp[1][s * 3 + 2] + redp[2][s * 3 + 2] + redp[3][s * 3 + 2];
    out[(b * S + s) * 2 + 0] = sx / se;
    out[(b * S + s) * 2 + 1] = sy / se;
  }
}

// ---------------- launcher ----------------
extern "C" void kernel_launch(void* const* d_in, const int* in_sizes, int n_in,
                              void* d_out, int out_size, void* d_ws, size_t ws_size,
                              hipStream_t stream)
{
  (void)in_sizes; (void)n_in; (void)out_size; (void)ws_size;
  const float* feat   = (const float*)d_in[0];
  const int*   action = (const int*)d_in[1];
  const float* fc_w = (const float*)d_in[3];
  const float* fc_b = (const float*)d_in[4];
  const float* gw0  = (const float*)d_in[5];
  const float* gb0  = (const float*)d_in[6];
  const float* dw0  = (const float*)d_in[7];
  const float* db0  = (const float*)d_in[8];
  const float* gw1  = (const float*)d_in[9];
  const float* gb1  = (const float*)d_in[10];
  const float* dw1  = (const float*)d_in[11];
  const float* db1  = (const float*)d_in[12];
  const float* gw2  = (const float*)d_in[13];
  const float* gb2  = (const float*)d_in[14];
  const float* dw2  = (const float*)d_in[15];
  const float* db2  = (const float*)d_in[16];
  const float* hgw  = (const float*)d_in[17];
  const float* hcw  = (const float*)d_in[19];

  float* ws = (float*)d_ws;
  u16* x0 = (u16*)(ws + OFF_REGB);
  u16* x2 = (u16*)(ws + OFF_REGB);
  u16* x1 = (u16*)(ws + OFF_REGA);
  u16* x3 = (u16*)(ws + OFF_REGA);
  u16* wt0 = (u16*)(ws + OFF_WT0);
  u16* wt1 = (u16*)(ws + OFF_WT1);
  u16* wt2 = (u16*)(ws + OFF_WT2);
  u16* wtf = (u16*)(ws + OFF_WTF);
  float2* psum = (float2*)(ws + O_PSUM);

  wtrans_all<<<1184, 256, 0, stream>>>(dw0, dw1, dw2, fc_w, wt0, wt1, wt2, wtf);
  fc_mfma<<<dim3(8, 64), 256, 0, stream>>>(feat, wtf, fc_b, gw0, gb0, x0);
  deconv_mfma<0><<<dim3(8, 128), 256, 0, stream>>>(x0, wt0, db0, x1, gw1, gb1);
  deconv_mfma<1><<<dim3(4, 512), 256, 0, stream>>>(x1, wt1, db1, x2, gw2, gb2);
  deconv2_q<<<dim3(2, 512), 256, 0, stream>>>(x2, wt2, db2, x3, psum);
  head_kernel<<<512, 256, 0, stream>>>(x3, psum, action, hgw, hcw, (float*)d_out);
}

// Round 15
// 238.744 us; speedup vs baseline: 1.9613x; 1.0072x over previous
//
#include <hip/hip_runtime.h>
#include <hip/hip_bf16.h>

#define DI __device__ __forceinline__
using u16 = unsigned short;
using u32 = unsigned int;

typedef short short8 __attribute__((ext_vector_type(8)));   // 8 bf16 (4 VGPRs)
typedef float f32x4 __attribute__((ext_vector_type(4)));

#define F4C(v, i) ((i) == 0 ? (v).x : (i) == 1 ? (v).y : (i) == 2 ? (v).z : (v).w)

DI float bflo(u32 u) { return __uint_as_float(u << 16); }
DI float bfhi(u32 u) { return __uint_as_float(u & 0xffff0000u); }
DI u16 f2bf(float a) {
  u32 xu = __float_as_uint(a);
  return (u16)((xu + 0x7fffu + ((xu >> 16) & 1)) >> 16);
}
DI u32 pack_bf16x2(float a, float b) {
  u32 xu = __float_as_uint(a), yu = __float_as_uint(b);
  xu = (xu + 0x7fffu + ((xu >> 16) & 1)) >> 16;
  yu = (yu + 0x7fffu + ((yu >> 16) & 1)) >> 16;
  return (xu & 0xffffu) | (yu << 16);
}

// ---------------- workspace layout (float units) ----------------
static constexpr size_t OFF_REGB = 0;
static constexpr size_t OFF_REGA = 16777216;
static constexpr size_t OFF_WT0  = 33554432;
static constexpr size_t OFF_WT1  = OFF_WT0 + 1179648;
static constexpr size_t OFF_WT2  = OFF_WT1 + 294912;
static constexpr size_t OFF_WTF  = OFF_WT2 + 73728;
static constexpr size_t OFF_ST   = 35200000;
static constexpr size_t O_PSUM = OFF_ST + 1048576;   // 512*64*2 float2 = 131072 floats

// ---------------- all weight pre-transposes in one launch ----------------
__global__ __launch_bounds__(256)
void wtrans_all(const float* __restrict__ dw0, const float* __restrict__ dw1,
                const float* __restrict__ dw2, const float* __restrict__ fcw,
                u16* __restrict__ wt0, u16* __restrict__ wt1,
                u16* __restrict__ wt2, u16* __restrict__ wtf)
{
  int id = blockIdx.x * 256 + threadIdx.x;
  if (id < 131072) {                       // dw0: CO=256, CI=512
    int m = id >> 9, c = id & 511;
    const float* src = dw0 + ((size_t)m * 512 + c) * 9;
#pragma unroll
    for (int tap = 0; tap < 9; ++tap)
      wt0[((size_t)tap * 256 + m) * 512 + c] = f2bf(src[tap]);
  } else if (id < 163840) {                // dw1: CO=128, CI=256
    int j = id - 131072;
    int m = j >> 8, c = j & 255;
    const float* src = dw1 + ((size_t)m * 256 + c) * 9;
#pragma unroll
    for (int tap = 0; tap < 9; ++tap)
      wt1[((size_t)tap * 128 + m) * 256 + c] = f2bf(src[tap]);
  } else if (id < 172032) {                // dw2: CO=64, CI=128
    int j = id - 163840;
    int m = j >> 7, c = j & 127;
    const float* src = dw2 + ((size_t)m * 128 + c) * 9;
#pragma unroll
    for (int tap = 0; tap < 9; ++tap)
      wt2[((size_t)tap * 64 + m) * 128 + c] = f2bf(src[tap]);
  } else {                                 // fc: wtf[d][c]
    int j = id - 172032;
    int d = j >> 8, c = j & 255;
    wtf[j] = f2bf(fcw[c * 512 + d]);
  }
}

// ---------------- fc1 via MFMA; GN0 applied in epilogue; x0 stored px-major ----------------
DI void fc_stage_A(const float* __restrict__ feat, int b, u16* Ab, int t)
{
#pragma unroll
  for (int it = 0; it < 2; ++it) {
    int idx = t + it * 256;
    int cp = idx >> 2, hw4 = idx & 3;
    int c = cp * 2;
    const float* xp = feat + ((size_t)b * 256 + c) * 16 + hw4 * 4;
    float4 v0 = *(const float4*)xp;
    float4 v1 = *(const float4*)(xp + 16);
    int c64 = c >> 6, jb = (c & 63) >> 3;
#pragma unroll
    for (int j = 0; j < 4; ++j) {
      int hw = hw4 * 4 + j;
      int row = c64 * 16 + hw;
      *(u32*)&Ab[(row << 6) + ((jb ^ (row & 7)) << 3) + (c & 7)] =
          pack_bf16x2(F4C(v0, j), F4C(v1, j));
    }
  }
}

__global__ __launch_bounds__(256, 3)
void fc_mfma(const float* __restrict__ feat, const u16* __restrict__ wtf,
             const float* __restrict__ fb, const float* __restrict__ gw,
             const float* __restrict__ gb, u16* __restrict__ x0)
{
  __shared__ __align__(16) u16 Wl[256 * 64];
  __shared__ __align__(16) u16 Al[2][64 * 64];
  const int t = threadIdx.x;
  const int lane = t & 63, wave = t >> 6;
  const int n15 = lane & 15, kq = lane >> 4;
  // XCD swizzle: XCD k owns b in [64k, 64k+64); 8 d-blocks of same b-group co-located
  const int lin = blockIdx.y * 8 + blockIdx.x;
  const int xk = lin & 7, pos = lin >> 3;          // pos 0..63
  const int d0 = (pos & 7) * 64;
  const int b0 = (xk * 8 + (pos >> 3)) * 8;

#pragma unroll
  for (int it = 0; it < 8; ++it) {
    int idx = t + it * 256;
    int dl = idx >> 5, jb32 = idx & 31;
    int row = (jb32 >> 3) * 64 + dl, jb = jb32 & 7;
    uint4 v = *(const uint4*)(wtf + (size_t)(d0 + dl) * 256 + jb32 * 8);
    *(uint4*)&Wl[(row << 6) + ((jb ^ (row & 7)) << 3)] = v;
  }
  fc_stage_A(feat, b0, Al[0], t);

  const int dg = d0 + wave * 16 + n15;
  const float bvn = fb[dg];
  const float gwv = gw[dg], gbv = gb[dg];

  for (int bi = 0; bi < 8; ++bi) {
    __syncthreads();
    if (bi + 1 < 8) fc_stage_A(feat, b0 + bi + 1, Al[(bi + 1) & 1], t);

    const u16* A = Al[bi & 1];
    f32x4 acc0 = {0.f, 0.f, 0.f, 0.f}, acc1 = {0.f, 0.f, 0.f, 0.f};
#pragma unroll
    for (int ks = 0; ks < 8; ++ks) {
      int js = ks * 4 + kq;
      int ra = (js >> 3) * 16 + n15;
      int rb = (js >> 3) * 64 + wave * 16 + n15;
      short8 av = *(const short8*)&A[(ra << 6) + (((js & 7) ^ (ra & 7)) << 3)];
      short8 bv = *(const short8*)&Wl[(rb << 6) + (((js & 7) ^ (rb & 7)) << 3)];
      if (ks & 1) acc1 = __builtin_amdgcn_mfma_f32_16x16x32_bf16(av, bv, acc1, 0, 0, 0);
      else        acc0 = __builtin_amdgcn_mfma_f32_16x16x32_bf16(av, bv, acc0, 0, 0, 0);
    }

    int b = b0 + bi;
    float v[4], s = 0.f, s2 = 0.f;
#pragma unroll
    for (int r = 0; r < 4; ++r) {
      v[r] = fmaxf(acc0[r] + acc1[r] + bvn, 0.f);
      s += v[r]; s2 += v[r] * v[r];
    }
    s  += __shfl_xor(s, 16, 64);  s  += __shfl_xor(s, 32, 64);
    s2 += __shfl_xor(s2, 16, 64); s2 += __shfl_xor(s2, 32, 64);
    // GN0 applied here: every lane has full 16-px sums after the butterfly.
    float mu = s * (1.f / 16.f);
    float var = fmaxf(s2 * (1.f / 16.f) - mu * mu, 0.f);
    float scale = gwv * rsqrtf(var + 1e-5f);
    float shift = gbv - mu * scale;
    // x0 layout px-major [b][16 px][512 d]; lane's 4 values are px kq*4+r, channel dg
    u16* yp = x0 + ((size_t)b * 16 + kq * 4) * 512 + dg;
#pragma unroll
    for (int r = 0; r < 4; ++r) yp[(size_t)r * 512] = f2bf(v[r] * scale + shift);
  }
}

// ---------------- deconv stages 0/1: inputs pre-normalized px-major; pure-copy stage-X
// STAGE 0: reads x0 px-major [b][16px][512c], writes x1 px-major [b][64px][256c].
// STAGE 1: reads x1 px-major, writes x2 px-major [b][256px][128c].
//          NB=2: one block covers 2 b's, W staged once per ch and reused (two X sub-phases).
template<int STAGE>
__global__ __launch_bounds__(256, 3)
void deconv_mfma(const u16* __restrict__ x, const u16* __restrict__ wt,
                 const float* __restrict__ bias, u16* __restrict__ y,
                 const float* __restrict__ gwn, const float* __restrict__ gbn)
{
  constexpr int CI  = STAGE == 0 ? 512 : 256;
  constexpr int CO  = CI / 2;
  constexpr int H   = STAGE == 0 ? 4 : 8;
  constexpr int WP  = H + 1;
  constexpr int XROWS = STAGE == 0 ? 100 : 81;
  constexpr int NCH = CI / 64;
  constexpr int NB  = STAGE == 0 ? 1 : 2;
  __shared__ __align__(16) u16 Wl[288 * 64];
  __shared__ __align__(16) u16 Xl[XROWS * 64];
  __shared__ float2 sbuf[2][2][16];
  __shared__ float scl[32], shl[32];

  const int t = threadIdx.x;
  const int lane = t & 63, wave = t >> 6;
  const int ms = wave >> 1, ns = wave & 1;
  const int n15 = lane & 15, kq = lane >> 4;

  // XCD swizzle: XCD k owns b in [64k, 64k+64); all m-blocks of a b co-located
  int m0, b0;
  if constexpr (STAGE == 0) {
    int lin = blockIdx.y * 8 + blockIdx.x;       // 1024 blocks
    int xk = lin & 7, pos = lin >> 3;            // pos 0..127
    m0 = (pos & 7) * 32;
    b0 = (xk * 16 + (pos >> 3)) * 4;
  } else {
    int lin = blockIdx.y * 4 + blockIdx.x;       // 1024 blocks
    int xk = lin & 7, pos = lin >> 3;            // pos 0..127
    m0 = (pos & 3) * 32;
    b0 = xk * 64 + (pos >> 2) * 2;               // 2 b's per block
  }

  int xrow[2];
#pragma unroll
  for (int ni = 0; ni < 2; ++ni) {
    if constexpr (STAGE == 0) xrow[ni] = (ns * 2 + ni) * 25 + (n15 >> 2) * 5 + (n15 & 3);
    else                      xrow[ni] = (2 * (ns * 2 + ni) + (n15 >> 3)) * 9 + (n15 & 7);
  }
  const int am = ms * 16 + n15;

  for (int i = t; i < XROWS * 32; i += 256) ((u32*)Xl)[i] = 0;

  f32x4 acc[NB][2][4];
#pragma unroll
  for (int bh = 0; bh < NB; ++bh)
#pragma unroll
    for (int ni = 0; ni < 2; ++ni)
#pragma unroll
      for (int c = 0; c < 4; ++c) acc[bh][ni][c] = f32x4{0.f, 0.f, 0.f, 0.f};

  auto stage_X = [&](int bh, int c0) {
    if constexpr (STAGE == 0) {
      for (int idx = t; idx < 64 * 8; idx += 256) {
        int pxl = idx >> 3, jb = idx & 7;
        int img = pxl >> 4, p = pxl & 15;
        int iy = p >> 2, ix = p & 3;
        uint4 q = *(const uint4*)(x + ((size_t)(b0 + img) * 16 + p) * 512 + c0 + jb * 8);
        int row = img * 25 + iy * 5 + ix;
        *(uint4*)&Xl[(row << 6) + ((jb ^ (row & 7)) << 3)] = q;
      }
    } else {
      for (int idx = t; idx < 64 * 8; idx += 256) {
        int pxl = idx >> 3, jb = idx & 7;
        int py = pxl >> 3, px_ = pxl & 7;
        uint4 q = *(const uint4*)(x + ((size_t)(b0 + bh) * 64 + pxl) * 256 + c0 + jb * 8);
        int row = py * 9 + px_;
        *(uint4*)&Xl[(row << 6) + ((jb ^ (row & 7)) << 3)] = q;
      }
    }
  };

  auto do_mfma = [&](f32x4 (&ac)[2][4]) {
#pragma unroll
    for (int s = 0; s < 2; ++s) {
      const int js = s * 4 + kq;
      short8 a[9];
#pragma unroll
      for (int tap = 0; tap < 9; ++tap) {
        int row = tap * 32 + am;
        a[tap] = *(const short8*)&Wl[(row << 6) + ((js ^ (row & 7)) << 3)];
      }
#pragma unroll
      for (int ni = 0; ni < 2; ++ni) {
        int r0 = xrow[ni], r1 = r0 + 1, r2 = r0 + WP, r3 = r0 + WP + 1;
        short8 b00 = *(const short8*)&Xl[(r0 << 6) + ((js ^ (r0 & 7)) << 3)];
        short8 b01 = *(const short8*)&Xl[(r1 << 6) + ((js ^ (r1 & 7)) << 3)];
        short8 b10 = *(const short8*)&Xl[(r2 << 6) + ((js ^ (r2 & 7)) << 3)];
        short8 b11 = *(const short8*)&Xl[(r3 << 6) + ((js ^ (r3 & 7)) << 3)];
        ac[ni][0] = __builtin_amdgcn_mfma_f32_16x16x32_bf16(a[4], b00, ac[ni][0], 0, 0, 0);
        ac[ni][1] = __builtin_amdgcn_mfma_f32_16x16x32_bf16(a[3], b00, ac[ni][1], 0, 0, 0);
        ac[ni][1] = __builtin_amdgcn_mfma_f32_16x16x32_bf16(a[5], b01, ac[ni][1], 0, 0, 0);
        ac[ni][2] = __builtin_amdgcn_mfma_f32_16x16x32_bf16(a[1], b00, ac[ni][2], 0, 0, 0);
        ac[ni][2] = __builtin_amdgcn_mfma_f32_16x16x32_bf16(a[7], b10, ac[ni][2], 0, 0, 0);
        ac[ni][3] = __builtin_amdgcn_mfma_f32_16x16x32_bf16(a[0], b00, ac[ni][3], 0, 0, 0);
        ac[ni][3] = __builtin_amdgcn_mfma_f32_16x16x32_bf16(a[2], b01, ac[ni][3], 0, 0, 0);
        ac[ni][3] = __builtin_amdgcn_mfma_f32_16x16x32_bf16(a[6], b10, ac[ni][3], 0, 0, 0);
        ac[ni][3] = __builtin_amdgcn_mfma_f32_16x16x32_bf16(a[8], b11, ac[ni][3], 0, 0, 0);
      }
    }
  };

  for (int ch = 0; ch < NCH; ++ch) {
    const int c0 = ch * 64;
    __syncthreads();

#pragma unroll
    for (int it = 0; it < 9; ++it) {
      int idx = t + it * 256;
      int row = idx >> 3, jb = idx & 7;
      int tap = row >> 5, ml = row & 31;
      uint4 v = *(const uint4*)(wt + ((size_t)(tap * CO + m0 + ml)) * CI + c0 + jb * 8);
      *(uint4*)&Wl[(row << 6) + ((jb ^ (row & 7)) << 3)] = v;
    }
    stage_X(0, c0);
    __syncthreads();
    do_mfma(acc[0]);

    if constexpr (NB == 2) {
      __syncthreads();          // protect Xl while prior MFMA reads done
      stage_X(1, c0);
      __syncthreads();
      do_mfma(acc[1]);
    }
  }

  // ---- epilogue: bias + relu + next-GN normalize + store ----
  float bv[4];
#pragma unroll
  for (int r = 0; r < 4; ++r) bv[r] = bias[m0 + ms * 16 + kq * 4 + r];

  if constexpr (STAGE == 0) {
    float gw4[4], gb4[4];
#pragma unroll
    for (int r = 0; r < 4; ++r) {
      int m = m0 + ms * 16 + kq * 4 + r;
      gw4[r] = gwn[m]; gb4[r] = gbn[m];
    }
#pragma unroll
    for (int ni = 0; ni < 2; ++ni) {
      int b = b0 + ns * 2 + ni, iy = n15 >> 2, ix = n15 & 3;
      float val[4][4];
      float sr[4] = {0.f, 0.f, 0.f, 0.f}, sr2[4] = {0.f, 0.f, 0.f, 0.f};
#pragma unroll
      for (int cl = 0; cl < 4; ++cl)
#pragma unroll
        for (int r = 0; r < 4; ++r) {
          val[cl][r] = fmaxf(acc[0][ni][cl][r] + bv[r], 0.f);
          sr[r] += val[cl][r]; sr2[r] += val[cl][r] * val[cl][r];
        }
#pragma unroll
      for (int r = 0; r < 4; ++r) {
#pragma unroll
        for (int off = 1; off <= 8; off <<= 1) {
          sr[r]  += __shfl_xor(sr[r], off, 64);
          sr2[r] += __shfl_xor(sr2[r], off, 64);
        }
      }
      // full 64-px stats now in all lanes -> normalize in-lane, store normalized px-major
      float scv[4], shv[4];
#pragma unroll
      for (int r = 0; r < 4; ++r) {
        float mu = sr[r] * (1.f / 64.f);
        float var = fmaxf(sr2[r] * (1.f / 64.f) - mu * mu, 0.f);
        scv[r] = gw4[r] * rsqrtf(var + 1e-5f);
        shv[r] = gb4[r] - mu * scv[r];
      }
      // x1 layout [b][8x8 px][256 c]
#pragma unroll
      for (int cl = 0; cl < 4; ++cl) {
        int oy = 2 * iy + (cl >> 1), ox = 2 * ix + (cl & 1);
        size_t base = ((size_t)b * 64 + oy * 8 + ox) * 256 + m0 + ms * 16 + kq * 4;
        uint2 pk = {pack_bf16x2(val[cl][0] * scv[0] + shv[0],
                                val[cl][1] * scv[1] + shv[1]),
                    pack_bf16x2(val[cl][2] * scv[2] + shv[2],
                                val[cl][3] * scv[3] + shv[3])};
        *(uint2*)(y + base) = pk;
      }
    }
  } else {
    for (int bh = 0; bh < NB; ++bh) {
      const int bcur = b0 + bh;
      float sr[4] = {0.f, 0.f, 0.f, 0.f}, sr2[4] = {0.f, 0.f, 0.f, 0.f};
#pragma unroll
      for (int ni = 0; ni < 2; ++ni)
#pragma unroll
        for (int cl = 0; cl < 4; ++cl)
#pragma unroll
          for (int r = 0; r < 4; ++r) {
            float v = fmaxf(acc[bh][ni][cl][r] + bv[r], 0.f);
            sr[r] += v; sr2[r] += v * v;
          }
#pragma unroll
      for (int r = 0; r < 4; ++r) {
#pragma unroll
        for (int off = 1; off <= 8; off <<= 1) {
          sr[r]  += __shfl_xor(sr[r], off, 64);
          sr2[r] += __shfl_xor(sr2[r], off, 64);
        }
      }
      __syncthreads();
      if (n15 == 0) {
#pragma unroll
        for (int r = 0; r < 4; ++r) sbuf[ms][ns][kq * 4 + r] = float2{sr[r], sr2[r]};
      }
      __syncthreads();
      if (t < 32) {
        int msx = t >> 4, i = t & 15;
        float2 p0 = sbuf[msx][0][i], p1 = sbuf[msx][1][i];
        float s = p0.x + p1.x, s2 = p0.y + p1.y;
        float mu = s * (1.f / 256.f);
        float var = fmaxf(s2 * (1.f / 256.f) - mu * mu, 0.f);
        int m = m0 + msx * 16 + i;
        float scale = gwn[m] * rsqrtf(var + 1e-5f);
        scl[t] = scale;
        shl[t] = gbn[m] - mu * scale;
      }
      __syncthreads();
      float scv[4], shv[4];
#pragma unroll
      for (int r = 0; r < 4; ++r) {
        scv[r] = scl[ms * 16 + kq * 4 + r];
        shv[r] = shl[ms * 16 + kq * 4 + r];
      }
      // x2 layout [b][256 px][128 c], stored pre-normalized
#pragma unroll
      for (int ni = 0; ni < 2; ++ni) {
        int iy = 2 * (ns * 2 + ni) + (n15 >> 3), ix = n15 & 7;
#pragma unroll
        for (int cl = 0; cl < 4; ++cl) {
          int opx = (2 * iy + (cl >> 1)) * 16 + 2 * ix + (cl & 1);
          size_t base = ((size_t)bcur * 256 + opx) * 128 + m0 + ms * 16 + kq * 4;
          float v0 = fmaxf(acc[bh][ni][cl][0] + bv[0], 0.f) * scv[0] + shv[0];
          float v1 = fmaxf(acc[bh][ni][cl][1] + bv[1], 0.f) * scv[1] + shv[1];
          float v2 = fmaxf(acc[bh][ni][cl][2] + bv[2], 0.f) * scv[2] + shv[2];
          float v3 = fmaxf(acc[bh][ni][cl][3] + bv[3], 0.f) * scv[3] + shv[3];
          *(u32*)(y + base)     = pack_bf16x2(v0, v1);
          *(u32*)(y + base + 2) = pack_bf16x2(v2, v3);
        }
      }
    }
  }
}

// ---------------- stage-2 deconv: merged m-halves; X staged once, reused by both m ----------------
#define XRD(ch, row) (*(const short8*)&Xl[ch][((row) << 6) + (((js ^ ((row) & 7))) << 3)])
__global__ __launch_bounds__(256, 2)
void deconv2_q(const u16* __restrict__ x, const u16* __restrict__ wt,
               const float* __restrict__ bias, u16* __restrict__ y,
               float2* __restrict__ psum)
{
  __shared__ __align__(16) u16 Wl[288 * 64];
  __shared__ __align__(16) u16 Xl[2][153 * 64]; // both ch chunks resident; halo stays 0
  __shared__ float2 sbuf[2][2][16];

  const int t = threadIdx.x;
  const int lane = t & 63, wave = t >> 6;
  const int ms = wave >> 1, ns = wave & 1;
  const int n15 = lane & 15, kq = lane >> 4;
  // XCD swizzle: XCD k owns b in [64k, 64k+64)
  const int lin = blockIdx.y * 2 + blockIdx.x;   // 1024 blocks
  const int xk = lin & 7, pos = lin >> 3;        // pos 0..127
  const int b   = xk * 64 + (pos >> 1);
  const int qz2 = pos & 1;                       // 0..1 (16 output rows each)

  for (int i = t; i < 2 * 153 * 32; i += 256) ((u32*)Xl)[i] = 0;

  const int am = ms * 16 + n15;
  const int xr0 = (ns * 4) * 17 + n15;

  const int NPX = (qz2 == 0) ? 144 : 128;     // input rows 0..8 / 8..15 (+zero halo)

  for (int mh = 0; mh < 2; ++mh) {
    const int m0 = mh * 32;

    f32x4 acc[4][4];
#pragma unroll
    for (int ni = 0; ni < 4; ++ni)
#pragma unroll
      for (int c = 0; c < 4; ++c) acc[ni][c] = f32x4{0.f, 0.f, 0.f, 0.f};

    for (int ch = 0; ch < 2; ++ch) {
      const int c0 = ch * 64;
      __syncthreads();

      // ---- stage W: 288 rows (tap*32+ml) x 8 blocks ----
#pragma unroll
      for (int it = 0; it < 9; ++it) {
        int idx = t + it * 256;
        int row = idx >> 3, jb = idx & 7;
        int tap = row >> 5, ml = row & 31;
        uint4 v = *(const uint4*)(wt + ((size_t)(tap * 64 + m0 + ml)) * 128 + c0 + jb * 8);
        *(uint4*)&Wl[(row << 6) + ((jb ^ (row & 7)) << 3)] = v;
      }

      // ---- stage X only in first m-pass: both m-halves reuse it ----
      if (mh == 0) {
        for (int idx = t; idx < NPX * 8; idx += 256) {
          int pxl = idx >> 3, jb = idx & 7;
          int rl = pxl >> 4, ix = pxl & 15;
          int gpx = (8 * qz2 + rl) * 16 + ix;
          uint4 q = *(const uint4*)(x + ((size_t)b * 256 + gpx) * 128 + c0 + jb * 8);
          int row = rl * 17 + ix;
          *(uint4*)&Xl[ch][(row << 6) + ((jb ^ (row & 7)) << 3)] = q;
        }
      }
      __syncthreads();

#pragma unroll
      for (int s = 0; s < 2; ++s) {
        const int js = s * 4 + kq;
        short8 a[9];
#pragma unroll
        for (int tap = 0; tap < 9; ++tap) {
          int row = tap * 32 + am;
          a[tap] = *(const short8*)&Wl[(row << 6) + ((js ^ (row & 7)) << 3)];
        }
        // 10 B rows shared across the wave's 4 adjacent n-tiles
        short8 Brow[10];
#pragma unroll
        for (int k = 0; k < 5; ++k) {
          Brow[2 * k]     = XRD(ch, xr0 + 17 * k);
          Brow[2 * k + 1] = XRD(ch, xr0 + 17 * k + 1);
        }
        __builtin_amdgcn_s_setprio(1);
#pragma unroll
        for (int ni = 0; ni < 4; ++ni) {
          short8 b00 = Brow[2 * ni],     b01 = Brow[2 * ni + 1];
          short8 b10 = Brow[2 * ni + 2], b11 = Brow[2 * ni + 3];
          acc[ni][0] = __builtin_amdgcn_mfma_f32_16x16x32_bf16(a[4], b00, acc[ni][0], 0, 0, 0);
          acc[ni][1] = __builtin_amdgcn_mfma_f32_16x16x32_bf16(a[3], b00, acc[ni][1], 0, 0, 0);
          acc[ni][1] = __builtin_amdgcn_mfma_f32_16x16x32_bf16(a[5], b01, acc[ni][1], 0, 0, 0);
          acc[ni][2] = __builtin_amdgcn_mfma_f32_16x16x32_bf16(a[1], b00, acc[ni][2], 0, 0, 0);
          acc[ni][2] = __builtin_amdgcn_mfma_f32_16x16x32_bf16(a[7], b10, acc[ni][2], 0, 0, 0);
          acc[ni][3] = __builtin_amdgcn_mfma_f32_16x16x32_bf16(a[0], b00, acc[ni][3], 0, 0, 0);
          acc[ni][3] = __builtin_amdgcn_mfma_f32_16x16x32_bf16(a[2], b01, acc[ni][3], 0, 0, 0);
          acc[ni][3] = __builtin_amdgcn_mfma_f32_16x16x32_bf16(a[6], b10, acc[ni][3], 0, 0, 0);
          acc[ni][3] = __builtin_amdgcn_mfma_f32_16x16x32_bf16(a[8], b11, acc[ni][3], 0, 0, 0);
        }
        __builtin_amdgcn_s_setprio(0);
      }
    }

    // ---- epilogue for this m-half: bias + relu + store + stat partials ----
    float bv[4];
#pragma unroll
    for (int r = 0; r < 4; ++r) bv[r] = bias[m0 + ms * 16 + kq * 4 + r];
    float sr[4] = {0.f, 0.f, 0.f, 0.f}, sr2[4] = {0.f, 0.f, 0.f, 0.f};
#pragma unroll
    for (int ni = 0; ni < 4; ++ni) {
      int iy = 8 * qz2 + ns * 4 + ni, ix = n15;
#pragma unroll
      for (int r = 0; r < 4; ++r) {
        int m = m0 + ms * 16 + kq * 4 + r;
        float v00 = fmaxf(acc[ni][0][r] + bv[r], 0.f);
        float v01 = fmaxf(acc[ni][1][r] + bv[r], 0.f);
        float v10 = fmaxf(acc[ni][2][r] + bv[r], 0.f);
        float v11 = fmaxf(acc[ni][3][r] + bv[r], 0.f);
        size_t base = ((size_t)b * 64 + m) * 1024 + (size_t)(2 * iy) * 32 + 2 * ix;
        *(u32*)(y + base)      = pack_bf16x2(v00, v01);
        *(u32*)(y + base + 32) = pack_bf16x2(v10, v11);
        sr[r]  += v00 + v01 + v10 + v11;
        sr2[r] += v00 * v00 + v01 * v01 + v10 * v10 + v11 * v11;
      }
    }
#pragma unroll
    for (int r = 0; r < 4; ++r) {
#pragma unroll
      for (int off = 1; off <= 8; off <<= 1) {
        sr[r]  += __shfl_xor(sr[r], off, 64);
        sr2[r] += __shfl_xor(sr2[r], off, 64);
      }
    }
    __syncthreads();
    if (n15 == 0) {
#pragma unroll
      for (int r = 0; r < 4; ++r) sbuf[ms][ns][kq * 4 + r] = float2{sr[r], sr2[r]};
    }
    __syncthreads();
    if (t < 32) {
      int msx = t >> 4, i = t & 15;
      float2 p0 = sbuf[msx][0][i], p1 = sbuf[msx][1][i];
      int m = m0 + msx * 16 + i;
      psum[((size_t)b * 64 + m) * 2 + qz2] = float2{p0.x + p1.x, p0.y + p1.y};
    }
  }
}

// ---------------- head: fold stat partials -> norm -> 1x1 conv -> spatial softmax ----------------
// Batched reductions: 3 barriers total.
__global__ __launch_bounds__(256)
void head_kernel(const u16* __restrict__ x3, const float2* __restrict__ psum,
                 const int* __restrict__ action, const float* __restrict__ hgw,
                 const float* __restrict__ hcw, float* __restrict__ out)
{
  constexpr int C = 64, S = 5, P = 1024;
  const int t = threadIdx.x;
  const int lane = t & 63, wv = t >> 6;
  const int b = (blockIdx.x & 7) * 64 + (blockIdx.x >> 3);   // XCD-consistent b mapping
  const int a = action[b];
  __shared__ float weff[S * C];
  __shared__ float sc_l[C], sh_l[C];
  __shared__ float redm[4][8];    // per-wave maxima (5 used)
  __shared__ float redp[4][16];   // per-wave partial sums (15 used)
  if (t < C) {
    float2 p0 = psum[((size_t)b * C + t) * 2 + 0];
    float2 p1 = psum[((size_t)b * C + t) * 2 + 1];
    float s = p0.x + p1.x, s2 = p0.y + p1.y;
    float mu = s * (1.f / 1024.f);
    float var = fmaxf(s2 * (1.f / 1024.f) - mu * mu, 0.f);
    float rstd = rsqrtf(var + 1e-5f);
    sc_l[t] = rstd; sh_l[t] = -mu * rstd;
  }
  for (int j = t; j < S * C; j += 256) {
    int s = j >> 6, c = j & 63;
    weff[j] = hcw[(a * S + s) * C + c] * hgw[a * C + c];
  }
  __syncthreads();

  float L[S][4];
#pragma unroll
  for (int s = 0; s < S; ++s)
#pragma unroll
    for (int k = 0; k < 4; ++k) L[s][k] = 0.f;

  const u32* xb = (const u32*)(x3 + (size_t)b * C * P);
  for (int c = 0; c < C; ++c) {
    float scv = sc_l[c], shv = sh_l[c];
    u32 u0 = xb[c * 512 + t];
    u32 u1 = xb[c * 512 + t + 256];
    float xv[4] = {bflo(u0) * scv + shv, bfhi(u0) * scv + shv,
                   bflo(u1) * scv + shv, bfhi(u1) * scv + shv};
#pragma unroll
    for (int s = 0; s < S; ++s) {
      float wv_ = weff[s * C + c];
#pragma unroll
      for (int k = 0; k < 4; ++k) L[s][k] += xv[k] * wv_;
    }
  }

  // ---- phase A: all 5 maxima in one interleaved reduce ----
  float m5[S];
#pragma unroll
  for (int s = 0; s < S; ++s)
    m5[s] = fmaxf(fmaxf(L[s][0], L[s][1]), fmaxf(L[s][2], L[s][3]));
#pragma unroll
  for (int off = 32; off; off >>= 1)
#pragma unroll
    for (int s = 0; s < S; ++s) m5[s] = fmaxf(m5[s], __shfl_xor(m5[s], off, 64));
  if (lane == 0) {
#pragma unroll
    for (int s = 0; s < S; ++s) redm[wv][s] = m5[s];
  }
  __syncthreads();
#pragma unroll
  for (int s = 0; s < S; ++s)
    m5[s] = fmaxf(fmaxf(redm[0][s], redm[1][s]), fmaxf(redm[2][s], redm[3][s]));

  // ---- phase B: all 15 sums (se,sx,sy per s) in one interleaved reduce ----
  float p15[15];
  const int pix[4] = {2 * t, 2 * t + 1, 512 + 2 * t, 512 + 2 * t + 1};
#pragma unroll
  for (int s = 0; s < S; ++s) {
    float se = 0.f, sx = 0.f, sy = 0.f;
#pragma unroll
    for (int k = 0; k < 4; ++k) {
      int p = pix[k];
      float e = __expf(L[s][k] - m5[s]);
      se += e;
      sx += e * ((float)(p & 31) * (2.f / 31.f) - 1.f);
      sy += e * ((float)(p >> 5) * (2.f / 31.f) - 1.f);
    }
    p15[s * 3 + 0] = se; p15[s * 3 + 1] = sx; p15[s * 3 + 2] = sy;
  }
#pragma unroll
  for (int off = 32; off; off >>= 1)
#pragma unroll
    for (int j = 0; j < 15; ++j) p15[j] += __shfl_xor(p15[j], off, 64);
  if (lane == 0) {
#pragma unroll
    for (int j = 0; j < 15; ++j) redp[wv][j] = p15[j];
  }
  __syncthreads();
  if (t < S) {
    int s = t;
    float se = redp[0][s * 3] + redp[1][s * 3] + redp[2][s * 3] + redp[3][s * 3];
    float sx = redp[0][s * 3 + 1] + redp[1][s * 3 + 1] + redp[2][s * 3 + 1] + redp[3][s * 3 + 1];
    float sy = redp[0][s * 3 + 2] + redp[1][s * 3 + 2] + redp[2][s * 3 + 2] + redp[3][s * 3 + 2];
    out[(b * S + s) * 2 + 0] = sx / se;
    out[(b * S + s) * 2 + 1] = sy / se;
  }
}

// ---------------- launcher ----------------
extern "C" void kernel_launch(void* const* d_in, const int* in_sizes, int n_in,
                              void* d_out, int out_size, void* d_ws, size_t ws_size,
                              hipStream_t stream)
{
  (void)in_sizes; (void)n_in; (void)out_size; (void)ws_size;
  const float* feat   = (const float*)d_in[0];
  const int*   action = (const int*)d_in[1];
  const float* fc_w = (const float*)d_in[3];
  const float* fc_b = (const float*)d_in[4];
  const float* gw0  = (const float*)d_in[5];
  const float* gb0  = (const float*)d_in[6];
  const float* dw0  = (const float*)d_in[7];
  const float* db0  = (const float*)d_in[8];
  const float* gw1  = (const float*)d_in[9];
  const float* gb1  = (const float*)d_in[10];
  const float* dw1  = (const float*)d_in[11];
  const float* db1  = (const float*)d_in[12];
  const float* gw2  = (const float*)d_in[13];
  const float* gb2  = (const float*)d_in[14];
  const float* dw2  = (const float*)d_in[15];
  const float* db2  = (const float*)d_in[16];
  const float* hgw  = (const float*)d_in[17];
  const float* hcw  = (const float*)d_in[19];

  float* ws = (float*)d_ws;
  u16* x0 = (u16*)(ws + OFF_REGB);
  u16* x2 = (u16*)(ws + OFF_REGB);
  u16* x1 = (u16*)(ws + OFF_REGA);
  u16* x3 = (u16*)(ws + OFF_REGA);
  u16* wt0 = (u16*)(ws + OFF_WT0);
  u16* wt1 = (u16*)(ws + OFF_WT1);
  u16* wt2 = (u16*)(ws + OFF_WT2);
  u16* wtf = (u16*)(ws + OFF_WTF);
  float2* psum = (float2*)(ws + O_PSUM);

  wtrans_all<<<1184, 256, 0, stream>>>(dw0, dw1, dw2, fc_w, wt0, wt1, wt2, wtf);
  fc_mfma<<<dim3(8, 64), 256, 0, stream>>>(feat, wtf, fc_b, gw0, gb0, x0);
  deconv_mfma<0><<<dim3(8, 128), 256, 0, stream>>>(x0, wt0, db0, x1, gw1, gb1);
  deconv_mfma<1><<<dim3(4, 256), 256, 0, stream>>>(x1, wt1, db1, x2, gw2, gb2);
  deconv2_q<<<dim3(2, 512), 256, 0, stream>>>(x2, wt2, db2, x3, psum);
  head_kernel<<<512, 256, 0, stream>>>(x3, psum, action, hgw, hcw, (float*)d_out);
}

// Round 16
// 236.880 us; speedup vs baseline: 1.9767x; 1.0079x over previous
//
#include <hip/hip_runtime.h>
#include <hip/hip_bf16.h>

#define DI __device__ __forceinline__
using u16 = unsigned short;
using u32 = unsigned int;

typedef short short8 __attribute__((ext_vector_type(8)));   // 8 bf16 (4 VGPRs)
typedef float f32x4 __attribute__((ext_vector_type(4)));

#define F4C(v, i) ((i) == 0 ? (v).x : (i) == 1 ? (v).y : (i) == 2 ? (v).z : (v).w)

DI float bflo(u32 u) { return __uint_as_float(u << 16); }
DI float bfhi(u32 u) { return __uint_as_float(u & 0xffff0000u); }
DI u16 f2bf(float a) {
  u32 xu = __float_as_uint(a);
  return (u16)((xu + 0x7fffu + ((xu >> 16) & 1)) >> 16);
}
DI u32 pack_bf16x2(float a, float b) {
  u32 xu = __float_as_uint(a), yu = __float_as_uint(b);
  xu = (xu + 0x7fffu + ((xu >> 16) & 1)) >> 16;
  yu = (yu + 0x7fffu + ((yu >> 16) & 1)) >> 16;
  return (xu & 0xffffu) | (yu << 16);
}

// ---------------- workspace layout (float units) ----------------
static constexpr size_t OFF_REGB = 0;
static constexpr size_t OFF_REGA = 16777216;
static constexpr size_t OFF_WT0  = 33554432;
static constexpr size_t OFF_WT1  = OFF_WT0 + 1179648;
static constexpr size_t OFF_WT2  = OFF_WT1 + 294912;
static constexpr size_t OFF_WTF  = OFF_WT2 + 73728;
static constexpr size_t OFF_ST   = 35200000;
static constexpr size_t O_PSUM = OFF_ST + 1048576;   // 512*64*2 float2 = 131072 floats

// ---------------- all weight pre-transposes in one launch ----------------
__global__ __launch_bounds__(256)
void wtrans_all(const float* __restrict__ dw0, const float* __restrict__ dw1,
                const float* __restrict__ dw2, const float* __restrict__ fcw,
                u16* __restrict__ wt0, u16* __restrict__ wt1,
                u16* __restrict__ wt2, u16* __restrict__ wtf)
{
  int id = blockIdx.x * 256 + threadIdx.x;
  if (id < 131072) {                       // dw0: CO=256, CI=512
    int m = id >> 9, c = id & 511;
    const float* src = dw0 + ((size_t)m * 512 + c) * 9;
#pragma unroll
    for (int tap = 0; tap < 9; ++tap)
      wt0[((size_t)tap * 256 + m) * 512 + c] = f2bf(src[tap]);
  } else if (id < 163840) {                // dw1: CO=128, CI=256
    int j = id - 131072;
    int m = j >> 8, c = j & 255;
    const float* src = dw1 + ((size_t)m * 256 + c) * 9;
#pragma unroll
    for (int tap = 0; tap < 9; ++tap)
      wt1[((size_t)tap * 128 + m) * 256 + c] = f2bf(src[tap]);
  } else if (id < 172032) {                // dw2: CO=64, CI=128
    int j = id - 163840;
    int m = j >> 7, c = j & 127;
    const float* src = dw2 + ((size_t)m * 128 + c) * 9;
#pragma unroll
    for (int tap = 0; tap < 9; ++tap)
      wt2[((size_t)tap * 64 + m) * 128 + c] = f2bf(src[tap]);
  } else {                                 // fc: wtf[d][c]
    int j = id - 172032;
    int d = j >> 8, c = j & 255;
    wtf[j] = f2bf(fcw[c * 512 + d]);
  }
}

// ---------------- fc1 via MFMA; GN0 applied in epilogue; x0 stored px-major ----------------
DI void fc_stage_A(const float* __restrict__ feat, int b, u16* Ab, int t)
{
#pragma unroll
  for (int it = 0; it < 2; ++it) {
    int idx = t + it * 256;
    int cp = idx >> 2, hw4 = idx & 3;
    int c = cp * 2;
    const float* xp = feat + ((size_t)b * 256 + c) * 16 + hw4 * 4;
    float4 v0 = *(const float4*)xp;
    float4 v1 = *(const float4*)(xp + 16);
    int c64 = c >> 6, jb = (c & 63) >> 3;
#pragma unroll
    for (int j = 0; j < 4; ++j) {
      int hw = hw4 * 4 + j;
      int row = c64 * 16 + hw;
      *(u32*)&Ab[(row << 6) + ((jb ^ (row & 7)) << 3) + (c & 7)] =
          pack_bf16x2(F4C(v0, j), F4C(v1, j));
    }
  }
}

__global__ __launch_bounds__(256, 3)
void fc_mfma(const float* __restrict__ feat, const u16* __restrict__ wtf,
             const float* __restrict__ fb, const float* __restrict__ gw,
             const float* __restrict__ gb, u16* __restrict__ x0)
{
  __shared__ __align__(16) u16 Wl[256 * 64];
  __shared__ __align__(16) u16 Al[2][64 * 64];
  const int t = threadIdx.x;
  const int lane = t & 63, wave = t >> 6;
  const int n15 = lane & 15, kq = lane >> 4;
  // XCD swizzle: XCD k owns b in [64k, 64k+64); 8 d-blocks of same b-group co-located
  const int lin = blockIdx.y * 8 + blockIdx.x;
  const int xk = lin & 7, pos = lin >> 3;          // pos 0..63
  const int d0 = (pos & 7) * 64;
  const int b0 = (xk * 8 + (pos >> 3)) * 8;

#pragma unroll
  for (int it = 0; it < 8; ++it) {
    int idx = t + it * 256;
    int dl = idx >> 5, jb32 = idx & 31;
    int row = (jb32 >> 3) * 64 + dl, jb = jb32 & 7;
    uint4 v = *(const uint4*)(wtf + (size_t)(d0 + dl) * 256 + jb32 * 8);
    *(uint4*)&Wl[(row << 6) + ((jb ^ (row & 7)) << 3)] = v;
  }
  fc_stage_A(feat, b0, Al[0], t);

  const int dg = d0 + wave * 16 + n15;
  const float bvn = fb[dg];
  const float gwv = gw[dg], gbv = gb[dg];

  for (int bi = 0; bi < 8; ++bi) {
    __syncthreads();
    if (bi + 1 < 8) fc_stage_A(feat, b0 + bi + 1, Al[(bi + 1) & 1], t);

    const u16* A = Al[bi & 1];
    f32x4 acc0 = {0.f, 0.f, 0.f, 0.f}, acc1 = {0.f, 0.f, 0.f, 0.f};
#pragma unroll
    for (int ks = 0; ks < 8; ++ks) {
      int js = ks * 4 + kq;
      int ra = (js >> 3) * 16 + n15;
      int rb = (js >> 3) * 64 + wave * 16 + n15;
      short8 av = *(const short8*)&A[(ra << 6) + (((js & 7) ^ (ra & 7)) << 3)];
      short8 bv = *(const short8*)&Wl[(rb << 6) + (((js & 7) ^ (rb & 7)) << 3)];
      if (ks & 1) acc1 = __builtin_amdgcn_mfma_f32_16x16x32_bf16(av, bv, acc1, 0, 0, 0);
      else        acc0 = __builtin_amdgcn_mfma_f32_16x16x32_bf16(av, bv, acc0, 0, 0, 0);
    }

    int b = b0 + bi;
    float v[4], s = 0.f, s2 = 0.f;
#pragma unroll
    for (int r = 0; r < 4; ++r) {
      v[r] = fmaxf(acc0[r] + acc1[r] + bvn, 0.f);
      s += v[r]; s2 += v[r] * v[r];
    }
    s  += __shfl_xor(s, 16, 64);  s  += __shfl_xor(s, 32, 64);
    s2 += __shfl_xor(s2, 16, 64); s2 += __shfl_xor(s2, 32, 64);
    // GN0 applied here: every lane has full 16-px sums after the butterfly.
    float mu = s * (1.f / 16.f);
    float var = fmaxf(s2 * (1.f / 16.f) - mu * mu, 0.f);
    float scale = gwv * rsqrtf(var + 1e-5f);
    float shift = gbv - mu * scale;
    // x0 layout px-major [b][16 px][512 d]; lane's 4 values are px kq*4+r, channel dg
    u16* yp = x0 + ((size_t)b * 16 + kq * 4) * 512 + dg;
#pragma unroll
    for (int r = 0; r < 4; ++r) yp[(size_t)r * 512] = f2bf(v[r] * scale + shift);
  }
}

// ---------------- deconv stages 0/1: inputs pre-normalized px-major; pure-copy stage-X
// STAGE 0: reads x0 px-major [b][16px][512c], writes x1 px-major [b][64px][256c]. NB=2 (8 b's).
// STAGE 1: reads x1 px-major, writes x2 px-major [b][256px][128c]. NB=2 (2 b's).
// W staged once per ch and reused across the NB X sub-phases.
template<int STAGE>
__global__ __launch_bounds__(256, 3)
void deconv_mfma(const u16* __restrict__ x, const u16* __restrict__ wt,
                 const float* __restrict__ bias, u16* __restrict__ y,
                 const float* __restrict__ gwn, const float* __restrict__ gbn)
{
  constexpr int CI  = STAGE == 0 ? 512 : 256;
  constexpr int CO  = CI / 2;
  constexpr int H   = STAGE == 0 ? 4 : 8;
  constexpr int WP  = H + 1;
  constexpr int XROWS = STAGE == 0 ? 100 : 81;
  constexpr int NCH = CI / 64;
  constexpr int NB  = 2;
  __shared__ __align__(16) u16 Wl[288 * 64];
  __shared__ __align__(16) u16 Xl[XROWS * 64];
  __shared__ float2 sbuf[2][2][16];
  __shared__ float scl[32], shl[32];

  const int t = threadIdx.x;
  const int lane = t & 63, wave = t >> 6;
  const int ms = wave >> 1, ns = wave & 1;
  const int n15 = lane & 15, kq = lane >> 4;

  // XCD swizzle: XCD k owns b in [64k, 64k+64); all m-blocks of a b co-located
  int m0, b0;
  if constexpr (STAGE == 0) {
    int lin = blockIdx.y * 8 + blockIdx.x;       // 512 blocks
    int xk = lin & 7, pos = lin >> 3;            // pos 0..63
    m0 = (pos & 7) * 32;
    b0 = xk * 64 + (pos >> 3) * 8;               // 8 b's per block (two 4-image sub-phases)
  } else {
    int lin = blockIdx.y * 4 + blockIdx.x;       // 1024 blocks
    int xk = lin & 7, pos = lin >> 3;            // pos 0..127
    m0 = (pos & 3) * 32;
    b0 = xk * 64 + (pos >> 2) * 2;               // 2 b's per block
  }

  int xrow[2];
#pragma unroll
  for (int ni = 0; ni < 2; ++ni) {
    if constexpr (STAGE == 0) xrow[ni] = (ns * 2 + ni) * 25 + (n15 >> 2) * 5 + (n15 & 3);
    else                      xrow[ni] = (2 * (ns * 2 + ni) + (n15 >> 3)) * 9 + (n15 & 7);
  }
  const int am = ms * 16 + n15;

  for (int i = t; i < XROWS * 32; i += 256) ((u32*)Xl)[i] = 0;

  f32x4 acc[NB][2][4];
#pragma unroll
  for (int bh = 0; bh < NB; ++bh)
#pragma unroll
    for (int ni = 0; ni < 2; ++ni)
#pragma unroll
      for (int c = 0; c < 4; ++c) acc[bh][ni][c] = f32x4{0.f, 0.f, 0.f, 0.f};

  auto stage_X = [&](int bh, int c0) {
    if constexpr (STAGE == 0) {
      for (int idx = t; idx < 64 * 8; idx += 256) {
        int pxl = idx >> 3, jb = idx & 7;
        int img = pxl >> 4, p = pxl & 15;
        int iy = p >> 2, ix = p & 3;
        uint4 q = *(const uint4*)(x + ((size_t)(b0 + bh * 4 + img) * 16 + p) * 512 + c0 + jb * 8);
        int row = img * 25 + iy * 5 + ix;
        *(uint4*)&Xl[(row << 6) + ((jb ^ (row & 7)) << 3)] = q;
      }
    } else {
      for (int idx = t; idx < 64 * 8; idx += 256) {
        int pxl = idx >> 3, jb = idx & 7;
        int py = pxl >> 3, px_ = pxl & 7;
        uint4 q = *(const uint4*)(x + ((size_t)(b0 + bh) * 64 + pxl) * 256 + c0 + jb * 8);
        int row = py * 9 + px_;
        *(uint4*)&Xl[(row << 6) + ((jb ^ (row & 7)) << 3)] = q;
      }
    }
  };

  auto do_mfma = [&](f32x4 (&ac)[2][4]) {
#pragma unroll
    for (int s = 0; s < 2; ++s) {
      const int js = s * 4 + kq;
      short8 a[9];
#pragma unroll
      for (int tap = 0; tap < 9; ++tap) {
        int row = tap * 32 + am;
        a[tap] = *(const short8*)&Wl[(row << 6) + ((js ^ (row & 7)) << 3)];
      }
#pragma unroll
      for (int ni = 0; ni < 2; ++ni) {
        int r0 = xrow[ni], r1 = r0 + 1, r2 = r0 + WP, r3 = r0 + WP + 1;
        short8 b00 = *(const short8*)&Xl[(r0 << 6) + ((js ^ (r0 & 7)) << 3)];
        short8 b01 = *(const short8*)&Xl[(r1 << 6) + ((js ^ (r1 & 7)) << 3)];
        short8 b10 = *(const short8*)&Xl[(r2 << 6) + ((js ^ (r2 & 7)) << 3)];
        short8 b11 = *(const short8*)&Xl[(r3 << 6) + ((js ^ (r3 & 7)) << 3)];
        ac[ni][0] = __builtin_amdgcn_mfma_f32_16x16x32_bf16(a[4], b00, ac[ni][0], 0, 0, 0);
        ac[ni][1] = __builtin_amdgcn_mfma_f32_16x16x32_bf16(a[3], b00, ac[ni][1], 0, 0, 0);
        ac[ni][1] = __builtin_amdgcn_mfma_f32_16x16x32_bf16(a[5], b01, ac[ni][1], 0, 0, 0);
        ac[ni][2] = __builtin_amdgcn_mfma_f32_16x16x32_bf16(a[1], b00, ac[ni][2], 0, 0, 0);
        ac[ni][2] = __builtin_amdgcn_mfma_f32_16x16x32_bf16(a[7], b10, ac[ni][2], 0, 0, 0);
        ac[ni][3] = __builtin_amdgcn_mfma_f32_16x16x32_bf16(a[0], b00, ac[ni][3], 0, 0, 0);
        ac[ni][3] = __builtin_amdgcn_mfma_f32_16x16x32_bf16(a[2], b01, ac[ni][3], 0, 0, 0);
        ac[ni][3] = __builtin_amdgcn_mfma_f32_16x16x32_bf16(a[6], b10, ac[ni][3], 0, 0, 0);
        ac[ni][3] = __builtin_amdgcn_mfma_f32_16x16x32_bf16(a[8], b11, ac[ni][3], 0, 0, 0);
      }
    }
  };

  for (int ch = 0; ch < NCH; ++ch) {
    const int c0 = ch * 64;
    __syncthreads();

#pragma unroll
    for (int it = 0; it < 9; ++it) {
      int idx = t + it * 256;
      int row = idx >> 3, jb = idx & 7;
      int tap = row >> 5, ml = row & 31;
      uint4 v = *(const uint4*)(wt + ((size_t)(tap * CO + m0 + ml)) * CI + c0 + jb * 8);
      *(uint4*)&Wl[(row << 6) + ((jb ^ (row & 7)) << 3)] = v;
    }
    stage_X(0, c0);
    __syncthreads();
    do_mfma(acc[0]);

    __syncthreads();          // protect Xl until prior MFMA reads done
    stage_X(1, c0);
    __syncthreads();
    do_mfma(acc[1]);
  }

  // ---- epilogue: bias + relu + next-GN normalize + store ----
  float bv[4];
#pragma unroll
  for (int r = 0; r < 4; ++r) bv[r] = bias[m0 + ms * 16 + kq * 4 + r];

  if constexpr (STAGE == 0) {
    float gw4[4], gb4[4];
#pragma unroll
    for (int r = 0; r < 4; ++r) {
      int m = m0 + ms * 16 + kq * 4 + r;
      gw4[r] = gwn[m]; gb4[r] = gbn[m];
    }
    for (int bh = 0; bh < NB; ++bh) {
#pragma unroll
      for (int ni = 0; ni < 2; ++ni) {
        int b = b0 + bh * 4 + ns * 2 + ni, iy = n15 >> 2, ix = n15 & 3;
        float val[4][4];
        float sr[4] = {0.f, 0.f, 0.f, 0.f}, sr2[4] = {0.f, 0.f, 0.f, 0.f};
#pragma unroll
        for (int cl = 0; cl < 4; ++cl)
#pragma unroll
          for (int r = 0; r < 4; ++r) {
            val[cl][r] = fmaxf(acc[bh][ni][cl][r] + bv[r], 0.f);
            sr[r] += val[cl][r]; sr2[r] += val[cl][r] * val[cl][r];
          }
#pragma unroll
        for (int r = 0; r < 4; ++r) {
#pragma unroll
          for (int off = 1; off <= 8; off <<= 1) {
            sr[r]  += __shfl_xor(sr[r], off, 64);
            sr2[r] += __shfl_xor(sr2[r], off, 64);
          }
        }
        // full 64-px stats now in all lanes -> normalize in-lane, store normalized px-major
        float scv[4], shv[4];
#pragma unroll
        for (int r = 0; r < 4; ++r) {
          float mu = sr[r] * (1.f / 64.f);
          float var = fmaxf(sr2[r] * (1.f / 64.f) - mu * mu, 0.f);
          scv[r] = gw4[r] * rsqrtf(var + 1e-5f);
          shv[r] = gb4[r] - mu * scv[r];
        }
        // x1 layout [b][8x8 px][256 c]
#pragma unroll
        for (int cl = 0; cl < 4; ++cl) {
          int oy = 2 * iy + (cl >> 1), ox = 2 * ix + (cl & 1);
          size_t base = ((size_t)b * 64 + oy * 8 + ox) * 256 + m0 + ms * 16 + kq * 4;
          uint2 pk = {pack_bf16x2(val[cl][0] * scv[0] + shv[0],
                                  val[cl][1] * scv[1] + shv[1]),
                      pack_bf16x2(val[cl][2] * scv[2] + shv[2],
                                  val[cl][3] * scv[3] + shv[3])};
          *(uint2*)(y + base) = pk;
        }
      }
    }
  } else {
    for (int bh = 0; bh < NB; ++bh) {
      const int bcur = b0 + bh;
      float sr[4] = {0.f, 0.f, 0.f, 0.f}, sr2[4] = {0.f, 0.f, 0.f, 0.f};
#pragma unroll
      for (int ni = 0; ni < 2; ++ni)
#pragma unroll
        for (int cl = 0; cl < 4; ++cl)
#pragma unroll
          for (int r = 0; r < 4; ++r) {
            float v = fmaxf(acc[bh][ni][cl][r] + bv[r], 0.f);
            sr[r] += v; sr2[r] += v * v;
          }
#pragma unroll
      for (int r = 0; r < 4; ++r) {
#pragma unroll
        for (int off = 1; off <= 8; off <<= 1) {
          sr[r]  += __shfl_xor(sr[r], off, 64);
          sr2[r] += __shfl_xor(sr2[r], off, 64);
        }
      }
      __syncthreads();
      if (n15 == 0) {
#pragma unroll
        for (int r = 0; r < 4; ++r) sbuf[ms][ns][kq * 4 + r] = float2{sr[r], sr2[r]};
      }
      __syncthreads();
      if (t < 32) {
        int msx = t >> 4, i = t & 15;
        float2 p0 = sbuf[msx][0][i], p1 = sbuf[msx][1][i];
        float s = p0.x + p1.x, s2 = p0.y + p1.y;
        float mu = s * (1.f / 256.f);
        float var = fmaxf(s2 * (1.f / 256.f) - mu * mu, 0.f);
        int m = m0 + msx * 16 + i;
        float scale = gwn[m] * rsqrtf(var + 1e-5f);
        scl[t] = scale;
        shl[t] = gbn[m] - mu * scale;
      }
      __syncthreads();
      float scv[4], shv[4];
#pragma unroll
      for (int r = 0; r < 4; ++r) {
        scv[r] = scl[ms * 16 + kq * 4 + r];
        shv[r] = shl[ms * 16 + kq * 4 + r];
      }
      // x2 layout [b][256 px][128 c], stored pre-normalized
#pragma unroll
      for (int ni = 0; ni < 2; ++ni) {
        int iy = 2 * (ns * 2 + ni) + (n15 >> 3), ix = n15 & 7;
#pragma unroll
        for (int cl = 0; cl < 4; ++cl) {
          int opx = (2 * iy + (cl >> 1)) * 16 + 2 * ix + (cl & 1);
          size_t base = ((size_t)bcur * 256 + opx) * 128 + m0 + ms * 16 + kq * 4;
          float v0 = fmaxf(acc[bh][ni][cl][0] + bv[0], 0.f) * scv[0] + shv[0];
          float v1 = fmaxf(acc[bh][ni][cl][1] + bv[1], 0.f) * scv[1] + shv[1];
          float v2 = fmaxf(acc[bh][ni][cl][2] + bv[2], 0.f) * scv[2] + shv[2];
          float v3 = fmaxf(acc[bh][ni][cl][3] + bv[3], 0.f) * scv[3] + shv[3];
          *(u32*)(y + base)     = pack_bf16x2(v0, v1);
          *(u32*)(y + base + 2) = pack_bf16x2(v2, v3);
        }
      }
    }
  }
}

// ---------------- stage-2 deconv: merged m-halves; X staged once, reused by both m ----------------
#define XRD(ch, row) (*(const short8*)&Xl[ch][((row) << 6) + (((js ^ ((row) & 7))) << 3)])
__global__ __launch_bounds__(256, 2)
void deconv2_q(const u16* __restrict__ x, const u16* __restrict__ wt,
               const float* __restrict__ bias, u16* __restrict__ y,
               float2* __restrict__ psum)
{
  __shared__ __align__(16) u16 Wl[288 * 64];
  __shared__ __align__(16) u16 Xl[2][153 * 64]; // both ch chunks resident; halo stays 0
  __shared__ float2 sbuf[2][2][16];

  const int t = threadIdx.x;
  const int lane = t & 63, wave = t >> 6;
  const int ms = wave >> 1, ns = wave & 1;
  const int n15 = lane & 15, kq = lane >> 4;
  // XCD swizzle: XCD k owns b in [64k, 64k+64)
  const int lin = blockIdx.y * 2 + blockIdx.x;   // 1024 blocks
  const int xk = lin & 7, pos = lin >> 3;        // pos 0..127
  const int b   = xk * 64 + (pos >> 1);
  const int qz2 = pos & 1;                       // 0..1 (16 output rows each)

  for (int i = t; i < 2 * 153 * 32; i += 256) ((u32*)Xl)[i] = 0;

  const int am = ms * 16 + n15;
  const int xr0 = (ns * 4) * 17 + n15;

  const int NPX = (qz2 == 0) ? 144 : 128;     // input rows 0..8 / 8..15 (+zero halo)

  for (int mh = 0; mh < 2; ++mh) {
    const int m0 = mh * 32;

    f32x4 acc[4][4];
#pragma unroll
    for (int ni = 0; ni < 4; ++ni)
#pragma unroll
      for (int c = 0; c < 4; ++c) acc[ni][c] = f32x4{0.f, 0.f, 0.f, 0.f};

    for (int ch = 0; ch < 2; ++ch) {
      const int c0 = ch * 64;
      __syncthreads();

      // ---- stage W: 288 rows (tap*32+ml) x 8 blocks ----
#pragma unroll
      for (int it = 0; it < 9; ++it) {
        int idx = t + it * 256;
        int row = idx >> 3, jb = idx & 7;
        int tap = row >> 5, ml = row & 31;
        uint4 v = *(const uint4*)(wt + ((size_t)(tap * 64 + m0 + ml)) * 128 + c0 + jb * 8);
        *(uint4*)&Wl[(row << 6) + ((jb ^ (row & 7)) << 3)] = v;
      }

      // ---- stage X only in first m-pass: both m-halves reuse it ----
      if (mh == 0) {
        for (int idx = t; idx < NPX * 8; idx += 256) {
          int pxl = idx >> 3, jb = idx & 7;
          int rl = pxl >> 4, ix = pxl & 15;
          int gpx = (8 * qz2 + rl) * 16 + ix;
          uint4 q = *(const uint4*)(x + ((size_t)b * 256 + gpx) * 128 + c0 + jb * 8);
          int row = rl * 17 + ix;
          *(uint4*)&Xl[ch][(row << 6) + ((jb ^ (row & 7)) << 3)] = q;
        }
      }
      __syncthreads();

#pragma unroll
      for (int s = 0; s < 2; ++s) {
        const int js = s * 4 + kq;
        short8 a[9];
#pragma unroll
        for (int tap = 0; tap < 9; ++tap) {
          int row = tap * 32 + am;
          a[tap] = *(const short8*)&Wl[(row << 6) + ((js ^ (row & 7)) << 3)];
        }
        // 10 B rows shared across the wave's 4 adjacent n-tiles
        short8 Brow[10];
#pragma unroll
        for (int k = 0; k < 5; ++k) {
          Brow[2 * k]     = XRD(ch, xr0 + 17 * k);
          Brow[2 * k + 1] = XRD(ch, xr0 + 17 * k + 1);
        }
        __builtin_amdgcn_s_setprio(1);
#pragma unroll
        for (int ni = 0; ni < 4; ++ni) {
          short8 b00 = Brow[2 * ni],     b01 = Brow[2 * ni + 1];
          short8 b10 = Brow[2 * ni + 2], b11 = Brow[2 * ni + 3];
          acc[ni][0] = __builtin_amdgcn_mfma_f32_16x16x32_bf16(a[4], b00, acc[ni][0], 0, 0, 0);
          acc[ni][1] = __builtin_amdgcn_mfma_f32_16x16x32_bf16(a[3], b00, acc[ni][1], 0, 0, 0);
          acc[ni][1] = __builtin_amdgcn_mfma_f32_16x16x32_bf16(a[5], b01, acc[ni][1], 0, 0, 0);
          acc[ni][2] = __builtin_amdgcn_mfma_f32_16x16x32_bf16(a[1], b00, acc[ni][2], 0, 0, 0);
          acc[ni][2] = __builtin_amdgcn_mfma_f32_16x16x32_bf16(a[7], b10, acc[ni][2], 0, 0, 0);
          acc[ni][3] = __builtin_amdgcn_mfma_f32_16x16x32_bf16(a[0], b00, acc[ni][3], 0, 0, 0);
          acc[ni][3] = __builtin_amdgcn_mfma_f32_16x16x32_bf16(a[2], b01, acc[ni][3], 0, 0, 0);
          acc[ni][3] = __builtin_amdgcn_mfma_f32_16x16x32_bf16(a[6], b10, acc[ni][3], 0, 0, 0);
          acc[ni][3] = __builtin_amdgcn_mfma_f32_16x16x32_bf16(a[8], b11, acc[ni][3], 0, 0, 0);
        }
        __builtin_amdgcn_s_setprio(0);
      }
    }

    // ---- epilogue for this m-half: bias + relu + store + stat partials ----
    float bv[4];
#pragma unroll
    for (int r = 0; r < 4; ++r) bv[r] = bias[m0 + ms * 16 + kq * 4 + r];
    float sr[4] = {0.f, 0.f, 0.f, 0.f}, sr2[4] = {0.f, 0.f, 0.f, 0.f};
#pragma unroll
    for (int ni = 0; ni < 4; ++ni) {
      int iy = 8 * qz2 + ns * 4 + ni, ix = n15;
#pragma unroll
      for (int r = 0; r < 4; ++r) {
        int m = m0 + ms * 16 + kq * 4 + r;
        float v00 = fmaxf(acc[ni][0][r] + bv[r], 0.f);
        float v01 = fmaxf(acc[ni][1][r] + bv[r], 0.f);
        float v10 = fmaxf(acc[ni][2][r] + bv[r], 0.f);
        float v11 = fmaxf(acc[ni][3][r] + bv[r], 0.f);
        size_t base = ((size_t)b * 64 + m) * 1024 + (size_t)(2 * iy) * 32 + 2 * ix;
        *(u32*)(y + base)      = pack_bf16x2(v00, v01);
        *(u32*)(y + base + 32) = pack_bf16x2(v10, v11);
        sr[r]  += v00 + v01 + v10 + v11;
        sr2[r] += v00 * v00 + v01 * v01 + v10 * v10 + v11 * v11;
      }
    }
#pragma unroll
    for (int r = 0; r < 4; ++r) {
#pragma unroll
      for (int off = 1; off <= 8; off <<= 1) {
        sr[r]  += __shfl_xor(sr[r], off, 64);
        sr2[r] += __shfl_xor(sr2[r], off, 64);
      }
    }
    __syncthreads();
    if (n15 == 0) {
#pragma unroll
      for (int r = 0; r < 4; ++r) sbuf[ms][ns][kq * 4 + r] = float2{sr[r], sr2[r]};
    }
    __syncthreads();
    if (t < 32) {
      int msx = t >> 4, i = t & 15;
      float2 p0 = sbuf[msx][0][i], p1 = sbuf[msx][1][i];
      int m = m0 + msx * 16 + i;
      psum[((size_t)b * 64 + m) * 2 + qz2] = float2{p0.x + p1.x, p0.y + p1.y};
    }
  }
}

// ---------------- head: fold stat partials -> norm -> 1x1 conv -> spatial softmax ----------------
// Batched reductions: 3 barriers total.
__global__ __launch_bounds__(256)
void head_kernel(const u16* __restrict__ x3, const float2* __restrict__ psum,
                 const int* __restrict__ action, const float* __restrict__ hgw,
                 const float* __restrict__ hcw, float* __restrict__ out)
{
  constexpr int C = 64, S = 5, P = 1024;
  const int t = threadIdx.x;
  const int lane = t & 63, wv = t >> 6;
  const int b = (blockIdx.x & 7) * 64 + (blockIdx.x >> 3);   // XCD-consistent b mapping
  const int a = action[b];
  __shared__ float weff[S * C];
  __shared__ float sc_l[C], sh_l[C];
  __shared__ float redm[4][8];    // per-wave maxima (5 used)
  __shared__ float redp[4][16];   // per-wave partial sums (15 used)
  if (t < C) {
    float2 p0 = psum[((size_t)b * C + t) * 2 + 0];
    float2 p1 = psum[((size_t)b * C + t) * 2 + 1];
    float s = p0.x + p1.x, s2 = p0.y + p1.y;
    float mu = s * (1.f / 1024.f);
    float var = fmaxf(s2 * (1.f / 1024.f) - mu * mu, 0.f);
    float rstd = rsqrtf(var + 1e-5f);
    sc_l[t] = rstd; sh_l[t] = -mu * rstd;
  }
  for (int j = t; j < S * C; j += 256) {
    int s = j >> 6, c = j & 63;
    weff[j] = hcw[(a * S + s) * C + c] * hgw[a * C + c];
  }
  __syncthreads();

  float L[S][4];
#pragma unroll
  for (int s = 0; s < S; ++s)
#pragma unroll
    for (int k = 0; k < 4; ++k) L[s][k] = 0.f;

  const u32* xb = (const u32*)(x3 + (size_t)b * C * P);
  for (int c = 0; c < C; ++c) {
    float scv = sc_l[c], shv = sh_l[c];
    u32 u0 = xb[c * 512 + t];
    u32 u1 = xb[c * 512 + t + 256];
    float xv[4] = {bflo(u0) * scv + shv, bfhi(u0) * scv + shv,
                   bflo(u1) * scv + shv, bfhi(u1) * scv + shv};
#pragma unroll
    for (int s = 0; s < S; ++s) {
      float wv_ = weff[s * C + c];
#pragma unroll
      for (int k = 0; k < 4; ++k) L[s][k] += xv[k] * wv_;
    }
  }

  // ---- phase A: all 5 maxima in one interleaved reduce ----
  float m5[S];
#pragma unroll
  for (int s = 0; s < S; ++s)
    m5[s] = fmaxf(fmaxf(L[s][0], L[s][1]), fmaxf(L[s][2], L[s][3]));
#pragma unroll
  for (int off = 32; off; off >>= 1)
#pragma unroll
    for (int s = 0; s < S; ++s) m5[s] = fmaxf(m5[s], __shfl_xor(m5[s], off, 64));
  if (lane == 0) {
#pragma unroll
    for (int s = 0; s < S; ++s) redm[wv][s] = m5[s];
  }
  __syncthreads();
#pragma unroll
  for (int s = 0; s < S; ++s)
    m5[s] = fmaxf(fmaxf(redm[0][s], redm[1][s]), fmaxf(redm[2][s], redm[3][s]));

  // ---- phase B: all 15 sums (se,sx,sy per s) in one interleaved reduce ----
  float p15[15];
  const int pix[4] = {2 * t, 2 * t + 1, 512 + 2 * t, 512 + 2 * t + 1};
#pragma unroll
  for (int s = 0; s < S; ++s) {
    float se = 0.f, sx = 0.f, sy = 0.f;
#pragma unroll
    for (int k = 0; k < 4; ++k) {
      int p = pix[k];
      float e = __expf(L[s][k] - m5[s]);
      se += e;
      sx += e * ((float)(p & 31) * (2.f / 31.f) - 1.f);
      sy += e * ((float)(p >> 5) * (2.f / 31.f) - 1.f);
    }
    p15[s * 3 + 0] = se; p15[s * 3 + 1] = sx; p15[s * 3 + 2] = sy;
  }
#pragma unroll
  for (int off = 32; off; off >>= 1)
#pragma unroll
    for (int j = 0; j < 15; ++j) p15[j] += __shfl_xor(p15[j], off, 64);
  if (lane == 0) {
#pragma unroll
    for (int j = 0; j < 15; ++j) redp[wv][j] = p15[j];
  }
  __syncthreads();
  if (t < S) {
    int s = t;
    float se = redp[0][s * 3] + redp[1][s * 3] + redp[2][s * 3] + redp[3][s * 3];
    float sx = redp[0][s * 3 + 1] + redp[1][s * 3 + 1] + redp[2][s * 3 + 1] + redp[3][s * 3 + 1];
    float sy = redp[0][s * 3 + 2] + redp[1][s * 3 + 2] + redp[2][s * 3 + 2] + redp[3][s * 3 + 2];
    out[(b * S + s) * 2 + 0] = sx / se;
    out[(b * S + s) * 2 + 1] = sy / se;
  }
}

// ---------------- launcher ----------------
extern "C" void kernel_launch(void* const* d_in, const int* in_sizes, int n_in,
                              void* d_out, int out_size, void* d_ws, size_t ws_size,
                              hipStream_t stream)
{
  (void)in_sizes; (void)n_in; (void)out_size; (void)ws_size;
  const float* feat   = (const float*)d_in[0];
  const int*   action = (const int*)d_in[1];
  const float* fc_w = (const float*)d_in[3];
  const float* fc_b = (const float*)d_in[4];
  const float* gw0  = (const float*)d_in[5];
  const float* gb0  = (const float*)d_in[6];
  const float* dw0  = (const float*)d_in[7];
  const float* db0  = (const float*)d_in[8];
  const float* gw1  = (const float*)d_in[9];
  const float* gb1  = (const float*)d_in[10];
  const float* dw1  = (const float*)d_in[11];
  const float* db1  = (const float*)d_in[12];
  const float* gw2  = (const float*)d_in[13];
  const float* gb2  = (const float*)d_in[14];
  const float* dw2  = (const float*)d_in[15];
  const float* db2  = (const float*)d_in[16];
  const float* hgw  = (const float*)d_in[17];
  const float* hcw  = (const float*)d_in[19];

  float* ws = (float*)d_ws;
  u16* x0 = (u16*)(ws + OFF_REGB);
  u16* x2 = (u16*)(ws + OFF_REGB);
  u16* x1 = (u16*)(ws + OFF_REGA);
  u16* x3 = (u16*)(ws + OFF_REGA);
  u16* wt0 = (u16*)(ws + OFF_WT0);
  u16* wt1 = (u16*)(ws + OFF_WT1);
  u16* wt2 = (u16*)(ws + OFF_WT2);
  u16* wtf = (u16*)(ws + OFF_WTF);
  float2* psum = (float2*)(ws + O_PSUM);

  wtrans_all<<<1184, 256, 0, stream>>>(dw0, dw1, dw2, fc_w, wt0, wt1, wt2, wtf);
  fc_mfma<<<dim3(8, 64), 256, 0, stream>>>(feat, wtf, fc_b, gw0, gb0, x0);
  deconv_mfma<0><<<dim3(8, 64), 256, 0, stream>>>(x0, wt0, db0, x1, gw1, gb1);
  deconv_mfma<1><<<dim3(4, 256), 256, 0, stream>>>(x1, wt1, db1, x2, gw2, gb2);
  deconv2_q<<<dim3(2, 512), 256, 0, stream>>>(x2, wt2, db2, x3, psum);
  head_kernel<<<512, 256, 0, stream>>>(x3, psum, action, hgw, hcw, (float*)d_out);
}

// Round 17
// 233.660 us; speedup vs baseline: 2.0040x; 1.0138x over previous
//
#include <hip/hip_runtime.h>
#include <hip/hip_bf16.h>

#define DI __device__ __forceinline__
using u16 = unsigned short;
using u32 = unsigned int;

typedef short short8 __attribute__((ext_vector_type(8)));   // 8 bf16 (4 VGPRs)
typedef float f32x4 __attribute__((ext_vector_type(4)));

#define F4C(v, i) ((i) == 0 ? (v).x : (i) == 1 ? (v).y : (i) == 2 ? (v).z : (v).w)

DI float bflo(u32 u) { return __uint_as_float(u << 16); }
DI float bfhi(u32 u) { return __uint_as_float(u & 0xffff0000u); }
DI u16 f2bf(float a) {
  u32 xu = __float_as_uint(a);
  return (u16)((xu + 0x7fffu + ((xu >> 16) & 1)) >> 16);
}
DI u32 pack_bf16x2(float a, float b) {
  u32 xu = __float_as_uint(a), yu = __float_as_uint(b);
  xu = (xu + 0x7fffu + ((xu >> 16) & 1)) >> 16;
  yu = (yu + 0x7fffu + ((yu >> 16) & 1)) >> 16;
  return (xu & 0xffffu) | (yu << 16);
}

// ---------------- workspace layout (float units) ----------------
static constexpr size_t OFF_REGB = 0;
static constexpr size_t OFF_REGA = 16777216;
static constexpr size_t OFF_WT0  = 33554432;
static constexpr size_t OFF_WT1  = OFF_WT0 + 1179648;
static constexpr size_t OFF_WT2  = OFF_WT1 + 294912;
static constexpr size_t OFF_WTF  = OFF_WT2 + 73728;
static constexpr size_t OFF_ST   = 35200000;
static constexpr size_t O_PSUM = OFF_ST + 1048576;   // 512*64*2 float2 = 131072 floats

// ---------------- all weight pre-transposes in one launch ----------------
__global__ __launch_bounds__(256)
void wtrans_all(const float* __restrict__ dw0, const float* __restrict__ dw1,
                const float* __restrict__ dw2, const float* __restrict__ fcw,
                u16* __restrict__ wt0, u16* __restrict__ wt1,
                u16* __restrict__ wt2, u16* __restrict__ wtf)
{
  int id = blockIdx.x * 256 + threadIdx.x;
  if (id < 131072) {                       // dw0: CO=256, CI=512
    int m = id >> 9, c = id & 511;
    const float* src = dw0 + ((size_t)m * 512 + c) * 9;
#pragma unroll
    for (int tap = 0; tap < 9; ++tap)
      wt0[((size_t)tap * 256 + m) * 512 + c] = f2bf(src[tap]);
  } else if (id < 163840) {                // dw1: CO=128, CI=256
    int j = id - 131072;
    int m = j >> 8, c = j & 255;
    const float* src = dw1 + ((size_t)m * 256 + c) * 9;
#pragma unroll
    for (int tap = 0; tap < 9; ++tap)
      wt1[((size_t)tap * 128 + m) * 256 + c] = f2bf(src[tap]);
  } else if (id < 172032) {                // dw2: CO=64, CI=128
    int j = id - 163840;
    int m = j >> 7, c = j & 127;
    const float* src = dw2 + ((size_t)m * 128 + c) * 9;
#pragma unroll
    for (int tap = 0; tap < 9; ++tap)
      wt2[((size_t)tap * 64 + m) * 128 + c] = f2bf(src[tap]);
  } else {                                 // fc: wtf[d][c]
    int j = id - 172032;
    int d = j >> 8, c = j & 255;
    wtf[j] = f2bf(fcw[c * 512 + d]);
  }
}

// ---------------- fc1 via MFMA; GN0 applied in epilogue; x0 stored px-major ----------------
DI void fc_stage_A(const float* __restrict__ feat, int b, u16* Ab, int t)
{
#pragma unroll
  for (int it = 0; it < 2; ++it) {
    int idx = t + it * 256;
    int cp = idx >> 2, hw4 = idx & 3;
    int c = cp * 2;
    const float* xp = feat + ((size_t)b * 256 + c) * 16 + hw4 * 4;
    float4 v0 = *(const float4*)xp;
    float4 v1 = *(const float4*)(xp + 16);
    int c64 = c >> 6, jb = (c & 63) >> 3;
#pragma unroll
    for (int j = 0; j < 4; ++j) {
      int hw = hw4 * 4 + j;
      int row = c64 * 16 + hw;
      *(u32*)&Ab[(row << 6) + ((jb ^ (row & 7)) << 3) + (c & 7)] =
          pack_bf16x2(F4C(v0, j), F4C(v1, j));
    }
  }
}

__global__ __launch_bounds__(256, 3)
void fc_mfma(const float* __restrict__ feat, const u16* __restrict__ wtf,
             const float* __restrict__ fb, const float* __restrict__ gw,
             const float* __restrict__ gb, u16* __restrict__ x0)
{
  __shared__ __align__(16) u16 Wl[256 * 64];
  __shared__ __align__(16) u16 Al[2][64 * 64];
  const int t = threadIdx.x;
  const int lane = t & 63, wave = t >> 6;
  const int n15 = lane & 15, kq = lane >> 4;
  // XCD swizzle: XCD k owns b in [64k, 64k+64); 8 d-blocks of same b-group co-located
  const int lin = blockIdx.y * 8 + blockIdx.x;
  const int xk = lin & 7, pos = lin >> 3;          // pos 0..63
  const int d0 = (pos & 7) * 64;
  const int b0 = (xk * 8 + (pos >> 3)) * 8;

#pragma unroll
  for (int it = 0; it < 8; ++it) {
    int idx = t + it * 256;
    int dl = idx >> 5, jb32 = idx & 31;
    int row = (jb32 >> 3) * 64 + dl, jb = jb32 & 7;
    uint4 v = *(const uint4*)(wtf + (size_t)(d0 + dl) * 256 + jb32 * 8);
    *(uint4*)&Wl[(row << 6) + ((jb ^ (row & 7)) << 3)] = v;
  }
  fc_stage_A(feat, b0, Al[0], t);

  const int dg = d0 + wave * 16 + n15;
  const float bvn = fb[dg];
  const float gwv = gw[dg], gbv = gb[dg];

  for (int bi = 0; bi < 8; ++bi) {
    __syncthreads();
    if (bi + 1 < 8) fc_stage_A(feat, b0 + bi + 1, Al[(bi + 1) & 1], t);

    const u16* A = Al[bi & 1];
    f32x4 acc0 = {0.f, 0.f, 0.f, 0.f}, acc1 = {0.f, 0.f, 0.f, 0.f};
#pragma unroll
    for (int ks = 0; ks < 8; ++ks) {
      int js = ks * 4 + kq;
      int ra = (js >> 3) * 16 + n15;
      int rb = (js >> 3) * 64 + wave * 16 + n15;
      short8 av = *(const short8*)&A[(ra << 6) + (((js & 7) ^ (ra & 7)) << 3)];
      short8 bv = *(const short8*)&Wl[(rb << 6) + (((js & 7) ^ (rb & 7)) << 3)];
      if (ks & 1) acc1 = __builtin_amdgcn_mfma_f32_16x16x32_bf16(av, bv, acc1, 0, 0, 0);
      else        acc0 = __builtin_amdgcn_mfma_f32_16x16x32_bf16(av, bv, acc0, 0, 0, 0);
    }

    int b = b0 + bi;
    float v[4], s = 0.f, s2 = 0.f;
#pragma unroll
    for (int r = 0; r < 4; ++r) {
      v[r] = fmaxf(acc0[r] + acc1[r] + bvn, 0.f);
      s += v[r]; s2 += v[r] * v[r];
    }
    s  += __shfl_xor(s, 16, 64);  s  += __shfl_xor(s, 32, 64);
    s2 += __shfl_xor(s2, 16, 64); s2 += __shfl_xor(s2, 32, 64);
    // GN0 applied here: every lane has full 16-px sums after the butterfly.
    float mu = s * (1.f / 16.f);
    float var = fmaxf(s2 * (1.f / 16.f) - mu * mu, 0.f);
    float scale = gwv * rsqrtf(var + 1e-5f);
    float shift = gbv - mu * scale;
    // x0 layout px-major [b][16 px][512 d]; lane's 4 values are px kq*4+r, channel dg
    u16* yp = x0 + ((size_t)b * 16 + kq * 4) * 512 + dg;
#pragma unroll
    for (int r = 0; r < 4; ++r) yp[(size_t)r * 512] = f2bf(v[r] * scale + shift);
  }
}

// ---------------- deconv stages 0/1: inputs pre-normalized px-major; pure-copy stage-X
// STAGE 0: reads x0 px-major [b][16px][512c], writes x1 px-major [b][64px][256c]. NB=2 (8 b's).
// STAGE 1: reads x1 px-major, writes x2 px-major [b][256px][128c]. NB=2 (2 b's).
// W staged once per ch and reused across the NB X sub-phases.
template<int STAGE>
__global__ __launch_bounds__(256, 3)
void deconv_mfma(const u16* __restrict__ x, const u16* __restrict__ wt,
                 const float* __restrict__ bias, u16* __restrict__ y,
                 const float* __restrict__ gwn, const float* __restrict__ gbn)
{
  constexpr int CI  = STAGE == 0 ? 512 : 256;
  constexpr int CO  = CI / 2;
  constexpr int H   = STAGE == 0 ? 4 : 8;
  constexpr int WP  = H + 1;
  constexpr int XROWS = STAGE == 0 ? 100 : 81;
  constexpr int NCH = CI / 64;
  constexpr int NB  = 2;
  __shared__ __align__(16) u16 Wl[288 * 64];
  __shared__ __align__(16) u16 Xl[XROWS * 64];
  __shared__ float2 sbuf[2][2][16];
  __shared__ float scl[32], shl[32];

  const int t = threadIdx.x;
  const int lane = t & 63, wave = t >> 6;
  const int ms = wave >> 1, ns = wave & 1;
  const int n15 = lane & 15, kq = lane >> 4;

  // XCD swizzle: XCD k owns b in [64k, 64k+64); all m-blocks of a b co-located
  int m0, b0;
  if constexpr (STAGE == 0) {
    int lin = blockIdx.y * 8 + blockIdx.x;       // 512 blocks
    int xk = lin & 7, pos = lin >> 3;            // pos 0..63
    m0 = (pos & 7) * 32;
    b0 = xk * 64 + (pos >> 3) * 8;               // 8 b's per block (two 4-image sub-phases)
  } else {
    int lin = blockIdx.y * 4 + blockIdx.x;       // 1024 blocks
    int xk = lin & 7, pos = lin >> 3;            // pos 0..127
    m0 = (pos & 3) * 32;
    b0 = xk * 64 + (pos >> 2) * 2;               // 2 b's per block
  }

  int xrow[2];
#pragma unroll
  for (int ni = 0; ni < 2; ++ni) {
    if constexpr (STAGE == 0) xrow[ni] = (ns * 2 + ni) * 25 + (n15 >> 2) * 5 + (n15 & 3);
    else                      xrow[ni] = (2 * (ns * 2 + ni) + (n15 >> 3)) * 9 + (n15 & 7);
  }
  const int am = ms * 16 + n15;

  for (int i = t; i < XROWS * 32; i += 256) ((u32*)Xl)[i] = 0;

  f32x4 acc[NB][2][4];
#pragma unroll
  for (int bh = 0; bh < NB; ++bh)
#pragma unroll
    for (int ni = 0; ni < 2; ++ni)
#pragma unroll
      for (int c = 0; c < 4; ++c) acc[bh][ni][c] = f32x4{0.f, 0.f, 0.f, 0.f};

  auto stage_X = [&](int bh, int c0) {
    if constexpr (STAGE == 0) {
      for (int idx = t; idx < 64 * 8; idx += 256) {
        int pxl = idx >> 3, jb = idx & 7;
        int img = pxl >> 4, p = pxl & 15;
        int iy = p >> 2, ix = p & 3;
        uint4 q = *(const uint4*)(x + ((size_t)(b0 + bh * 4 + img) * 16 + p) * 512 + c0 + jb * 8);
        int row = img * 25 + iy * 5 + ix;
        *(uint4*)&Xl[(row << 6) + ((jb ^ (row & 7)) << 3)] = q;
      }
    } else {
      for (int idx = t; idx < 64 * 8; idx += 256) {
        int pxl = idx >> 3, jb = idx & 7;
        int py = pxl >> 3, px_ = pxl & 7;
        uint4 q = *(const uint4*)(x + ((size_t)(b0 + bh) * 64 + pxl) * 256 + c0 + jb * 8);
        int row = py * 9 + px_;
        *(uint4*)&Xl[(row << 6) + ((jb ^ (row & 7)) << 3)] = q;
      }
    }
  };

  auto do_mfma = [&](f32x4 (&ac)[2][4]) {
#pragma unroll
    for (int s = 0; s < 2; ++s) {
      const int js = s * 4 + kq;
      short8 a[9];
#pragma unroll
      for (int tap = 0; tap < 9; ++tap) {
        int row = tap * 32 + am;
        a[tap] = *(const short8*)&Wl[(row << 6) + ((js ^ (row & 7)) << 3)];
      }
#pragma unroll
      for (int ni = 0; ni < 2; ++ni) {
        int r0 = xrow[ni], r1 = r0 + 1, r2 = r0 + WP, r3 = r0 + WP + 1;
        short8 b00 = *(const short8*)&Xl[(r0 << 6) + ((js ^ (r0 & 7)) << 3)];
        short8 b01 = *(const short8*)&Xl[(r1 << 6) + ((js ^ (r1 & 7)) << 3)];
        short8 b10 = *(const short8*)&Xl[(r2 << 6) + ((js ^ (r2 & 7)) << 3)];
        short8 b11 = *(const short8*)&Xl[(r3 << 6) + ((js ^ (r3 & 7)) << 3)];
        ac[ni][0] = __builtin_amdgcn_mfma_f32_16x16x32_bf16(a[4], b00, ac[ni][0], 0, 0, 0);
        ac[ni][1] = __builtin_amdgcn_mfma_f32_16x16x32_bf16(a[3], b00, ac[ni][1], 0, 0, 0);
        ac[ni][1] = __builtin_amdgcn_mfma_f32_16x16x32_bf16(a[5], b01, ac[ni][1], 0, 0, 0);
        ac[ni][2] = __builtin_amdgcn_mfma_f32_16x16x32_bf16(a[1], b00, ac[ni][2], 0, 0, 0);
        ac[ni][2] = __builtin_amdgcn_mfma_f32_16x16x32_bf16(a[7], b10, ac[ni][2], 0, 0, 0);
        ac[ni][3] = __builtin_amdgcn_mfma_f32_16x16x32_bf16(a[0], b00, ac[ni][3], 0, 0, 0);
        ac[ni][3] = __builtin_amdgcn_mfma_f32_16x16x32_bf16(a[2], b01, ac[ni][3], 0, 0, 0);
        ac[ni][3] = __builtin_amdgcn_mfma_f32_16x16x32_bf16(a[6], b10, ac[ni][3], 0, 0, 0);
        ac[ni][3] = __builtin_amdgcn_mfma_f32_16x16x32_bf16(a[8], b11, ac[ni][3], 0, 0, 0);
      }
    }
  };

  for (int ch = 0; ch < NCH; ++ch) {
    const int c0 = ch * 64;
    __syncthreads();

#pragma unroll
    for (int it = 0; it < 9; ++it) {
      int idx = t + it * 256;
      int row = idx >> 3, jb = idx & 7;
      int tap = row >> 5, ml = row & 31;
      uint4 v = *(const uint4*)(wt + ((size_t)(tap * CO + m0 + ml)) * CI + c0 + jb * 8);
      *(uint4*)&Wl[(row << 6) + ((jb ^ (row & 7)) << 3)] = v;
    }
    stage_X(0, c0);
    __syncthreads();
    do_mfma(acc[0]);

    __syncthreads();          // protect Xl until prior MFMA reads done
    stage_X(1, c0);
    __syncthreads();
    do_mfma(acc[1]);
  }

  // ---- epilogue: bias + relu + next-GN normalize + store ----
  float bv[4];
#pragma unroll
  for (int r = 0; r < 4; ++r) bv[r] = bias[m0 + ms * 16 + kq * 4 + r];

  if constexpr (STAGE == 0) {
    float gw4[4], gb4[4];
#pragma unroll
    for (int r = 0; r < 4; ++r) {
      int m = m0 + ms * 16 + kq * 4 + r;
      gw4[r] = gwn[m]; gb4[r] = gbn[m];
    }
    for (int bh = 0; bh < NB; ++bh) {
#pragma unroll
      for (int ni = 0; ni < 2; ++ni) {
        int b = b0 + bh * 4 + ns * 2 + ni, iy = n15 >> 2, ix = n15 & 3;
        float val[4][4];
        float sr[4] = {0.f, 0.f, 0.f, 0.f}, sr2[4] = {0.f, 0.f, 0.f, 0.f};
#pragma unroll
        for (int cl = 0; cl < 4; ++cl)
#pragma unroll
          for (int r = 0; r < 4; ++r) {
            val[cl][r] = fmaxf(acc[bh][ni][cl][r] + bv[r], 0.f);
            sr[r] += val[cl][r]; sr2[r] += val[cl][r] * val[cl][r];
          }
#pragma unroll
        for (int r = 0; r < 4; ++r) {
#pragma unroll
          for (int off = 1; off <= 8; off <<= 1) {
            sr[r]  += __shfl_xor(sr[r], off, 64);
            sr2[r] += __shfl_xor(sr2[r], off, 64);
          }
        }
        // full 64-px stats now in all lanes -> normalize in-lane, store normalized px-major
        float scv[4], shv[4];
#pragma unroll
        for (int r = 0; r < 4; ++r) {
          float mu = sr[r] * (1.f / 64.f);
          float var = fmaxf(sr2[r] * (1.f / 64.f) - mu * mu, 0.f);
          scv[r] = gw4[r] * rsqrtf(var + 1e-5f);
          shv[r] = gb4[r] - mu * scv[r];
        }
        // x1 layout [b][8x8 px][256 c]
#pragma unroll
        for (int cl = 0; cl < 4; ++cl) {
          int oy = 2 * iy + (cl >> 1), ox = 2 * ix + (cl & 1);
          size_t base = ((size_t)b * 64 + oy * 8 + ox) * 256 + m0 + ms * 16 + kq * 4;
          uint2 pk = {pack_bf16x2(val[cl][0] * scv[0] + shv[0],
                                  val[cl][1] * scv[1] + shv[1]),
                      pack_bf16x2(val[cl][2] * scv[2] + shv[2],
                                  val[cl][3] * scv[3] + shv[3])};
          *(uint2*)(y + base) = pk;
        }
      }
    }
  } else {
    for (int bh = 0; bh < NB; ++bh) {
      const int bcur = b0 + bh;
      float sr[4] = {0.f, 0.f, 0.f, 0.f}, sr2[4] = {0.f, 0.f, 0.f, 0.f};
#pragma unroll
      for (int ni = 0; ni < 2; ++ni)
#pragma unroll
        for (int cl = 0; cl < 4; ++cl)
#pragma unroll
          for (int r = 0; r < 4; ++r) {
            float v = fmaxf(acc[bh][ni][cl][r] + bv[r], 0.f);
            sr[r] += v; sr2[r] += v * v;
          }
#pragma unroll
      for (int r = 0; r < 4; ++r) {
#pragma unroll
        for (int off = 1; off <= 8; off <<= 1) {
          sr[r]  += __shfl_xor(sr[r], off, 64);
          sr2[r] += __shfl_xor(sr2[r], off, 64);
        }
      }
      __syncthreads();
      if (n15 == 0) {
#pragma unroll
        for (int r = 0; r < 4; ++r) sbuf[ms][ns][kq * 4 + r] = float2{sr[r], sr2[r]};
      }
      __syncthreads();
      if (t < 32) {
        int msx = t >> 4, i = t & 15;
        float2 p0 = sbuf[msx][0][i], p1 = sbuf[msx][1][i];
        float s = p0.x + p1.x, s2 = p0.y + p1.y;
        float mu = s * (1.f / 256.f);
        float var = fmaxf(s2 * (1.f / 256.f) - mu * mu, 0.f);
        int m = m0 + msx * 16 + i;
        float scale = gwn[m] * rsqrtf(var + 1e-5f);
        scl[t] = scale;
        shl[t] = gbn[m] - mu * scale;
      }
      __syncthreads();
      float scv[4], shv[4];
#pragma unroll
      for (int r = 0; r < 4; ++r) {
        scv[r] = scl[ms * 16 + kq * 4 + r];
        shv[r] = shl[ms * 16 + kq * 4 + r];
      }
      // x2 layout [b][256 px][128 c], stored pre-normalized
#pragma unroll
      for (int ni = 0; ni < 2; ++ni) {
        int iy = 2 * (ns * 2 + ni) + (n15 >> 3), ix = n15 & 7;
#pragma unroll
        for (int cl = 0; cl < 4; ++cl) {
          int opx = (2 * iy + (cl >> 1)) * 16 + 2 * ix + (cl & 1);
          size_t base = ((size_t)bcur * 256 + opx) * 128 + m0 + ms * 16 + kq * 4;
          float v0 = fmaxf(acc[bh][ni][cl][0] + bv[0], 0.f) * scv[0] + shv[0];
          float v1 = fmaxf(acc[bh][ni][cl][1] + bv[1], 0.f) * scv[1] + shv[1];
          float v2 = fmaxf(acc[bh][ni][cl][2] + bv[2], 0.f) * scv[2] + shv[2];
          float v3 = fmaxf(acc[bh][ni][cl][3] + bv[3], 0.f) * scv[3] + shv[3];
          *(u32*)(y + base)     = pack_bf16x2(v0, v1);
          *(u32*)(y + base + 2) = pack_bf16x2(v2, v3);
        }
      }
    }
  }
}

// ---------------- stage-2 deconv: merged m-halves; X staged once, reused by both m ----------------
#define XRD(ch, row) (*(const short8*)&Xl[ch][((row) << 6) + (((js ^ ((row) & 7))) << 3)])
__global__ __launch_bounds__(256, 2)
void deconv2_q(const u16* __restrict__ x, const u16* __restrict__ wt,
               const float* __restrict__ bias, u16* __restrict__ y,
               float2* __restrict__ psum)
{
  __shared__ __align__(16) u16 Wl[288 * 64];
  __shared__ __align__(16) u16 Xl[2][153 * 64]; // both ch chunks resident; halo stays 0
  __shared__ float2 sbuf[2][2][16];

  const int t = threadIdx.x;
  const int lane = t & 63, wave = t >> 6;
  const int ms = wave >> 1, ns = wave & 1;
  const int n15 = lane & 15, kq = lane >> 4;
  // XCD swizzle: XCD k owns b in [64k, 64k+64)
  const int lin = blockIdx.y * 2 + blockIdx.x;   // 1024 blocks
  const int xk = lin & 7, pos = lin >> 3;        // pos 0..127
  const int b   = xk * 64 + (pos >> 1);
  const int qz2 = pos & 1;                       // 0..1 (16 output rows each)

  for (int i = t; i < 2 * 153 * 32; i += 256) ((u32*)Xl)[i] = 0;

  const int am = ms * 16 + n15;
  const int xr0 = (ns * 4) * 17 + n15;

  const int NPX = (qz2 == 0) ? 144 : 128;     // input rows 0..8 / 8..15 (+zero halo)

  for (int mh = 0; mh < 2; ++mh) {
    const int m0 = mh * 32;

    f32x4 acc[4][4];
#pragma unroll
    for (int ni = 0; ni < 4; ++ni)
#pragma unroll
      for (int c = 0; c < 4; ++c) acc[ni][c] = f32x4{0.f, 0.f, 0.f, 0.f};

    for (int ch = 0; ch < 2; ++ch) {
      const int c0 = ch * 64;
      __syncthreads();

      // ---- stage W: 288 rows (tap*32+ml) x 8 blocks ----
#pragma unroll
      for (int it = 0; it < 9; ++it) {
        int idx = t + it * 256;
        int row = idx >> 3, jb = idx & 7;
        int tap = row >> 5, ml = row & 31;
        uint4 v = *(const uint4*)(wt + ((size_t)(tap * 64 + m0 + ml)) * 128 + c0 + jb * 8);
        *(uint4*)&Wl[(row << 6) + ((jb ^ (row & 7)) << 3)] = v;
      }

      // ---- stage X only in first m-pass: both m-halves reuse it ----
      if (mh == 0) {
        for (int idx = t; idx < NPX * 8; idx += 256) {
          int pxl = idx >> 3, jb = idx & 7;
          int rl = pxl >> 4, ix = pxl & 15;
          int gpx = (8 * qz2 + rl) * 16 + ix;
          uint4 q = *(const uint4*)(x + ((size_t)b * 256 + gpx) * 128 + c0 + jb * 8);
          int row = rl * 17 + ix;
          *(uint4*)&Xl[ch][(row << 6) + ((jb ^ (row & 7)) << 3)] = q;
        }
      }
      __syncthreads();

#pragma unroll
      for (int s = 0; s < 2; ++s) {
        const int js = s * 4 + kq;
        short8 a[9];
#pragma unroll
        for (int tap = 0; tap < 9; ++tap) {
          int row = tap * 32 + am;
          a[tap] = *(const short8*)&Wl[(row << 6) + ((js ^ (row & 7)) << 3)];
        }
        // 10 B rows shared across the wave's 4 adjacent n-tiles
        short8 Brow[10];
#pragma unroll
        for (int k = 0; k < 5; ++k) {
          Brow[2 * k]     = XRD(ch, xr0 + 17 * k);
          Brow[2 * k + 1] = XRD(ch, xr0 + 17 * k + 1);
        }
        __builtin_amdgcn_s_setprio(1);
#pragma unroll
        for (int ni = 0; ni < 4; ++ni) {
          short8 b00 = Brow[2 * ni],     b01 = Brow[2 * ni + 1];
          short8 b10 = Brow[2 * ni + 2], b11 = Brow[2 * ni + 3];
          acc[ni][0] = __builtin_amdgcn_mfma_f32_16x16x32_bf16(a[4], b00, acc[ni][0], 0, 0, 0);
          acc[ni][1] = __builtin_amdgcn_mfma_f32_16x16x32_bf16(a[3], b00, acc[ni][1], 0, 0, 0);
          acc[ni][1] = __builtin_amdgcn_mfma_f32_16x16x32_bf16(a[5], b01, acc[ni][1], 0, 0, 0);
          acc[ni][2] = __builtin_amdgcn_mfma_f32_16x16x32_bf16(a[1], b00, acc[ni][2], 0, 0, 0);
          acc[ni][2] = __builtin_amdgcn_mfma_f32_16x16x32_bf16(a[7], b10, acc[ni][2], 0, 0, 0);
          acc[ni][3] = __builtin_amdgcn_mfma_f32_16x16x32_bf16(a[0], b00, acc[ni][3], 0, 0, 0);
          acc[ni][3] = __builtin_amdgcn_mfma_f32_16x16x32_bf16(a[2], b01, acc[ni][3], 0, 0, 0);
          acc[ni][3] = __builtin_amdgcn_mfma_f32_16x16x32_bf16(a[6], b10, acc[ni][3], 0, 0, 0);
          acc[ni][3] = __builtin_amdgcn_mfma_f32_16x16x32_bf16(a[8], b11, acc[ni][3], 0, 0, 0);
        }
        __builtin_amdgcn_s_setprio(0);
      }
    }

    // ---- epilogue for this m-half: bias + relu + store + stat partials ----
    float bv[4];
#pragma unroll
    for (int r = 0; r < 4; ++r) bv[r] = bias[m0 + ms * 16 + kq * 4 + r];
    float sr[4] = {0.f, 0.f, 0.f, 0.f}, sr2[4] = {0.f, 0.f, 0.f, 0.f};
#pragma unroll
    for (int ni = 0; ni < 4; ++ni) {
      int iy = 8 * qz2 + ns * 4 + ni, ix = n15;
#pragma unroll
      for (int r = 0; r < 4; ++r) {
        int m = m0 + ms * 16 + kq * 4 + r;
        float v00 = fmaxf(acc[ni][0][r] + bv[r], 0.f);
        float v01 = fmaxf(acc[ni][1][r] + bv[r], 0.f);
        float v10 = fmaxf(acc[ni][2][r] + bv[r], 0.f);
        float v11 = fmaxf(acc[ni][3][r] + bv[r], 0.f);
        size_t base = ((size_t)b * 64 + m) * 1024 + (size_t)(2 * iy) * 32 + 2 * ix;
        *(u32*)(y + base)      = pack_bf16x2(v00, v01);
        *(u32*)(y + base + 32) = pack_bf16x2(v10, v11);
        sr[r]  += v00 + v01 + v10 + v11;
        sr2[r] += v00 * v00 + v01 * v01 + v10 * v10 + v11 * v11;
      }
    }
#pragma unroll
    for (int r = 0; r < 4; ++r) {
#pragma unroll
      for (int off = 1; off <= 8; off <<= 1) {
        sr[r]  += __shfl_xor(sr[r], off, 64);
        sr2[r] += __shfl_xor(sr2[r], off, 64);
      }
    }
    __syncthreads();
    if (n15 == 0) {
#pragma unroll
      for (int r = 0; r < 4; ++r) sbuf[ms][ns][kq * 4 + r] = float2{sr[r], sr2[r]};
    }
    __syncthreads();
    if (t < 32) {
      int msx = t >> 4, i = t & 15;
      float2 p0 = sbuf[msx][0][i], p1 = sbuf[msx][1][i];
      int m = m0 + msx * 16 + i;
      psum[((size_t)b * 64 + m) * 2 + qz2] = float2{p0.x + p1.x, p0.y + p1.y};
    }
  }
}

// ---------------- head: fold stat partials -> norm -> 1x1 conv -> spatial softmax ----------------
// 512 threads (2 px/thread) for 2x TLP on the x3 streaming loop; 3 barriers total.
__global__ __launch_bounds__(512)
void head_kernel(const u16* __restrict__ x3, const float2* __restrict__ psum,
                 const int* __restrict__ action, const float* __restrict__ hgw,
                 const float* __restrict__ hcw, float* __restrict__ out)
{
  constexpr int C = 64, S = 5, P = 1024;
  const int t = threadIdx.x;
  const int lane = t & 63, wv = t >> 6;              // 8 waves
  const int b = (blockIdx.x & 7) * 64 + (blockIdx.x >> 3);   // XCD-consistent b mapping
  const int a = action[b];
  __shared__ float weff[S * C];
  __shared__ float sc_l[C], sh_l[C];
  __shared__ float redm[8][8];    // per-wave maxima (5 used)
  __shared__ float redp[8][16];   // per-wave partial sums (15 used)
  if (t < C) {
    float2 p0 = psum[((size_t)b * C + t) * 2 + 0];
    float2 p1 = psum[((size_t)b * C + t) * 2 + 1];
    float s = p0.x + p1.x, s2 = p0.y + p1.y;
    float mu = s * (1.f / 1024.f);
    float var = fmaxf(s2 * (1.f / 1024.f) - mu * mu, 0.f);
    float rstd = rsqrtf(var + 1e-5f);
    sc_l[t] = rstd; sh_l[t] = -mu * rstd;
  }
  if (t < S * C) {
    int s = t >> 6, c = t & 63;
    weff[t] = hcw[(a * S + s) * C + c] * hgw[a * C + c];
  }
  __syncthreads();

  float L[S][2];
#pragma unroll
  for (int s = 0; s < S; ++s)
#pragma unroll
    for (int k = 0; k < 2; ++k) L[s][k] = 0.f;

  const u32* xb = (const u32*)(x3 + (size_t)b * C * P);
  for (int c = 0; c < C; ++c) {
    float scv = sc_l[c], shv = sh_l[c];
    u32 u0 = xb[c * 512 + t];
    float xv[2] = {bflo(u0) * scv + shv, bfhi(u0) * scv + shv};
#pragma unroll
    for (int s = 0; s < S; ++s) {
      float wv_ = weff[s * C + c];
#pragma unroll
      for (int k = 0; k < 2; ++k) L[s][k] += xv[k] * wv_;
    }
  }

  // ---- phase A: all 5 maxima in one interleaved reduce ----
  float m5[S];
#pragma unroll
  for (int s = 0; s < S; ++s)
    m5[s] = fmaxf(L[s][0], L[s][1]);
#pragma unroll
  for (int off = 32; off; off >>= 1)
#pragma unroll
    for (int s = 0; s < S; ++s) m5[s] = fmaxf(m5[s], __shfl_xor(m5[s], off, 64));
  if (lane == 0) {
#pragma unroll
    for (int s = 0; s < S; ++s) redm[wv][s] = m5[s];
  }
  __syncthreads();
#pragma unroll
  for (int s = 0; s < S; ++s) {
    float mm = redm[0][s];
#pragma unroll
    for (int w = 1; w < 8; ++w) mm = fmaxf(mm, redm[w][s]);
    m5[s] = mm;
  }

  // ---- phase B: all 15 sums (se,sx,sy per s) in one interleaved reduce ----
  float p15[15];
  const int pix[2] = {2 * t, 2 * t + 1};
#pragma unroll
  for (int s = 0; s < S; ++s) {
    float se = 0.f, sx = 0.f, sy = 0.f;
#pragma unroll
    for (int k = 0; k < 2; ++k) {
      int p = pix[k];
      float e = __expf(L[s][k] - m5[s]);
      se += e;
      sx += e * ((float)(p & 31) * (2.f / 31.f) - 1.f);
      sy += e * ((float)(p >> 5) * (2.f / 31.f) - 1.f);
    }
    p15[s * 3 + 0] = se; p15[s * 3 + 1] = sx; p15[s * 3 + 2] = sy;
  }
#pragma unroll
  for (int off = 32; off; off >>= 1)
#pragma unroll
    for (int j = 0; j < 15; ++j) p15[j] += __shfl_xor(p15[j], off, 64);
  if (lane == 0) {
#pragma unroll
    for (int j = 0; j < 15; ++j) redp[wv][j] = p15[j];
  }
  __syncthreads();
  if (t < S) {
    int s = t;
    float se = 0.f, sx = 0.f, sy = 0.f;
#pragma unroll
    for (int w = 0; w < 8; ++w) {
      se += redp[w][s * 3 + 0];
      sx += redp[w][s * 3 + 1];
      sy += redp[w][s * 3 + 2];
    }
    out[(b * S + s) * 2 + 0] = sx / se;
    out[(b * S + s) * 2 + 1] = sy / se;
  }
}

// ---------------- launcher ----------------
extern "C" void kernel_launch(void* const* d_in, const int* in_sizes, int n_in,
                              void* d_out, int out_size, void* d_ws, size_t ws_size,
                              hipStream_t stream)
{
  (void)in_sizes; (void)n_in; (void)out_size; (void)ws_size;
  const float* feat   = (const float*)d_in[0];
  const int*   action = (const int*)d_in[1];
  const float* fc_w = (const float*)d_in[3];
  const float* fc_b = (const float*)d_in[4];
  const float* gw0  = (const float*)d_in[5];
  const float* gb0  = (const float*)d_in[6];
  const float* dw0  = (const float*)d_in[7];
  const float* db0  = (const float*)d_in[8];
  const float* gw1  = (const float*)d_in[9];
  const float* gb1  = (const float*)d_in[10];
  const float* dw1  = (const float*)d_in[11];
  const float* db1  = (const float*)d_in[12];
  const float* gw2  = (const float*)d_in[13];
  const float* gb2  = (const float*)d_in[14];
  const float* dw2  = (const float*)d_in[15];
  const float* db2  = (const float*)d_in[16];
  const float* hgw  = (const float*)d_in[17];
  const float* hcw  = (const float*)d_in[19];

  float* ws = (float*)d_ws;
  u16* x0 = (u16*)(ws + OFF_REGB);
  u16* x2 = (u16*)(ws + OFF_REGB);
  u16* x1 = (u16*)(ws + OFF_REGA);
  u16* x3 = (u16*)(ws + OFF_REGA);
  u16* wt0 = (u16*)(ws + OFF_WT0);
  u16* wt1 = (u16*)(ws + OFF_WT1);
  u16* wt2 = (u16*)(ws + OFF_WT2);
  u16* wtf = (u16*)(ws + OFF_WTF);
  float2* psum = (float2*)(ws + O_PSUM);

  wtrans_all<<<1184, 256, 0, stream>>>(dw0, dw1, dw2, fc_w, wt0, wt1, wt2, wtf);
  fc_mfma<<<dim3(8, 64), 256, 0, stream>>>(feat, wtf, fc_b, gw0, gb0, x0);
  deconv_mfma<0><<<dim3(8, 64), 256, 0, stream>>>(x0, wt0, db0, x1, gw1, gb1);
  deconv_mfma<1><<<dim3(4, 256), 256, 0, stream>>>(x1, wt1, db1, x2, gw2, gb2);
  deconv2_q<<<dim3(2, 512), 256, 0, stream>>>(x2, wt2, db2, x3, psum);
  head_kernel<<<512, 512, 0, stream>>>(x3, psum, action, hgw, hcw, (float*)d_out);
}